// Round 1
// 967.441 us; speedup vs baseline: 1.2090x; 1.2090x over previous
//
#include <hip/hip_runtime.h>
#include <math.h>

// ---------------------------------------------------------------------------
// DiffPool GNN (N=8192, E=262144, F=H=128, C1=1024, C2=128, NC=16).
// R10: occupancy + latency round.
//  - merged K=8192 MFMA GEMMs (adj1/G/x1) into one launch, split-K z=8
//  - TT relocated (no Sb alias) so both big bf16 transposes fuse into one launch
//  - unroll-4 edge-gather loops (spmm_seg, agg_b16, agg16_ls)
//  - fused 3x S2s^T gemms into one launch; PP split-K widened to 16
// ---------------------------------------------------------------------------

#define N_NODES 8192
#define N_EDGES 262144

typedef __attribute__((ext_vector_type(8))) short short8;
typedef __attribute__((ext_vector_type(4))) float floatx4;

// ---------------- workspace layout (float-slot offsets, 16-aligned) ----------------
#define OFF_DEG     0           // 8192  (zeroed)
#define OFF_CNTC    8192        // 8192  (zeroed)
#define OFF_CNTR    16384       // 8192  (zeroed)
#define OFF_SCAL    24576       // 16 (zeroed) [0]=e1 [1]=cross(tr adj1) [2]=g2 [3]=sumA2
                                //             [4]=ss_adj1 [5]=e2 [6]=cross2(tr adj2) [7]=g2b
#define ZERO_FLOATS 24592
#define OFF_COLPTR  24592       // 8193
#define OFF_ROWPTR  32785       // 8193
#define OFF_CURC    40978       // 8192 (later: colsum partials 16x1024 span CURC+CURR)
#define OFF_CURR    49170       // 8192
#define OFF_COLR    57362       // E (int)
#define OFF_COLN    319506      // E
#define OFF_ROWC    581650      // E (int)
#define OFF_ROWW    843794      // E
#define OFF_DINV    1105938     // 8192
#define OFF_X0      1114144     // 8192*128 fp32 (x0_)
#define OFF_H0      2162720     // h0b bf16 [8192][128]
// Region A (4M slots at OFF_S: Sb -> {an1Tb, adj1b, hats...}):
#define OFF_S       3211296     // Sb bf16 [8192][1024]
#define OFF_AN1TB   OFF_S                 // bf16 [1024][1024] (after Sb dead)
#define OFF_ADJ1B   (OFF_S+524288)        // bf16 [1024][1024]
#define OFF_HAT     (OFF_S+1048576)       // bf16 [128][1024]
#define OFF_HBT     (OFF_S+1114112)       // bf16 [128][1024]
#define OFF_HCATT   (OFF_S+1179648)       // bf16 [128][1024]
#define OFF_S2ST    (OFF_S+1245184)       // bf16 [128][1024]
#define OFF_X0T     7405600     // bf16 [128][8192]
#define OFF_X0B     7929888     // bf16 [8192][128]
#define A2          8454176
#define OFF_X1      (A2+0)            // 1024*128
#define OFF_Y16     (A2+131072)       // 1024*16
#define OFF_X1_     (A2+262144)       // 1024*128
#define OFF_S2      (A2+524288)       // 1024*128
#define OFF_S2S     (A2+655360)       // 1024*128
#define OFF_U       (A2+786432)       // 1024*128
#define OFF_X2      (A2+917504)       // 128*128
#define OFF_ADJ2    (A2+933888)
#define OFF_HC      (A2+950272)
#define OFF_X2_     (A2+966656)
#define OFF_AN2     (A2+983040)
#define OFF_Z2      (A2+999424)       // 128*128
#define OFF_HCAT    (A2+1130496)      // 1024*128 fp32
#define OFF_X1O     (A2+1261568)      // 1024*128
#define OFF_P16     (A2+1392640)      // 8192*16
#define OFF_DI1     (A2+1654784)      // 1024
#define OFF_DF1     (A2+1655808)
#define OFF_DI2     (A2+1656832)      // 128
#define OFF_DF2     (A2+1656960)
// Region B:
#define OFF_ST      10111264          // S_T bf16 [1024][8192]
#define OFF_TBF     14305568          // t bf16 [8192][1024]; WP1T aliases; later PADJ
#define OFF_WP1T    OFF_TBF
#define OFF_PADJ    OFF_TBF           // fp32 [8][1024][1024]
#define OFF_PG      22694176          // fp32 [8][1024][1024]; later PP fp32 [16][1024][128]
#define OFF_PP      OFF_PG
#define OFF_PX1     31082784          // fp32 [8][1024][128]
#define OFF_TT2     32131360          // TT bf16 [8192][1024] (own region, no Sb alias)
// total: 36,325,664 float-slots = 138.6 MiB (ws is 1 GiB per harness fill size)

// ------------------- output layout (floats) -------------------
#define OUT_PRED 0          // 8192*16
#define OUT_S1   131072     // 8192*1024
#define OUT_LOSS 8519680    // 1
#define OUT_ADJ1 8519681    // 1024*1024

__device__ __forceinline__ unsigned short f2bf(float f) {
    union { float f; unsigned u; } v; v.f = f;
    unsigned r = (v.u + 0x7FFF + ((v.u >> 16) & 1)) >> 16;
    return (unsigned short)r;
}
__device__ __forceinline__ float bf2f(unsigned short b) {
    union { unsigned u; float f; } v; v.u = (unsigned)b << 16; return v.f;
}

// =========================== graph-structure kernels ===========================

__global__ void k_hist(const int* __restrict__ row, const int* __restrict__ col,
                       const float* __restrict__ ew, int E,
                       float* deg, int* cntc, int* cntr, float* sumA2) {
    __shared__ float red[256];
    int e = blockIdx.x * 256 + threadIdx.x;
    float w2 = 0.f;
    if (e < E) {
        int r = row[e], c = col[e];
        float w = ew[e];
        atomicAdd(&deg[c], w);
        atomicAdd(&cntc[c], 1);
        atomicAdd(&cntr[r], 1);
        w2 = w * w;
    }
    red[threadIdx.x] = w2; __syncthreads();
    for (int s = 128; s > 0; s >>= 1) { if (threadIdx.x < s) red[threadIdx.x] += red[threadIdx.x + s]; __syncthreads(); }
    if (threadIdx.x == 0) atomicAdd(sumA2, red[0]);
}

// scan of both count arrays + dinv (fused)
__global__ __launch_bounds__(1024) void k_scan(const int* cntc, const int* cntr,
        int* colptr, int* rowptr, int* curc, int* curr, int n, int E,
        const float* __restrict__ deg, float* __restrict__ dinv) {
    __shared__ int part[1024];
    int tid = threadIdx.x;
    const int per = 8;
    for (int pass = 0; pass < 2; ++pass) {
        const int* cnt = pass ? cntr : cntc;
        int* ptr = pass ? rowptr : colptr;
        int* cur = pass ? curr : curc;
        int st = tid * per;
        int loc[per]; int s = 0;
        for (int i = 0; i < per; ++i) { loc[i] = s; s += cnt[st + i]; }
        part[tid] = s; __syncthreads();
        for (int off = 1; off < 1024; off <<= 1) {
            int v = part[tid];
            int add = (tid >= off) ? part[tid - off] : 0;
            __syncthreads();
            part[tid] = v + add;
            __syncthreads();
        }
        int pre = (tid == 0) ? 0 : part[tid - 1];
        for (int i = 0; i < per; ++i) { int v = pre + loc[i]; ptr[st + i] = v; cur[st + i] = v; }
        if (tid == 0) ptr[n] = E;
        __syncthreads();
    }
    for (int i = tid; i < n; i += 1024) {
        float d = deg[i] + 1.0f;
        dinv[i] = (d > 0.f) ? 1.0f / sqrtf(d) : 0.f;
    }
}

__global__ void k_scatter(const int* __restrict__ row, const int* __restrict__ col,
                          const float* __restrict__ ew, int E, const float* __restrict__ dinv,
                          int* curc, int* curr, int* colr, float* coln, int* rowc, float* roww) {
    int e = blockIdx.x * 256 + threadIdx.x;
    if (e >= E) return;
    int r = row[e], c = col[e];
    float w = ew[e];
    float nrm = dinv[r] * w * dinv[c];
    int p = atomicAdd(&curc[c], 1);
    colr[p] = r; coln[p] = nrm;
    int q = atomicAdd(&curr[r], 1);
    rowc[q] = c; roww[q] = w;
}

// =========================== fp32 GEMMs ===========================

__global__ __launch_bounds__(256) void gemm_ab_b16(const float* __restrict__ A, const float* __restrict__ B,
        unsigned short* __restrict__ C, int M, int N, int K) {
    __shared__ float As[16][68];
    __shared__ float Bs[16][68];
    int tid = threadIdx.x, tx = tid & 15, ty = tid >> 4;
    int m0 = blockIdx.y * 64, n0 = blockIdx.x * 64;
    float acc[4][4] = {};
    for (int k0 = 0; k0 < K; k0 += 16) {
        for (int l = 0; l < 4; ++l) {
            int idx = tid + 256 * l;
            int mm = idx >> 4, kk = idx & 15;
            As[kk][mm] = A[(size_t)(m0 + mm) * K + k0 + kk];
            int kk2 = idx >> 6, nn = idx & 63;
            Bs[kk2][nn] = B[(size_t)(k0 + kk2) * N + n0 + nn];
        }
        __syncthreads();
        #pragma unroll
        for (int kk = 0; kk < 16; ++kk) {
            float a[4], b[4];
            #pragma unroll
            for (int i = 0; i < 4; ++i) a[i] = As[kk][ty * 4 + i];
            #pragma unroll
            for (int j = 0; j < 4; ++j) b[j] = Bs[kk][tx * 4 + j];
            #pragma unroll
            for (int i = 0; i < 4; ++i)
                #pragma unroll
                for (int j = 0; j < 4; ++j) acc[i][j] += a[i] * b[j];
        }
        __syncthreads();
    }
    for (int i = 0; i < 4; ++i)
        for (int j = 0; j < 4; ++j)
            C[(size_t)(m0 + ty * 4 + i) * N + n0 + tx * 4 + j] = f2bf(acc[i][j]);
}

// 32x32 tile, C = A@B (+bias/relu/accum), fp32 out
__global__ __launch_bounds__(256) void gemm_ab32(const float* __restrict__ A, const float* __restrict__ B,
        float* __restrict__ C, int M, int N, int K,
        const float* __restrict__ bias, int relu, int accum) {
    __shared__ float As[32][33];
    __shared__ float Bs[32][33];
    int tid = threadIdx.x, tx = tid & 15, ty = tid >> 4;
    int m0 = blockIdx.y * 32, n0 = blockIdx.x * 32;
    float acc[2][2] = {};
    for (int k0 = 0; k0 < K; k0 += 32) {
        #pragma unroll
        for (int l = 0; l < 4; ++l) {
            int idx = tid + 256 * l;
            int r = idx >> 5, c = idx & 31;
            As[r][c] = A[(size_t)(m0 + r) * K + k0 + c];
            Bs[r][c] = B[(size_t)(k0 + r) * N + n0 + c];
        }
        __syncthreads();
        #pragma unroll
        for (int kk = 0; kk < 32; ++kk) {
            float a0 = As[ty * 2][kk], a1 = As[ty * 2 + 1][kk];
            float b0 = Bs[kk][tx * 2], b1 = Bs[kk][tx * 2 + 1];
            acc[0][0] += a0 * b0; acc[0][1] += a0 * b1;
            acc[1][0] += a1 * b0; acc[1][1] += a1 * b1;
        }
        __syncthreads();
    }
    #pragma unroll
    for (int i = 0; i < 2; ++i)
        #pragma unroll
        for (int j = 0; j < 2; ++j) {
            int m = m0 + ty * 2 + i, n = n0 + tx * 2 + j;
            float v = acc[i][j];
            if (accum) v += C[(size_t)m * N + n];
            if (bias) v += bias[n];
            if (relu) v = fmaxf(v, 0.f);
            C[(size_t)m * N + n] = v;
        }
}

// 32x32 tile: CT[N][M] bf16 = (A@B)^T, single-source
__global__ __launch_bounds__(256) void gemm_ab32_bt(const float* __restrict__ A,
        const float* __restrict__ B, unsigned short* __restrict__ CT, int M, int N, int K) {
    __shared__ float As[32][33];
    __shared__ float Bs[32][33];
    int tid = threadIdx.x, tx = tid & 15, ty = tid >> 4;
    int m0 = blockIdx.y * 32, n0 = blockIdx.x * 32;
    float acc[2][2] = {};
    for (int k0 = 0; k0 < K; k0 += 32) {
        #pragma unroll
        for (int l = 0; l < 4; ++l) {
            int idx = tid + 256 * l;
            int r = idx >> 5, c = idx & 31;
            As[r][c] = A[(size_t)(m0 + r) * K + k0 + c];
            Bs[r][c] = B[(size_t)(k0 + r) * N + n0 + c];
        }
        __syncthreads();
        #pragma unroll
        for (int kk = 0; kk < 32; ++kk) {
            float a0 = As[ty * 2][kk], a1 = As[ty * 2 + 1][kk];
            float b0 = Bs[kk][tx * 2], b1 = Bs[kk][tx * 2 + 1];
            acc[0][0] += a0 * b0; acc[0][1] += a0 * b1;
            acc[1][0] += a1 * b0; acc[1][1] += a1 * b1;
        }
        __syncthreads();
    }
    // stage C tile in LDS (reuse As), write transposed bf16 coalesced
    #pragma unroll
    for (int i = 0; i < 2; ++i)
        #pragma unroll
        for (int j = 0; j < 2; ++j)
            As[ty * 2 + i][tx * 2 + j] = acc[i][j];   // As[m_local][n_local]
    __syncthreads();
    int nl = tid >> 3, moff = (tid & 7) * 4;
    ushort4 o;
    o.x = f2bf(As[moff + 0][nl]);
    o.y = f2bf(As[moff + 1][nl]);
    o.z = f2bf(As[moff + 2][nl]);
    o.w = f2bf(As[moff + 3][nl]);
    *(ushort4*)(CT + (size_t)(n0 + nl) * M + m0 + moff) = o;
}

// 32x32 tile, C = A^T@B with A[K][M], B[K][N]; optional sumsq-only mode
__global__ __launch_bounds__(256) void gemm_atb32(const float* __restrict__ A, const float* __restrict__ B,
        float* __restrict__ C, int M, int N, int K,
        const float* __restrict__ bias, int relu, float* sumsq_acc) {
    __shared__ float As[32][33];
    __shared__ float Bs[32][33];
    __shared__ float red[256];
    int tid = threadIdx.x, tx = tid & 15, ty = tid >> 4;
    int m0 = blockIdx.y * 32, n0 = blockIdx.x * 32;
    float acc[2][2] = {};
    for (int k0 = 0; k0 < K; k0 += 32) {
        #pragma unroll
        for (int l = 0; l < 4; ++l) {
            int idx = tid + 256 * l;
            int r = idx >> 5, c = idx & 31;
            As[c][r] = A[(size_t)(k0 + r) * M + m0 + c];
            Bs[r][c] = B[(size_t)(k0 + r) * N + n0 + c];
        }
        __syncthreads();
        #pragma unroll
        for (int kk = 0; kk < 32; ++kk) {
            float a0 = As[ty * 2][kk], a1 = As[ty * 2 + 1][kk];
            float b0 = Bs[kk][tx * 2], b1 = Bs[kk][tx * 2 + 1];
            acc[0][0] += a0 * b0; acc[0][1] += a0 * b1;
            acc[1][0] += a1 * b0; acc[1][1] += a1 * b1;
        }
        __syncthreads();
    }
    if (sumsq_acc) {
        float ss = acc[0][0] * acc[0][0] + acc[0][1] * acc[0][1]
                 + acc[1][0] * acc[1][0] + acc[1][1] * acc[1][1];
        red[tid] = ss; __syncthreads();
        for (int s = 128; s > 0; s >>= 1) { if (tid < s) red[tid] += red[tid + s]; __syncthreads(); }
        if (tid == 0) atomicAdd(sumsq_acc, red[0]);
        return;
    }
    #pragma unroll
    for (int i = 0; i < 2; ++i)
        #pragma unroll
        for (int j = 0; j < 2; ++j) {
            int m = m0 + ty * 2 + i, n = n0 + tx * 2 + j;
            float v = acc[i][j];
            if (bias) v += bias[n];
            if (relu) v = fmaxf(v, 0.f);
            C[(size_t)m * N + n] = v;
        }
}

// fused 3x (A^T@B) sharing A=S2s: op0 C0=A^T@B0, op1 C1=A^T@B1, op2 sumsq(A^T@B2)
__global__ __launch_bounds__(256) void k_atb32_3(const float* __restrict__ A,
        const float* __restrict__ B0, const float* __restrict__ B1, const float* __restrict__ B2,
        float* __restrict__ C0, float* __restrict__ C1, float* ss_acc,
        int M, int N, int K) {
    __shared__ float As[32][33];
    __shared__ float Bs[32][33];
    __shared__ float red[256];
    int op = blockIdx.z;
    const float* B = (op == 0) ? B0 : (op == 1) ? B1 : B2;
    int tid = threadIdx.x, tx = tid & 15, ty = tid >> 4;
    int m0 = blockIdx.y * 32, n0 = blockIdx.x * 32;
    float acc[2][2] = {};
    for (int k0 = 0; k0 < K; k0 += 32) {
        #pragma unroll
        for (int l = 0; l < 4; ++l) {
            int idx = tid + 256 * l;
            int r = idx >> 5, c = idx & 31;
            As[c][r] = A[(size_t)(k0 + r) * M + m0 + c];
            Bs[r][c] = B[(size_t)(k0 + r) * N + n0 + c];
        }
        __syncthreads();
        #pragma unroll
        for (int kk = 0; kk < 32; ++kk) {
            float a0 = As[ty * 2][kk], a1 = As[ty * 2 + 1][kk];
            float b0 = Bs[kk][tx * 2], b1 = Bs[kk][tx * 2 + 1];
            acc[0][0] += a0 * b0; acc[0][1] += a0 * b1;
            acc[1][0] += a1 * b0; acc[1][1] += a1 * b1;
        }
        __syncthreads();
    }
    if (op == 2) {
        float ss = acc[0][0] * acc[0][0] + acc[0][1] * acc[0][1]
                 + acc[1][0] * acc[1][0] + acc[1][1] * acc[1][1];
        red[tid] = ss; __syncthreads();
        for (int s = 128; s > 0; s >>= 1) { if (tid < s) red[tid] += red[tid + s]; __syncthreads(); }
        if (tid == 0) atomicAdd(ss_acc, red[0]);
        return;
    }
    float* C = (op == 0) ? C0 : C1;
    #pragma unroll
    for (int i = 0; i < 2; ++i)
        #pragma unroll
        for (int j = 0; j < 2; ++j)
            C[(size_t)(m0 + ty * 2 + i) * N + n0 + tx * 2 + j] = acc[i][j];
}

// C[M][16] (+)= A[M][K] @ B[K][16]
__global__ __launch_bounds__(256) void k_gemm_n16(const float* __restrict__ A, const float* __restrict__ B,
        float* __restrict__ C, int M, int K, int accum) {
    __shared__ float As[16][64];
    __shared__ float Bs[64][16];
    int tid = threadIdx.x;
    int r = tid >> 4, c = tid & 15;
    int m0 = blockIdx.x * 16;
    float acc = 0.f;
    for (int k0 = 0; k0 < K; k0 += 64) {
        #pragma unroll
        for (int l = 0; l < 4; ++l) {
            int idx = tid + 256 * l;
            int rr = idx >> 6, cc = idx & 63;
            As[rr][cc] = A[(size_t)(m0 + rr) * K + k0 + cc];
            int kk = idx >> 4, c2 = idx & 15;
            Bs[kk][c2] = B[(size_t)(k0 + kk) * 16 + c2];
        }
        __syncthreads();
        #pragma unroll 16
        for (int kk = 0; kk < 64; ++kk) acc += As[r][kk] * Bs[kk][c];
        __syncthreads();
    }
    float* p = &C[(size_t)(m0 + r) * 16 + c];
    if (accum) acc += *p;
    *p = acc;
}

// =========================== bf16 MFMA GEMMs ===========================

// split-K partial store: P[z][M][N] = partial of sum_k A[m][k]*B[n][k]
__global__ __launch_bounds__(256) void gemm_tn_bf16_part(
        const unsigned short* __restrict__ A, const unsigned short* __restrict__ B,
        float* __restrict__ P, int M, int N, int K) {
    __shared__ __align__(16) unsigned short As[128 * 64];
    __shared__ __align__(16) unsigned short Bs[128 * 64];
    int tid = threadIdx.x;
    int wave = tid >> 6, lane = tid & 63;
    int wm = wave >> 1, wn = wave & 1;
    int m0 = blockIdx.x * 128, n0 = blockIdx.y * 128;
    int kchunk = K / gridDim.z;
    int k0 = blockIdx.z * kchunk;
    float* Pz = P + (size_t)blockIdx.z * M * N;
    floatx4 acc[4][4] = {};
    int sr = tid >> 3;
    int sc = (tid & 7) * 8;
    int q = lane >> 4, lm = lane & 15;
    for (int kt = 0; kt < kchunk; kt += 64) {
        #pragma unroll
        for (int p = 0; p < 4; ++p) {
            int mrow = sr + p * 32;
            int gk = k0 + kt + sc;
            int scs = sc ^ ((mrow & 7) * 8);
            *(short8*)(&As[mrow * 64 + scs]) = *(const short8*)(&A[(size_t)(m0 + mrow) * K + gk]);
            *(short8*)(&Bs[mrow * 64 + scs]) = *(const short8*)(&B[(size_t)(n0 + mrow) * K + gk]);
        }
        __syncthreads();
        #pragma unroll
        for (int ks = 0; ks < 64; ks += 32) {
            short8 af[4], bf[4];
            int kk = ks + q * 8;
            #pragma unroll
            for (int i = 0; i < 4; ++i) {
                int ml = wm * 64 + i * 16 + lm;
                af[i] = *(const short8*)(&As[ml * 64 + (kk ^ ((ml & 7) * 8))]);
                int nl = wn * 64 + i * 16 + lm;
                bf[i] = *(const short8*)(&Bs[nl * 64 + (kk ^ ((nl & 7) * 8))]);
            }
            #pragma unroll
            for (int i = 0; i < 4; ++i)
                #pragma unroll
                for (int j = 0; j < 4; ++j)
                    acc[i][j] = __builtin_amdgcn_mfma_f32_16x16x32_bf16(af[i], bf[j], acc[i][j], 0, 0, 0);
        }
        __syncthreads();
    }
    for (int i = 0; i < 4; ++i) {
        int rowb = m0 + wm * 64 + i * 16 + q * 4;
        for (int j = 0; j < 4; ++j) {
            int col = n0 + wn * 64 + j * 16 + lm;
            #pragma unroll
            for (int r = 0; r < 4; ++r)
                Pz[(size_t)(rowb + r) * N + col] = acc[i][j][r];
        }
    }
}

// merged K=8192 split-K GEMM: grid (8, 17, 8). A=ST [1024][8192].
//  by 0..7  : B=TT  (N=1024) -> P0 (adj1 partials)
//  by 8..15 : B=ST  (N=1024) -> P1 (G partials)
//  by 16    : B=X0T (N=128)  -> P2 (x1 partials)
__global__ __launch_bounds__(256) void gemm_tn_bf16_part3(
        const unsigned short* __restrict__ A,
        const unsigned short* __restrict__ B0, const unsigned short* __restrict__ B1,
        const unsigned short* __restrict__ B2,
        float* __restrict__ P0, float* __restrict__ P1, float* __restrict__ P2,
        int K) {
    __shared__ __align__(16) unsigned short As[128 * 64];
    __shared__ __align__(16) unsigned short Bs[128 * 64];
    int tid = threadIdx.x;
    int wave = tid >> 6, lane = tid & 63;
    int wm = wave >> 1, wn = wave & 1;
    int by = blockIdx.y;
    const unsigned short* B; float* P; int N, n0;
    if (by < 8)       { B = B0; P = P0; N = 1024; n0 = by * 128; }
    else if (by < 16) { B = B1; P = P1; N = 1024; n0 = (by - 8) * 128; }
    else              { B = B2; P = P2; N = 128;  n0 = 0; }
    int m0 = blockIdx.x * 128;
    int kchunk = K / gridDim.z;
    int k0 = blockIdx.z * kchunk;
    float* Pz = P + (size_t)blockIdx.z * 1024 * N;
    floatx4 acc[4][4] = {};
    int sr = tid >> 3;
    int sc = (tid & 7) * 8;
    int q = lane >> 4, lm = lane & 15;
    for (int kt = 0; kt < kchunk; kt += 64) {
        #pragma unroll
        for (int p = 0; p < 4; ++p) {
            int mrow = sr + p * 32;
            int gk = k0 + kt + sc;
            int scs = sc ^ ((mrow & 7) * 8);
            *(short8*)(&As[mrow * 64 + scs]) = *(const short8*)(&A[(size_t)(m0 + mrow) * K + gk]);
            *(short8*)(&Bs[mrow * 64 + scs]) = *(const short8*)(&B[(size_t)(n0 + mrow) * K + gk]);
        }
        __syncthreads();
        #pragma unroll
        for (int ks = 0; ks < 64; ks += 32) {
            short8 af[4], bf[4];
            int kk = ks + q * 8;
            #pragma unroll
            for (int i = 0; i < 4; ++i) {
                int ml = wm * 64 + i * 16 + lm;
                af[i] = *(const short8*)(&As[ml * 64 + (kk ^ ((ml & 7) * 8))]);
                int nl = wn * 64 + i * 16 + lm;
                bf[i] = *(const short8*)(&Bs[nl * 64 + (kk ^ ((nl & 7) * 8))]);
            }
            #pragma unroll
            for (int i = 0; i < 4; ++i)
                #pragma unroll
                for (int j = 0; j < 4; ++j)
                    acc[i][j] = __builtin_amdgcn_mfma_f32_16x16x32_bf16(af[i], bf[j], acc[i][j], 0, 0, 0);
        }
        __syncthreads();
    }
    for (int i = 0; i < 4; ++i) {
        int rowb = m0 + wm * 64 + i * 16 + q * 4;
        for (int j = 0; j < 4; ++j) {
            int col = n0 + wn * 64 + j * 16 + lm;
            #pragma unroll
            for (int r = 0; r < 4; ++r)
                Pz[(size_t)(rowb + r) * N + col] = acc[i][j][r];
        }
    }
}

// full-K store with bias+relu (s1o)
__global__ __launch_bounds__(256) void gemm_tn_bf16_store(
        const unsigned short* __restrict__ A, const unsigned short* __restrict__ B,
        float* __restrict__ C, int M, int N, int K,
        const float* __restrict__ bias, int relu) {
    __shared__ __align__(16) unsigned short As[128 * 64];
    __shared__ __align__(16) unsigned short Bs[128 * 64];
    int tid = threadIdx.x;
    int wave = tid >> 6, lane = tid & 63;
    int wm = wave >> 1, wn = wave & 1;
    int m0 = blockIdx.x * 128, n0 = blockIdx.y * 128;
    floatx4 acc[4][4] = {};
    int sr = tid >> 3;
    int sc = (tid & 7) * 8;
    int q = lane >> 4, lm = lane & 15;
    for (int kt = 0; kt < K; kt += 64) {
        #pragma unroll
        for (int p = 0; p < 4; ++p) {
            int mrow = sr + p * 32;
            int gk = kt + sc;
            int scs = sc ^ ((mrow & 7) * 8);
            *(short8*)(&As[mrow * 64 + scs]) = *(const short8*)(&A[(size_t)(m0 + mrow) * K + gk]);
            *(short8*)(&Bs[mrow * 64 + scs]) = *(const short8*)(&B[(size_t)(n0 + mrow) * K + gk]);
        }
        __syncthreads();
        #pragma unroll
        for (int ks = 0; ks < 64; ks += 32) {
            short8 af[4], bf[4];
            int kk = ks + q * 8;
            #pragma unroll
            for (int i = 0; i < 4; ++i) {
                int ml = wm * 64 + i * 16 + lm;
                af[i] = *(const short8*)(&As[ml * 64 + (kk ^ ((ml & 7) * 8))]);
                int nl = wn * 64 + i * 16 + lm;
                bf[i] = *(const short8*)(&Bs[nl * 64 + (kk ^ ((nl & 7) * 8))]);
            }
            #pragma unroll
            for (int i = 0; i < 4; ++i)
                #pragma unroll
                for (int j = 0; j < 4; ++j)
                    acc[i][j] = __builtin_amdgcn_mfma_f32_16x16x32_bf16(af[i], bf[j], acc[i][j], 0, 0, 0);
        }
        __syncthreads();
    }
    for (int i = 0; i < 4; ++i) {
        int rowb = m0 + wm * 64 + i * 16 + q * 4;
        for (int j = 0; j < 4; ++j) {
            int col = n0 + wn * 64 + j * 16 + lm;
            float bv = bias ? bias[col] : 0.f;
            #pragma unroll
            for (int r = 0; r < 4; ++r) {
                float v = acc[i][j][r] + bv;
                if (relu) v = fmaxf(v, 0.f);
                C[(size_t)(rowb + r) * N + col] = v;
            }
        }
    }
}

// reduce nsplit partials; optional fp32 C, dual bf16 Cb, sumsq accumulation
__global__ __launch_bounds__(256) void k_reduce4(const float* __restrict__ P,
        float* __restrict__ C, unsigned short* __restrict__ Cb,
        int n, int nsplit, float* ss_acc) {
    __shared__ float red[256];
    float ss = 0.f;
    for (int i4 = (blockIdx.x * 256 + threadIdx.x) * 4; i4 < n; i4 += gridDim.x * 256 * 4) {
        float4 v = *(const float4*)(P + i4);
        for (int s = 1; s < nsplit; ++s) {
            float4 w = *(const float4*)(P + (size_t)s * n + i4);
            v.x += w.x; v.y += w.y; v.z += w.z; v.w += w.w;
        }
        if (C) *(float4*)(C + i4) = v;
        if (Cb) {
            ushort4 o; o.x = f2bf(v.x); o.y = f2bf(v.y); o.z = f2bf(v.z); o.w = f2bf(v.w);
            *(ushort4*)(Cb + i4) = o;
        }
        ss += v.x * v.x + v.y * v.y + v.z * v.z + v.w * v.w;
    }
    if (!ss_acc) return;
    red[threadIdx.x] = ss; __syncthreads();
    for (int s = 128; s > 0; s >>= 1) { if (threadIdx.x < s) red[threadIdx.x] += red[threadIdx.x + s]; __syncthreads(); }
    if (threadIdx.x == 0) atomicAdd(ss_acc, red[0]);
}

// reduce nsplit partials [ns][M][N] -> C fp32 with bias (len N) + relu
__global__ __launch_bounds__(256) void k_reduce_br(const float* __restrict__ P,
        float* __restrict__ C, int n, int N, int nsplit,
        const float* __restrict__ bias, int relu) {
    for (int i4 = (blockIdx.x * 256 + threadIdx.x) * 4; i4 < n; i4 += gridDim.x * 256 * 4) {
        float4 v = *(const float4*)(P + i4);
        for (int s = 1; s < nsplit; ++s) {
            float4 w = *(const float4*)(P + (size_t)s * n + i4);
            v.x += w.x; v.y += w.y; v.z += w.z; v.w += w.w;
        }
        if (bias) {
            float4 b = *(const float4*)(bias + (i4 % N));
            v.x += b.x; v.y += b.y; v.z += b.z; v.w += b.w;
        }
        if (relu) {
            v.x = fmaxf(v.x, 0.f); v.y = fmaxf(v.y, 0.f);
            v.z = fmaxf(v.z, 0.f); v.w = fmaxf(v.w, 0.f);
        }
        *(float4*)(C + i4) = v;
    }
}

// =========================== transposes ===========================

__global__ __launch_bounds__(256) void k_transpose_f2b(
        const float* __restrict__ in, unsigned short* __restrict__ outb,
        int R, int C, const float* __restrict__ rowscale) {
    __shared__ float tile[64][65];
    int rb = blockIdx.y * 64, cb = blockIdx.x * 64;
    int t = threadIdx.x;
    int lr = t >> 4, lc4 = (t & 15) * 4;
    #pragma unroll
    for (int p = 0; p < 4; ++p) {
        int r = rb + lr + p * 16;
        float4 v = *(const float4*)(in + (size_t)r * C + cb + lc4);
        float s = rowscale ? rowscale[r] : 1.0f;
        tile[lr + p * 16][lc4 + 0] = v.x * s;
        tile[lr + p * 16][lc4 + 1] = v.y * s;
        tile[lr + p * 16][lc4 + 2] = v.z * s;
        tile[lr + p * 16][lc4 + 3] = v.w * s;
    }
    __syncthreads();
    int cc0 = t >> 5, rr = (t & 31) * 2;
    #pragma unroll
    for (int p = 0; p < 8; ++p) {
        int cc = cc0 + p * 8;
        unsigned a = f2bf(tile[rr][cc]);
        unsigned b = f2bf(tile[rr + 1][cc]);
        *(unsigned*)(outb + (size_t)(cb + cc) * R + rb + rr) = a | (b << 16);
    }
}

// dual bf16 transpose: blockIdx.z selects (in0->out0) or (in1->out1)
__global__ __launch_bounds__(256) void k_transpose_b2b2(
        const unsigned short* __restrict__ in0, unsigned short* __restrict__ out0,
        const unsigned short* __restrict__ in1, unsigned short* __restrict__ out1,
        int R, int C) {
    __shared__ __align__(16) unsigned short tile[64][72];
    const unsigned short* in = blockIdx.z ? in1 : in0;
    unsigned short* out = blockIdx.z ? out1 : out0;
    int rb = blockIdx.y * 64, cb = blockIdx.x * 64;
    int t = threadIdx.x;
    int lr = t >> 3, lc = (t & 7) * 8;
    #pragma unroll
    for (int p = 0; p < 2; ++p) {
        int r = lr + p * 32;
        *(short8*)(&tile[r][lc]) = *(const short8*)(&in[(size_t)(rb + r) * C + cb + lc]);
    }
    __syncthreads();
    int cc0 = t >> 4, rr = (t & 15) * 4;
    #pragma unroll
    for (int p = 0; p < 4; ++p) {
        int cc = cc0 + p * 16;
        unsigned long long v = (unsigned long long)tile[rr][cc]
                             | ((unsigned long long)tile[rr + 1][cc] << 16)
                             | ((unsigned long long)tile[rr + 2][cc] << 32)
                             | ((unsigned long long)tile[rr + 3][cc] << 48);
        *(unsigned long long*)(&out[(size_t)(cb + cc) * R + rb + rr]) = v;
    }
}

// an1Tb[j][i] = bf16( dinv[i]*(adj1[i][j] + (i==j)*dfix[i])*dinv[j] )
__global__ __launch_bounds__(256) void k_anorm_tb(const float* __restrict__ adjm, int n,
        const float* __restrict__ dinvv, const float* __restrict__ dfix,
        unsigned short* __restrict__ outb) {
    __shared__ float tile[64][65];
    int rb = blockIdx.y * 64, cb = blockIdx.x * 64;
    int t = threadIdx.x;
    int lr = t >> 4, lc4 = (t & 15) * 4;
    #pragma unroll
    for (int p = 0; p < 4; ++p) {
        int i = rb + lr + p * 16;
        float4 v = *(const float4*)(adjm + (size_t)i * n + cb + lc4);
        float di = dinvv[i];
        float vv[4] = {v.x, v.y, v.z, v.w};
        #pragma unroll
        for (int q = 0; q < 4; ++q) {
            int j = cb + lc4 + q;
            float val = vv[q];
            if (i == j) val += dfix[i];
            tile[lr + p * 16][lc4 + q] = di * val * dinvv[j];
        }
    }
    __syncthreads();
    int cc0 = t >> 5, rr = (t & 31) * 2;
    #pragma unroll
    for (int p = 0; p < 8; ++p) {
        int cc = cc0 + p * 8;
        unsigned a = f2bf(tile[rr][cc]);
        unsigned b = f2bf(tile[rr + 1][cc]);
        *(unsigned*)(outb + (size_t)(cb + cc) * n + rb + rr) = a | (b << 16);
    }
}

// =========================== aggregation / misc ===========================

__global__ __launch_bounds__(64) void k_agg_b16(const unsigned short* __restrict__ h,
        float* __restrict__ out, unsigned short* __restrict__ outb,
        const int* __restrict__ cptr, const int* __restrict__ colr,
        const float* __restrict__ coln, const float* __restrict__ dinv,
        const float* __restrict__ bias, int relu) {
    int c = blockIdx.x, t = threadIdx.x;
    int f0 = t * 2;
    float d = dinv[c], dd = d * d;
    const unsigned short* hf = h + f0;
    unsigned u = *(const unsigned*)(hf + (size_t)c * 128);
    float a0 = dd * bf2f((unsigned short)(u & 0xffff));
    float a1 = dd * bf2f((unsigned short)(u >> 16));
    int e0 = cptr[c], e1 = cptr[c + 1];
    int e = e0;
    for (; e + 4 <= e1; e += 4) {
        int r0 = colr[e], r1 = colr[e + 1], r2 = colr[e + 2], r3 = colr[e + 3];
        float w0 = coln[e], w1 = coln[e + 1], w2 = coln[e + 2], w3 = coln[e + 3];
        unsigned v0 = *(const unsigned*)(hf + (size_t)r0 * 128);
        unsigned v1 = *(const unsigned*)(hf + (size_t)r1 * 128);
        unsigned v2 = *(const unsigned*)(hf + (size_t)r2 * 128);
        unsigned v3 = *(const unsigned*)(hf + (size_t)r3 * 128);
        a0 += w0 * bf2f((unsigned short)(v0 & 0xffff)) + w1 * bf2f((unsigned short)(v1 & 0xffff))
            + w2 * bf2f((unsigned short)(v2 & 0xffff)) + w3 * bf2f((unsigned short)(v3 & 0xffff));
        a1 += w0 * bf2f((unsigned short)(v0 >> 16)) + w1 * bf2f((unsigned short)(v1 >> 16))
            + w2 * bf2f((unsigned short)(v2 >> 16)) + w3 * bf2f((unsigned short)(v3 >> 16));
    }
    for (; e < e1; ++e) {
        float w = coln[e];
        unsigned v = *(const unsigned*)(hf + (size_t)colr[e] * 128);
        a0 += w * bf2f((unsigned short)(v & 0xffff));
        a1 += w * bf2f((unsigned short)(v >> 16));
    }
    if (bias) { a0 += bias[f0]; a1 += bias[f0 + 1]; }
    if (relu) { a0 = fmaxf(a0, 0.f); a1 = fmaxf(a1, 0.f); }
    if (out) { out[(size_t)c * 128 + f0] = a0; out[(size_t)c * 128 + f0 + 1] = a1; }
    if (outb) {
        unsigned o = (unsigned)f2bf(a0) | ((unsigned)f2bf(a1) << 16);
        *(unsigned*)(outb + (size_t)c * 128 + f0) = o;
    }
}

// F=16 agg + fused log_softmax (16-lane groups), writes prediction directly
__global__ __launch_bounds__(256) void k_agg16_ls(const float* __restrict__ h, float* __restrict__ pred,
        const int* __restrict__ cptr, const int* __restrict__ colr,
        const float* __restrict__ coln, const float* __restrict__ dinv,
        const float* __restrict__ bias) {
    int node = blockIdx.x * 16 + (threadIdx.x >> 4);
    int f = threadIdx.x & 15;
    float d = dinv[node];
    const float* hf = h + f;
    float acc = d * d * hf[(size_t)node * 16];
    int e0 = cptr[node], e1 = cptr[node + 1];
    int e = e0;
    for (; e + 4 <= e1; e += 4) {
        int r0 = colr[e], r1 = colr[e + 1], r2 = colr[e + 2], r3 = colr[e + 3];
        float w0 = coln[e], w1 = coln[e + 1], w2 = coln[e + 2], w3 = coln[e + 3];
        float v0 = hf[(size_t)r0 * 16], v1 = hf[(size_t)r1 * 16];
        float v2 = hf[(size_t)r2 * 16], v3 = hf[(size_t)r3 * 16];
        acc += w0 * v0 + w1 * v1 + w2 * v2 + w3 * v3;
    }
    for (; e < e1; ++e)
        acc += coln[e] * hf[(size_t)colr[e] * 16];
    acc += bias[f];
    acc = fmaxf(acc, 0.f);
    float m = acc;
    #pragma unroll
    for (int off = 1; off < 16; off <<= 1) m = fmaxf(m, __shfl_xor(m, off, 16));
    float ex = expf(acc - m);
    float s = ex;
    #pragma unroll
    for (int off = 1; off < 16; off <<= 1) s += __shfl_xor(s, off, 16);
    pred[(size_t)node * 16 + f] = acc - m - logf(s);
}

__global__ __launch_bounds__(256) void k_softmax1024(const float* __restrict__ x,
        unsigned short* __restrict__ Sb, const float* __restrict__ mask, float* ent_acc) {
    __shared__ float red[256];
    int r = blockIdx.x, tid = threadIdx.x;
    const float* xr = x + (size_t)r * 1024;
    float4 v = *(const float4*)(xr + tid * 4);
    float m = fmaxf(fmaxf(v.x, v.y), fmaxf(v.z, v.w));
    red[tid] = m; __syncthreads();
    for (int s = 128; s > 0; s >>= 1) { if (tid < s) red[tid] = fmaxf(red[tid], red[tid + s]); __syncthreads(); }
    m = red[0]; __syncthreads();
    float e0 = expf(v.x - m), e1 = expf(v.y - m), e2 = expf(v.z - m), e3 = expf(v.w - m);
    red[tid] = e0 + e1 + e2 + e3; __syncthreads();
    for (int s = 128; s > 0; s >>= 1) { if (tid < s) red[tid] += red[tid + s]; __syncthreads(); }
    float inv = 1.0f / red[0]; __syncthreads();
    float mk = mask ? mask[r] : 1.0f;
    float s0 = e0 * inv * mk, s1 = e1 * inv * mk, s2 = e2 * inv * mk, s3 = e3 * inv * mk;
    float ent = -(s0 * logf(s0 + 1e-15f) + s1 * logf(s1 + 1e-15f)
                + s2 * logf(s2 + 1e-15f) + s3 * logf(s3 + 1e-15f));
    ushort4 o;
    o.x = f2bf(s0); o.y = f2bf(s1); o.z = f2bf(s2); o.w = f2bf(s3);
    *(ushort4*)(Sb + (size_t)r * 1024 + tid * 4) = o;
    red[tid] = ent; __syncthreads();
    for (int s = 128; s > 0; s >>= 1) { if (tid < s) red[tid] += red[tid + s]; __syncthreads(); }
    if (tid == 0) atomicAdd(ent_acc, red[0]);
}

__global__ __launch_bounds__(256) void k_softmax_ent(const float* __restrict__ x, float* __restrict__ S,
        int W, const float* __restrict__ mask, float* ent_acc) {
    __shared__ float red[256];
    int row = blockIdx.x, tid = threadIdx.x;
    const float* xr = x + (size_t)row * W;
    float m = -3.0e38f;
    for (int q = tid; q < W; q += 256) m = fmaxf(m, xr[q]);
    red[tid] = m; __syncthreads();
    for (int s = 128; s > 0; s >>= 1) { if (tid < s) red[tid] = fmaxf(red[tid], red[tid + s]); __syncthreads(); }
    m = red[0]; __syncthreads();
    float sum = 0.f;
    for (int q = tid; q < W; q += 256) sum += expf(xr[q] - m);
    red[tid] = sum; __syncthreads();
    for (int s = 128; s > 0; s >>= 1) { if (tid < s) red[tid] += red[tid + s]; __syncthreads(); }
    float inv = 1.0f / red[0]; __syncthreads();
    float mk = mask ? mask[row] : 1.0f;
    float* Sr = S + (size_t)row * W;
    float ent = 0.f;
    for (int q = tid; q < W; q += 256) {
        float v = expf(xr[q] - m) * inv * mk;
        Sr[q] = v;
        ent -= v * logf(v + 1e-15f);
    }
    red[tid] = ent; __syncthreads();
    for (int s = 128; s > 0; s >>= 1) { if (tid < s) red[tid] += red[tid + s]; __syncthreads(); }
    if (tid == 0) atomicAdd(ent_acc, red[0]);
}

// L2-segmented SpMM, 4 waves/block = 4 rows, pass p = cols [p*128, p*128+128)
__global__ __launch_bounds__(256) void k_spmm_seg(const unsigned short* __restrict__ Sb,
        const int* __restrict__ rptr, const int* __restrict__ rowc, const float* __restrict__ roww,
        unsigned short* __restrict__ tb) {
    int wave = threadIdx.x >> 6, lane = threadIdx.x & 63;
    int r = blockIdx.x * 4 + wave;
    int j0 = blockIdx.y * 128 + lane * 2;
    const unsigned short* Sj = Sb + j0;
    float a0 = 0.f, a1 = 0.f;
    int e0 = rptr[r], e1 = rptr[r + 1];
    int e = e0;
    for (; e + 4 <= e1; e += 4) {
        int c0 = rowc[e], c1 = rowc[e + 1], c2 = rowc[e + 2], c3 = rowc[e + 3];
        float w0 = roww[e], w1 = roww[e + 1], w2 = roww[e + 2], w3 = roww[e + 3];
        unsigned v0 = *(const unsigned*)(Sj + (size_t)c0 * 1024);
        unsigned v1 = *(const unsigned*)(Sj + (size_t)c1 * 1024);
        unsigned v2 = *(const unsigned*)(Sj + (size_t)c2 * 1024);
        unsigned v3 = *(const unsigned*)(Sj + (size_t)c3 * 1024);
        a0 += w0 * bf2f((unsigned short)(v0 & 0xffff)) + w1 * bf2f((unsigned short)(v1 & 0xffff))
            + w2 * bf2f((unsigned short)(v2 & 0xffff)) + w3 * bf2f((unsigned short)(v3 & 0xffff));
        a1 += w0 * bf2f((unsigned short)(v0 >> 16)) + w1 * bf2f((unsigned short)(v1 >> 16))
            + w2 * bf2f((unsigned short)(v2 >> 16)) + w3 * bf2f((unsigned short)(v3 >> 16));
    }
    for (; e < e1; ++e) {
        int c = rowc[e]; float w = roww[e];
        unsigned v = *(const unsigned*)(Sj + (size_t)c * 1024);
        a0 += w * bf2f((unsigned short)(v & 0xffff));
        a1 += w * bf2f((unsigned short)(v >> 16));
    }
    unsigned o = (unsigned)f2bf(a0) | ((unsigned)f2bf(a1) << 16);
    *(unsigned*)(tb + (size_t)r * 1024 + j0) = o;
}

__global__ void k_colsum_part(const float* __restrict__ adjm, int n, float* part) {
    int j = blockIdx.x * blockDim.x + threadIdx.x;
    if (j >= n) return;
    int r0 = blockIdx.y * 64;
    float s = 0.f;
    for (int r = r0; r < r0 + 64; ++r) s += adjm[(size_t)r * n + j];
    part[(size_t)blockIdx.y * n + j] = s;
}

// dfix + dinv for adj1 + cross = trace(adj1)
__global__ void k_dfix_part(const float* __restrict__ adjm, int n, const float* __restrict__ part,
                            int nparts, float* dinvv, float* dfix, float* cross_acc) {
    __shared__ float red[256];
    int j = blockIdx.x * blockDim.x + threadIdx.x;
    float diag = 0.f;
    if (j < n) {
        float s = 0.f;
        for (int p = 0; p < nparts; ++p) s += part[(size_t)p * n + j];
        diag = adjm[(size_t)j * n + j];
        float fix = (diag == 0.f) ? 1.0f : 0.f;
        s += fix;
        dfix[j] = fix;
        dinvv[j] = (s > 0.f) ? 1.0f / sqrtf(s) : 0.f;
    }
    red[threadIdx.x] = diag; __syncthreads();
    for (int s = 128; s > 0; s >>= 1) { if (threadIdx.x < s) red[threadIdx.x] += red[threadIdx.x + s]; __syncthreads(); }
    if (threadIdx.x == 0) atomicAdd(cross_acc, red[0]);
}

// fused colsum+dfix for n=128 + cross2 = trace(adj2)
__global__ __launch_bounds__(128) void k_coldfix128(const float* __restrict__ adjm,
        float* dinvv, float* dfix, float* cross2_out) {
    __shared__ float red[128];
    int j = threadIdx.x;
    float s = 0.f;
    for (int i = 0; i < 128; ++i) s += adjm[(size_t)i * 128 + j];
    float diag = adjm[(size_t)j * 128 + j];
    float fix = (diag == 0.f) ? 1.0f : 0.f;
    s += fix;
    dfix[j] = fix;
    dinvv[j] = (s > 0.f) ? 1.0f / sqrtf(s) : 0.f;
    red[j] = diag; __syncthreads();
    for (int st = 64; st > 0; st >>= 1) { if (j < st) red[j] += red[j + st]; __syncthreads(); }
    if (j == 0) *cross2_out = red[0];
}

__global__ void k_anorm(const float* __restrict__ adjm, int n, const float* __restrict__ dinvv,
                        const float* __restrict__ dfix, float* __restrict__ anorm) {
    int idx = blockIdx.x * 256 + threadIdx.x;
    if (idx >= n * n) return;
    int i = idx / n, j = idx % n;
    float v = adjm[idx] + ((i == j) ? dfix[j] : 0.f);
    anorm[idx] = dinvv[i] * v * dinvv[j];
}

__global__ void k_finalize(const float* __restrict__ sc, float* loss) {
    if (threadIdx.x == 0 && blockIdx.x == 0) {
        float e1     = sc[0] / 8192.0f;
        float cross  = sc[1];
        float g2     = sc[2];
        float sumA2  = sc[3];
        float ssadj1 = sc[4];
        float e2     = sc[5] / 1024.0f;
        float cross2 = sc[6];
        float g2b    = sc[7];
        float l1 = sqrtf(fmaxf(sumA2 - 2.0f * cross + g2, 0.f)) / 67108864.0f;
        float l2 = sqrtf(fmaxf(ssadj1 - 2.0f * cross2 + g2b, 0.f)) / 1048576.0f;
        *loss = l1 + e1 + l2 + e2;
    }
}

// =========================== launcher ===========================

extern "C" void kernel_launch(void* const* d_in, const int* in_sizes, int n_in,
                              void* d_out, int out_size, void* d_ws, size_t ws_size,
                              hipStream_t stream) {
    const int N = N_NODES, E = N_EDGES;
    const float* x0     = (const float*)d_in[0];
    const int*   eidx   = (const int*)d_in[1];
    const float* ew     = (const float*)d_in[2];
    const float* mask   = (const float*)d_in[4];
    const float* W0_in  = (const float*)d_in[5];
    const float* b0_in  = (const float*)d_in[6];
    const float* Wp1    = (const float*)d_in[7];
    const float* bp1    = (const float*)d_in[8];
    const float* W1_in  = (const float*)d_in[9];
    const float* b1_in  = (const float*)d_in[10];
    const float* Wp2    = (const float*)d_in[11];
    const float* bp2    = (const float*)d_in[12];
    const float* W2_in  = (const float*)d_in[13];
    const float* b2_in  = (const float*)d_in[14];
    const float* W1_out = (const float*)d_in[15];
    const float* b1_out = (const float*)d_in[16];
    const float* W0_out = (const float*)d_in[17];
    const float* b0_out = (const float*)d_in[18];

    float* out   = (float*)d_out;
    float* predo = out + OUT_PRED;
    float* s1o   = out + OUT_S1;
    float* losso = out + OUT_LOSS;
    float* adj1o = out + OUT_ADJ1;

    float* wsf = (float*)d_ws;
    int*   wsi = (int*)d_ws;
    float* deg   = wsf + OFF_DEG;
    int*   cntc  = wsi + OFF_CNTC;
    int*   cntr  = wsi + OFF_CNTR;
    float* scal  = wsf + OFF_SCAL;
    int*   cptr  = wsi + OFF_COLPTR;
    int*   rptr  = wsi + OFF_ROWPTR;
    int*   curc  = wsi + OFF_CURC;
    int*   curr  = wsi + OFF_CURR;
    int*   colr  = wsi + OFF_COLR;
    float* coln  = wsf + OFF_COLN;
    int*   rowc  = wsi + OFF_ROWC;
    float* roww  = wsf + OFF_ROWW;
    float* dinv  = wsf + OFF_DINV;
    float* x0_   = wsf + OFF_X0;
    unsigned short* h0b   = (unsigned short*)(wsf + OFF_H0);
    unsigned short* Sb    = (unsigned short*)(wsf + OFF_S);
    unsigned short* TT    = (unsigned short*)(wsf + OFF_TT2);
    unsigned short* AN1TB = (unsigned short*)(wsf + OFF_AN1TB);
    unsigned short* ADJ1B = (unsigned short*)(wsf + OFF_ADJ1B);
    unsigned short* HAT   = (unsigned short*)(wsf + OFF_HAT);
    unsigned short* HBT   = (unsigned short*)(wsf + OFF_HBT);
    unsigned short* HCATT = (unsigned short*)(wsf + OFF_HCATT);
    unsigned short* S2ST  = (unsigned short*)(wsf + OFF_S2ST);
    unsigned short* ST    = (unsigned short*)(wsf + OFF_ST);
    unsigned short* TBF   = (unsigned short*)(wsf + OFF_TBF);
    unsigned short* WP1T  = (unsigned short*)(wsf + OFF_WP1T);
    unsigned short* X0T   = (unsigned short*)(wsf + OFF_X0T);
    unsigned short* x0b   = (unsigned short*)(wsf + OFF_X0B);
    float* PADJ  = wsf + OFF_PADJ;
    float* PG    = wsf + OFF_PG;
    float* PP    = wsf + OFF_PP;
    float* PX1   = wsf + OFF_PX1;
    float* x1    = wsf + OFF_X1;
    float* y16   = wsf + OFF_Y16;
    float* x1_   = wsf + OFF_X1_;
    float* s2    = wsf + OFF_S2;
    float* S2s   = wsf + OFF_S2S;
    float* u     = wsf + OFF_U;
    float* x2    = wsf + OFF_X2;
    float* adj2  = wsf + OFF_ADJ2;
    float* hC    = wsf + OFF_HC;
    float* x2_   = wsf + OFF_X2_;
    float* an2   = wsf + OFF_AN2;
    float* z2    = wsf + OFF_Z2;
    float* hcat  = wsf + OFF_HCAT;
    float* x1o_  = wsf + OFF_X1O;
    float* p16   = wsf + OFF_P16;
    float* di1   = wsf + OFF_DI1;
    float* df1   = wsf + OFF_DF1;
    float* di2   = wsf + OFF_DI2;
    float* df2   = wsf + OFF_DF2;
    float* cspart = wsf + OFF_CURC;

    const int* row = eidx;
    const int* col = eidx + E;

    hipMemsetAsync(wsf, 0, (size_t)ZERO_FLOATS * sizeof(float), stream);

    // --- graph structure ---
    k_hist<<<E / 256, 256, 0, stream>>>(row, col, ew, E, deg, cntc, cntr, &scal[3]);
    k_scan<<<1, 1024, 0, stream>>>(cntc, cntr, cptr, rptr, curc, curr, N, E, deg, dinv);
    k_scatter<<<E / 256, 256, 0, stream>>>(row, col, ew, E, dinv, curc, curr, colr, coln, rowc, roww);

    // --- level 0 GCN ---
    gemm_ab_b16<<<dim3(2, 128), 256, 0, stream>>>(x0, W0_in, h0b, 8192, 128, 128);
    k_agg_b16<<<N, 64, 0, stream>>>(h0b, x0_, x0b, cptr, colr, coln, dinv, b0_in, 1);

    // --- s1 = relu((M^T x0_)@Wp1 + bp1) ---
    k_agg_b16<<<N, 64, 0, stream>>>(x0b, nullptr, h0b, cptr, colr, coln, dinv, nullptr, 0);
    k_transpose_f2b<<<dim3(16, 2), 256, 0, stream>>>(Wp1, WP1T, 128, 1024, nullptr);
    gemm_tn_bf16_store<<<dim3(64, 8), 256, 0, stream>>>(h0b, WP1T, s1o, 8192, 1024, 128, bp1, 1);

    // --- diff_pool level 1 ---
    k_softmax1024<<<N, 256, 0, stream>>>(s1o, Sb, mask, &scal[0]);
    k_spmm_seg<<<dim3(N / 4, 8), 256, 0, stream>>>(Sb, rptr, rowc, roww, TBF);
    k_transpose_b2b2<<<dim3(16, 128, 2), 256, 0, stream>>>(Sb, ST, TBF, TT, 8192, 1024);
    k_transpose_f2b<<<dim3(2, 128), 256, 0, stream>>>(x0_, X0T, 8192, 128, mask);

    // merged: adj1 = ST@TT^T, G = ST@ST^T, x1 = ST@X0T^T  (split-K z=8)
    gemm_tn_bf16_part3<<<dim3(8, 17, 8), 256, 0, stream>>>(ST, TT, ST, X0T, PADJ, PG, PX1, 8192);
    k_reduce4<<<1024, 256, 0, stream>>>(PADJ, adj1o, ADJ1B, 1024 * 1024, 8, &scal[4]);
    k_reduce4<<<1024, 256, 0, stream>>>(PG, nullptr, nullptr, 1024 * 1024, 8, &scal[2]);
    k_reduce4<<<128, 256, 0, stream>>>(PX1, x1, nullptr, 1024 * 128, 8, nullptr);

    // --- a_norm for adj1 (bf16 transposed only) + cross = tr(adj1) ---
    k_colsum_part<<<dim3(4, 16), 256, 0, stream>>>(adj1o, 1024, cspart);
    k_dfix_part<<<4, 256, 0, stream>>>(adj1o, 1024, cspart, 16, di1, df1, &scal[1]);
    k_anorm_tb<<<dim3(16, 16), 256, 0, stream>>>(adj1o, 1024, di1, df1, AN1TB);

    // --- level 1 dense GCNs (MFMA, K=1024, split-K z=16) ---
    gemm_ab32_bt<<<dim3(4, 32), 256, 0, stream>>>(x1, W1_in, HAT, 1024, 128, 128);
    gemm_tn_bf16_part<<<dim3(8, 1, 16), 256, 0, stream>>>(AN1TB, HAT, PP, 1024, 128, 1024);
    k_reduce_br<<<128, 256, 0, stream>>>(PP, x1_, 1024 * 128, 128, 16, b1_in, 1);
    gemm_ab32_bt<<<dim3(4, 32), 256, 0, stream>>>(x1_, Wp2, HBT, 1024, 128, 128);
    gemm_tn_bf16_part<<<dim3(8, 1, 16), 256, 0, stream>>>(AN1TB, HBT, PP, 1024, 128, 1024);
    k_reduce_br<<<128, 256, 0, stream>>>(PP, s2, 1024 * 128, 128, 16, bp2, 1);

    // --- diff_pool level 2 ---
    k_softmax_ent<<<1024, 256, 0, stream>>>(s2, S2s, 128, nullptr, &scal[5]);
    k_transpose_f2b<<<dim3(2, 16), 256, 0, stream>>>(S2s, S2ST, 1024, 128, nullptr);
    gemm_tn_bf16_part<<<dim3(8, 1, 16), 256, 0, stream>>>(ADJ1B, S2ST, PP, 1024, 128, 1024);
    k_reduce_br<<<128, 256, 0, stream>>>(PP, u, 1024 * 128, 128, 16, nullptr, 0);
    // fused: x2 = S2s^T@x1_, adj2 = S2s^T@u, g2b = ||S2s^T@S2s||^2
    k_atb32_3<<<dim3(4, 4, 3), 256, 0, stream>>>(S2s, x1_, u, S2s, x2, adj2, &scal[7], 128, 128, 1024);

    // --- a_norm for adj2 (+cross2 = tr(adj2)), level 2 GCN ---
    k_coldfix128<<<1, 128, 0, stream>>>(adj2, di2, df2, &scal[6]);
    k_anorm<<<64, 256, 0, stream>>>(adj2, 128, di2, df2, an2);
    gemm_ab32<<<dim3(4, 4), 256, 0, stream>>>(x2, W2_in, hC, 128, 128, 128, nullptr, 0, 0);
    gemm_atb32<<<dim3(4, 4), 256, 0, stream>>>(an2, hC, x2_, 128, 128, 128, b2_in, 1, nullptr);

    // --- unpool to level 1: hcat = x1_@W1o1 + s2@z2; x1o_ via MFMA ---
    gemm_ab32<<<dim3(4, 4), 256, 0, stream>>>(x2_, W1_out + 128 * 128, z2, 128, 128, 128, nullptr, 0, 0);
    gemm_ab32<<<dim3(4, 32), 256, 0, stream>>>(x1_, W1_out, hcat, 1024, 128, 128, nullptr, 0, 0);
    gemm_ab32<<<dim3(4, 32), 256, 0, stream>>>(s2, z2, hcat, 1024, 128, 128, nullptr, 0, 1);
    k_transpose_f2b<<<dim3(2, 16), 256, 0, stream>>>(hcat, HCATT, 1024, 128, nullptr);
    gemm_tn_bf16_part<<<dim3(8, 1, 16), 256, 0, stream>>>(AN1TB, HCATT, PP, 1024, 128, 1024);
    k_reduce_br<<<128, 256, 0, stream>>>(PP, x1o_, 1024 * 128, 128, 16, b1_out, 1);

    // --- unpool to level 0: p16 = x0_@W0out1 + s1o@(x1o_@W0out2) ---
    k_gemm_n16<<<64, 256, 0, stream>>>(x1o_, W0_out + 128 * 16, y16, 1024, 128, 0);
    k_gemm_n16<<<512, 256, 0, stream>>>(x0_, W0_out, p16, 8192, 128, 0);
    k_gemm_n16<<<512, 256, 0, stream>>>(s1o, y16, p16, 8192, 1024, 1);
    k_agg16_ls<<<512, 256, 0, stream>>>(p16, predo, cptr, colr, coln, dinv, b0_out);

    k_finalize<<<1, 64, 0, stream>>>(scal, losso);
}

// Round 2
// 945.845 us; speedup vs baseline: 1.2366x; 1.0228x over previous
//
#include <hip/hip_runtime.h>
#include <math.h>

// ---------------------------------------------------------------------------
// DiffPool GNN (N=8192, E=262144, F=H=128, C1=1024, C2=128, NC=16).
// R11: global_load_lds(16B) staging w/ pre-swizzled source in all MFMA gemms;
//      fusions: reduce4x3->1, colsum+dfix->1, anorm folded into atb gemm,
//      hcat dual-gemm writes bf16^T directly, p16 dual-K gemm; spmm 4-pass.
// ---------------------------------------------------------------------------

#define N_NODES 8192
#define N_EDGES 262144

typedef __attribute__((ext_vector_type(8))) short short8;
typedef __attribute__((ext_vector_type(4))) float floatx4;

// ---------------- workspace layout (float-slot offsets, 16-aligned) ----------------
#define OFF_DEG     0           // 8192  (zeroed)
#define OFF_CNTC    8192        // 8192  (zeroed)
#define OFF_CNTR    16384       // 8192  (zeroed)
#define OFF_SCAL    24576       // 16 (zeroed) [0]=e1 [1]=cross(tr adj1) [2]=g2 [3]=sumA2
                                //             [4]=ss_adj1 [5]=e2 [6]=cross2(tr adj2) [7]=g2b
#define ZERO_FLOATS 24592
#define OFF_COLPTR  24592       // 8193
#define OFF_ROWPTR  32785       // 8193
#define OFF_CURC    40978       // 8192
#define OFF_CURR    49170       // 8192
#define OFF_COLR    57362       // E (int)
#define OFF_COLN    319506      // E
#define OFF_ROWC    581650      // E (int)
#define OFF_ROWW    843794      // E
#define OFF_DINV    1105938     // 8192
#define OFF_X0      1114144     // 8192*128 fp32 (x0_)
#define OFF_H0      2162720     // h0b bf16 [8192][128]
// Region A (4M slots at OFF_S: Sb -> {an1Tb, adj1b, hats...}):
#define OFF_S       3211296     // Sb bf16 [8192][1024]
#define OFF_AN1TB   OFF_S                 // bf16 [1024][1024] (after Sb dead)
#define OFF_ADJ1B   (OFF_S+524288)        // bf16 [1024][1024]
#define OFF_HAT     (OFF_S+1048576)       // bf16 [128][1024]
#define OFF_HBT     (OFF_S+1114112)       // bf16 [128][1024]
#define OFF_HCATT   (OFF_S+1179648)       // bf16 [128][1024]
#define OFF_S2ST    (OFF_S+1245184)       // bf16 [128][1024]
#define OFF_X0T     7405600     // bf16 [128][8192]
#define OFF_X0B     7929888     // bf16 [8192][128]
#define A2          8454176
#define OFF_X1      (A2+0)            // 1024*128
#define OFF_Y16     (A2+131072)       // 1024*16
#define OFF_X1_     (A2+262144)       // 1024*128
#define OFF_S2      (A2+524288)       // 1024*128
#define OFF_S2S     (A2+655360)       // 1024*128
#define OFF_U       (A2+786432)       // 1024*128
#define OFF_X2      (A2+917504)       // 128*128
#define OFF_ADJ2    (A2+933888)
#define OFF_HC      (A2+950272)
#define OFF_X2_     (A2+966656)
#define OFF_Z2      (A2+999424)       // 128*128
#define OFF_X1O     (A2+1261568)      // 1024*128
#define OFF_P16     (A2+1392640)      // 8192*16
#define OFF_DI1     (A2+1654784)      // 1024
#define OFF_DF1     (A2+1655808)
#define OFF_DI2     (A2+1656832)      // 128
#define OFF_DF2     (A2+1656960)
// Region B:
#define OFF_ST      10111264          // S_T bf16 [1024][8192]
#define OFF_TBF     14305568          // t bf16 [8192][1024]; WP1T aliases; later PADJ
#define OFF_WP1T    OFF_TBF
#define OFF_PADJ    OFF_TBF           // fp32 [8][1024][1024]
#define OFF_PG      22694176          // fp32 [8][1024][1024]; later PP fp32 [16][1024][128]
#define OFF_PP      OFF_PG
#define OFF_PX1     31082784          // fp32 [8][1024][128]
#define OFF_TT2     32131360          // TT bf16 [8192][1024]
// total: 36,325,664 float-slots = 138.6 MiB

// ------------------- output layout (floats) -------------------
#define OUT_PRED 0          // 8192*16
#define OUT_S1   131072     // 8192*1024
#define OUT_LOSS 8519680    // 1
#define OUT_ADJ1 8519681    // 1024*1024

__device__ __forceinline__ unsigned short f2bf(float f) {
    union { float f; unsigned u; } v; v.f = f;
    unsigned r = (v.u + 0x7FFF + ((v.u >> 16) & 1)) >> 16;
    return (unsigned short)r;
}
__device__ __forceinline__ float bf2f(unsigned short b) {
    union { unsigned u; float f; } v; v.u = (unsigned)b << 16; return v.f;
}
// async global->LDS 16B (wave-uniform LDS base + lane*16)
__device__ __forceinline__ void gl_lds16(const unsigned short* g, unsigned short* l) {
    __builtin_amdgcn_global_load_lds(
        (const __attribute__((address_space(1))) void*)g,
        (__attribute__((address_space(3))) void*)l, 16, 0, 0);
}

// =========================== graph-structure kernels ===========================

__global__ void k_hist(const int* __restrict__ row, const int* __restrict__ col,
                       const float* __restrict__ ew, int E,
                       float* deg, int* cntc, int* cntr, float* sumA2) {
    __shared__ float red[256];
    int e = blockIdx.x * 256 + threadIdx.x;
    float w2 = 0.f;
    if (e < E) {
        int r = row[e], c = col[e];
        float w = ew[e];
        atomicAdd(&deg[c], w);
        atomicAdd(&cntc[c], 1);
        atomicAdd(&cntr[r], 1);
        w2 = w * w;
    }
    red[threadIdx.x] = w2; __syncthreads();
    for (int s = 128; s > 0; s >>= 1) { if (threadIdx.x < s) red[threadIdx.x] += red[threadIdx.x + s]; __syncthreads(); }
    if (threadIdx.x == 0) atomicAdd(sumA2, red[0]);
}

__global__ __launch_bounds__(1024) void k_scan(const int* cntc, const int* cntr,
        int* colptr, int* rowptr, int* curc, int* curr, int n, int E,
        const float* __restrict__ deg, float* __restrict__ dinv) {
    __shared__ int part[1024];
    int tid = threadIdx.x;
    const int per = 8;
    for (int pass = 0; pass < 2; ++pass) {
        const int* cnt = pass ? cntr : cntc;
        int* ptr = pass ? rowptr : colptr;
        int* cur = pass ? curr : curc;
        int st = tid * per;
        int loc[per]; int s = 0;
        for (int i = 0; i < per; ++i) { loc[i] = s; s += cnt[st + i]; }
        part[tid] = s; __syncthreads();
        for (int off = 1; off < 1024; off <<= 1) {
            int v = part[tid];
            int add = (tid >= off) ? part[tid - off] : 0;
            __syncthreads();
            part[tid] = v + add;
            __syncthreads();
        }
        int pre = (tid == 0) ? 0 : part[tid - 1];
        for (int i = 0; i < per; ++i) { int v = pre + loc[i]; ptr[st + i] = v; cur[st + i] = v; }
        if (tid == 0) ptr[n] = E;
        __syncthreads();
    }
    for (int i = tid; i < n; i += 1024) {
        float d = deg[i] + 1.0f;
        dinv[i] = (d > 0.f) ? 1.0f / sqrtf(d) : 0.f;
    }
}

__global__ void k_scatter(const int* __restrict__ row, const int* __restrict__ col,
                          const float* __restrict__ ew, int E, const float* __restrict__ dinv,
                          int* curc, int* curr, int* colr, float* coln, int* rowc, float* roww) {
    int e = blockIdx.x * 256 + threadIdx.x;
    if (e >= E) return;
    int r = row[e], c = col[e];
    float w = ew[e];
    float nrm = dinv[r] * w * dinv[c];
    int p = atomicAdd(&curc[c], 1);
    colr[p] = r; coln[p] = nrm;
    int q = atomicAdd(&curr[r], 1);
    rowc[q] = c; roww[q] = w;
}

// =========================== fp32 GEMMs ===========================

__global__ __launch_bounds__(256) void gemm_ab_b16(const float* __restrict__ A, const float* __restrict__ B,
        unsigned short* __restrict__ C, int M, int N, int K) {
    __shared__ float As[16][68];
    __shared__ float Bs[16][68];
    int tid = threadIdx.x, tx = tid & 15, ty = tid >> 4;
    int m0 = blockIdx.y * 64, n0 = blockIdx.x * 64;
    float acc[4][4] = {};
    for (int k0 = 0; k0 < K; k0 += 16) {
        for (int l = 0; l < 4; ++l) {
            int idx = tid + 256 * l;
            int mm = idx >> 4, kk = idx & 15;
            As[kk][mm] = A[(size_t)(m0 + mm) * K + k0 + kk];
            int kk2 = idx >> 6, nn = idx & 63;
            Bs[kk2][nn] = B[(size_t)(k0 + kk2) * N + n0 + nn];
        }
        __syncthreads();
        #pragma unroll
        for (int kk = 0; kk < 16; ++kk) {
            float a[4], b[4];
            #pragma unroll
            for (int i = 0; i < 4; ++i) a[i] = As[kk][ty * 4 + i];
            #pragma unroll
            for (int j = 0; j < 4; ++j) b[j] = Bs[kk][tx * 4 + j];
            #pragma unroll
            for (int i = 0; i < 4; ++i)
                #pragma unroll
                for (int j = 0; j < 4; ++j) acc[i][j] += a[i] * b[j];
        }
        __syncthreads();
    }
    for (int i = 0; i < 4; ++i)
        for (int j = 0; j < 4; ++j)
            C[(size_t)(m0 + ty * 4 + i) * N + n0 + tx * 4 + j] = f2bf(acc[i][j]);
}

// 32x32 tile, C = A@B (+bias/relu/accum), fp32 out
__global__ __launch_bounds__(256) void gemm_ab32(const float* __restrict__ A, const float* __restrict__ B,
        float* __restrict__ C, int M, int N, int K,
        const float* __restrict__ bias, int relu, int accum) {
    __shared__ float As[32][33];
    __shared__ float Bs[32][33];
    int tid = threadIdx.x, tx = tid & 15, ty = tid >> 4;
    int m0 = blockIdx.y * 32, n0 = blockIdx.x * 32;
    float acc[2][2] = {};
    for (int k0 = 0; k0 < K; k0 += 32) {
        #pragma unroll
        for (int l = 0; l < 4; ++l) {
            int idx = tid + 256 * l;
            int r = idx >> 5, c = idx & 31;
            As[r][c] = A[(size_t)(m0 + r) * K + k0 + c];
            Bs[r][c] = B[(size_t)(k0 + r) * N + n0 + c];
        }
        __syncthreads();
        #pragma unroll
        for (int kk = 0; kk < 32; ++kk) {
            float a0 = As[ty * 2][kk], a1 = As[ty * 2 + 1][kk];
            float b0 = Bs[kk][tx * 2], b1 = Bs[kk][tx * 2 + 1];
            acc[0][0] += a0 * b0; acc[0][1] += a0 * b1;
            acc[1][0] += a1 * b0; acc[1][1] += a1 * b1;
        }
        __syncthreads();
    }
    #pragma unroll
    for (int i = 0; i < 2; ++i)
        #pragma unroll
        for (int j = 0; j < 2; ++j) {
            int m = m0 + ty * 2 + i, n = n0 + tx * 2 + j;
            float v = acc[i][j];
            if (accum) v += C[(size_t)m * N + n];
            if (bias) v += bias[n];
            if (relu) v = fmaxf(v, 0.f);
            C[(size_t)m * N + n] = v;
        }
}

// 32x32 tile: CT[N][M] bf16 = (A@B)^T, single-source
__global__ __launch_bounds__(256) void gemm_ab32_bt(const float* __restrict__ A,
        const float* __restrict__ B, unsigned short* __restrict__ CT, int M, int N, int K) {
    __shared__ float As[32][33];
    __shared__ float Bs[32][33];
    int tid = threadIdx.x, tx = tid & 15, ty = tid >> 4;
    int m0 = blockIdx.y * 32, n0 = blockIdx.x * 32;
    float acc[2][2] = {};
    for (int k0 = 0; k0 < K; k0 += 32) {
        #pragma unroll
        for (int l = 0; l < 4; ++l) {
            int idx = tid + 256 * l;
            int r = idx >> 5, c = idx & 31;
            As[r][c] = A[(size_t)(m0 + r) * K + k0 + c];
            Bs[r][c] = B[(size_t)(k0 + r) * N + n0 + c];
        }
        __syncthreads();
        #pragma unroll
        for (int kk = 0; kk < 32; ++kk) {
            float a0 = As[ty * 2][kk], a1 = As[ty * 2 + 1][kk];
            float b0 = Bs[kk][tx * 2], b1 = Bs[kk][tx * 2 + 1];
            acc[0][0] += a0 * b0; acc[0][1] += a0 * b1;
            acc[1][0] += a1 * b0; acc[1][1] += a1 * b1;
        }
        __syncthreads();
    }
    #pragma unroll
    for (int i = 0; i < 2; ++i)
        #pragma unroll
        for (int j = 0; j < 2; ++j)
            As[ty * 2 + i][tx * 2 + j] = acc[i][j];
    __syncthreads();
    int nl = tid >> 3, moff = (tid & 7) * 4;
    ushort4 o;
    o.x = f2bf(As[moff + 0][nl]);
    o.y = f2bf(As[moff + 1][nl]);
    o.z = f2bf(As[moff + 2][nl]);
    o.w = f2bf(As[moff + 3][nl]);
    *(ushort4*)(CT + (size_t)(n0 + nl) * M + m0 + moff) = o;
}

// dual-source: CT[N][M] bf16 = (A0@B0 + A1@B1)^T  (both K=Kc)
__global__ __launch_bounds__(256) void gemm_dual_bt(const float* __restrict__ A0,
        const float* __restrict__ B0, const float* __restrict__ A1, const float* __restrict__ B1,
        unsigned short* __restrict__ CT, int M, int N, int Kc) {
    __shared__ float As[32][33];
    __shared__ float Bs[32][33];
    int tid = threadIdx.x, tx = tid & 15, ty = tid >> 4;
    int m0 = blockIdx.y * 32, n0 = blockIdx.x * 32;
    float acc[2][2] = {};
    for (int src = 0; src < 2; ++src) {
        const float* A = src ? A1 : A0;
        const float* B = src ? B1 : B0;
        for (int k0 = 0; k0 < Kc; k0 += 32) {
            #pragma unroll
            for (int l = 0; l < 4; ++l) {
                int idx = tid + 256 * l;
                int r = idx >> 5, c = idx & 31;
                As[r][c] = A[(size_t)(m0 + r) * Kc + k0 + c];
                Bs[r][c] = B[(size_t)(k0 + r) * N + n0 + c];
            }
            __syncthreads();
            #pragma unroll
            for (int kk = 0; kk < 32; ++kk) {
                float a0 = As[ty * 2][kk], a1 = As[ty * 2 + 1][kk];
                float b0 = Bs[kk][tx * 2], b1 = Bs[kk][tx * 2 + 1];
                acc[0][0] += a0 * b0; acc[0][1] += a0 * b1;
                acc[1][0] += a1 * b0; acc[1][1] += a1 * b1;
            }
            __syncthreads();
        }
    }
    #pragma unroll
    for (int i = 0; i < 2; ++i)
        #pragma unroll
        for (int j = 0; j < 2; ++j)
            As[ty * 2 + i][tx * 2 + j] = acc[i][j];
    __syncthreads();
    int nl = tid >> 3, moff = (tid & 7) * 4;
    ushort4 o;
    o.x = f2bf(As[moff + 0][nl]);
    o.y = f2bf(As[moff + 1][nl]);
    o.z = f2bf(As[moff + 2][nl]);
    o.w = f2bf(As[moff + 3][nl]);
    *(ushort4*)(CT + (size_t)(n0 + nl) * M + m0 + moff) = o;
}

// 32x32 tile, C = relu(mscale[m] * (sum_k kscale[k]*(A[k][m]+(k==m)*dfix[m])*B[k][n]) + bias[n])
__global__ __launch_bounds__(256) void gemm_atb32n(const float* __restrict__ A, const float* __restrict__ B,
        float* __restrict__ C, int M, int N, int K,
        const float* __restrict__ bias, const float* __restrict__ kscale,
        const float* __restrict__ dfixv, const float* __restrict__ mscale) {
    __shared__ float As[32][33];
    __shared__ float Bs[32][33];
    int tid = threadIdx.x, tx = tid & 15, ty = tid >> 4;
    int m0 = blockIdx.y * 32, n0 = blockIdx.x * 32;
    float acc[2][2] = {};
    for (int k0 = 0; k0 < K; k0 += 32) {
        #pragma unroll
        for (int l = 0; l < 4; ++l) {
            int idx = tid + 256 * l;
            int r = idx >> 5, c = idx & 31;
            int k = k0 + r, m = m0 + c;
            float v = A[(size_t)k * M + m];
            if (k == m) v += dfixv[m];
            As[c][r] = v * kscale[k];
            Bs[r][c] = B[(size_t)k * N + n0 + c];
        }
        __syncthreads();
        #pragma unroll
        for (int kk = 0; kk < 32; ++kk) {
            float a0 = As[ty * 2][kk], a1 = As[ty * 2 + 1][kk];
            float b0 = Bs[kk][tx * 2], b1 = Bs[kk][tx * 2 + 1];
            acc[0][0] += a0 * b0; acc[0][1] += a0 * b1;
            acc[1][0] += a1 * b0; acc[1][1] += a1 * b1;
        }
        __syncthreads();
    }
    #pragma unroll
    for (int i = 0; i < 2; ++i)
        #pragma unroll
        for (int j = 0; j < 2; ++j) {
            int m = m0 + ty * 2 + i, n = n0 + tx * 2 + j;
            float v = acc[i][j] * mscale[m] + bias[n];
            C[(size_t)m * N + n] = fmaxf(v, 0.f);
        }
}

// fused 3x (A^T@B) sharing A=S2s: op0 C0=A^T@B0, op1 C1=A^T@B1, op2 sumsq(A^T@B2)
__global__ __launch_bounds__(256) void k_atb32_3(const float* __restrict__ A,
        const float* __restrict__ B0, const float* __restrict__ B1, const float* __restrict__ B2,
        float* __restrict__ C0, float* __restrict__ C1, float* ss_acc,
        int M, int N, int K) {
    __shared__ float As[32][33];
    __shared__ float Bs[32][33];
    __shared__ float red[256];
    int op = blockIdx.z;
    const float* B = (op == 0) ? B0 : (op == 1) ? B1 : B2;
    int tid = threadIdx.x, tx = tid & 15, ty = tid >> 4;
    int m0 = blockIdx.y * 32, n0 = blockIdx.x * 32;
    float acc[2][2] = {};
    for (int k0 = 0; k0 < K; k0 += 32) {
        #pragma unroll
        for (int l = 0; l < 4; ++l) {
            int idx = tid + 256 * l;
            int r = idx >> 5, c = idx & 31;
            As[c][r] = A[(size_t)(k0 + r) * M + m0 + c];
            Bs[r][c] = B[(size_t)(k0 + r) * N + n0 + c];
        }
        __syncthreads();
        #pragma unroll
        for (int kk = 0; kk < 32; ++kk) {
            float a0 = As[ty * 2][kk], a1 = As[ty * 2 + 1][kk];
            float b0 = Bs[kk][tx * 2], b1 = Bs[kk][tx * 2 + 1];
            acc[0][0] += a0 * b0; acc[0][1] += a0 * b1;
            acc[1][0] += a1 * b0; acc[1][1] += a1 * b1;
        }
        __syncthreads();
    }
    if (op == 2) {
        float ss = acc[0][0] * acc[0][0] + acc[0][1] * acc[0][1]
                 + acc[1][0] * acc[1][0] + acc[1][1] * acc[1][1];
        red[tid] = ss; __syncthreads();
        for (int s = 128; s > 0; s >>= 1) { if (tid < s) red[tid] += red[tid + s]; __syncthreads(); }
        if (tid == 0) atomicAdd(ss_acc, red[0]);
        return;
    }
    float* C = (op == 0) ? C0 : C1;
    #pragma unroll
    for (int i = 0; i < 2; ++i)
        #pragma unroll
        for (int j = 0; j < 2; ++j)
            C[(size_t)(m0 + ty * 2 + i) * N + n0 + tx * 2 + j] = acc[i][j];
}

// C[M][16] (+)= A[M][K] @ B[K][16]
__global__ __launch_bounds__(256) void k_gemm_n16(const float* __restrict__ A, const float* __restrict__ B,
        float* __restrict__ C, int M, int K, int accum) {
    __shared__ float As[16][64];
    __shared__ float Bs[64][16];
    int tid = threadIdx.x;
    int r = tid >> 4, c = tid & 15;
    int m0 = blockIdx.x * 16;
    float acc = 0.f;
    for (int k0 = 0; k0 < K; k0 += 64) {
        #pragma unroll
        for (int l = 0; l < 4; ++l) {
            int idx = tid + 256 * l;
            int rr = idx >> 6, cc = idx & 63;
            As[rr][cc] = A[(size_t)(m0 + rr) * K + k0 + cc];
            int kk = idx >> 4, c2 = idx & 15;
            Bs[kk][c2] = B[(size_t)(k0 + kk) * 16 + c2];
        }
        __syncthreads();
        #pragma unroll 16
        for (int kk = 0; kk < 64; ++kk) acc += As[r][kk] * Bs[kk][c];
        __syncthreads();
    }
    float* p = &C[(size_t)(m0 + r) * 16 + c];
    if (accum) acc += *p;
    *p = acc;
}

// C[M][16] = A0[M][K0]@B0 + A1[M][K1]@B1
__global__ __launch_bounds__(256) void k_gemm_n16_dual(
        const float* __restrict__ A0, int K0, const float* __restrict__ B0,
        const float* __restrict__ A1, int K1, const float* __restrict__ B1,
        float* __restrict__ C, int M) {
    __shared__ float As[16][64];
    __shared__ float Bs[64][16];
    int tid = threadIdx.x;
    int r = tid >> 4, c = tid & 15;
    int m0 = blockIdx.x * 16;
    float acc = 0.f;
    for (int src = 0; src < 2; ++src) {
        const float* A = src ? A1 : A0;
        const float* B = src ? B1 : B0;
        int K = src ? K1 : K0;
        for (int k0 = 0; k0 < K; k0 += 64) {
            #pragma unroll
            for (int l = 0; l < 4; ++l) {
                int idx = tid + 256 * l;
                int rr = idx >> 6, cc = idx & 63;
                As[rr][cc] = A[(size_t)(m0 + rr) * K + k0 + cc];
                int kk = idx >> 4, c2 = idx & 15;
                Bs[kk][c2] = B[(size_t)(k0 + kk) * 16 + c2];
            }
            __syncthreads();
            #pragma unroll 16
            for (int kk = 0; kk < 64; ++kk) acc += As[r][kk] * Bs[kk][c];
            __syncthreads();
        }
    }
    C[(size_t)(m0 + r) * 16 + c] = acc;
}

// =========================== bf16 MFMA GEMMs ===========================
// staging: global_load_lds 16B, linear LDS dest, source col pre-swizzled
// (XOR involution: phys (row,c) holds logical (row, c ^ ((row&7)*8)))

// split-K partial store: P[z][M][N] = partial of sum_k A[m][k]*B[n][k]
__global__ __launch_bounds__(256) void gemm_tn_bf16_part(
        const unsigned short* __restrict__ A, const unsigned short* __restrict__ B,
        float* __restrict__ P, int M, int N, int K) {
    __shared__ __align__(16) unsigned short As[128 * 64];
    __shared__ __align__(16) unsigned short Bs[128 * 64];
    int tid = threadIdx.x;
    int wave = tid >> 6, lane = tid & 63;
    int wm = wave >> 1, wn = wave & 1;
    int m0 = blockIdx.x * 128, n0 = blockIdx.y * 128;
    int kchunk = K / gridDim.z;
    int k0 = blockIdx.z * kchunk;
    float* Pz = P + (size_t)blockIdx.z * M * N;
    floatx4 acc[4][4] = {};
    int q = lane >> 4, lm = lane & 15;
    int lrow = lane >> 3, lcol = (lane & 7) * 8;
    for (int kt = 0; kt < kchunk; kt += 64) {
        int gk0 = k0 + kt;
        #pragma unroll
        for (int p = 0; p < 4; ++p) {
            int rbase = wave * 32 + p * 8;
            int row = rbase + lrow;
            int scol = lcol ^ ((row & 7) * 8);
            gl_lds16(&A[(size_t)(m0 + row) * K + gk0 + scol], &As[rbase * 64]);
            gl_lds16(&B[(size_t)(n0 + row) * K + gk0 + scol], &Bs[rbase * 64]);
        }
        __syncthreads();
        #pragma unroll
        for (int ks = 0; ks < 64; ks += 32) {
            short8 af[4], bf[4];
            int kk = ks + q * 8;
            #pragma unroll
            for (int i = 0; i < 4; ++i) {
                int ml = wm * 64 + i * 16 + lm;
                af[i] = *(const short8*)(&As[ml * 64 + (kk ^ ((ml & 7) * 8))]);
                int nl = wn * 64 + i * 16 + lm;
                bf[i] = *(const short8*)(&Bs[nl * 64 + (kk ^ ((nl & 7) * 8))]);
            }
            #pragma unroll
            for (int i = 0; i < 4; ++i)
                #pragma unroll
                for (int j = 0; j < 4; ++j)
                    acc[i][j] = __builtin_amdgcn_mfma_f32_16x16x32_bf16(af[i], bf[j], acc[i][j], 0, 0, 0);
        }
        __syncthreads();
    }
    for (int i = 0; i < 4; ++i) {
        int rowb = m0 + wm * 64 + i * 16 + q * 4;
        for (int j = 0; j < 4; ++j) {
            int col = n0 + wn * 64 + j * 16 + lm;
            #pragma unroll
            for (int r = 0; r < 4; ++r)
                Pz[(size_t)(rowb + r) * N + col] = acc[i][j][r];
        }
    }
}

// merged K=8192 split-K GEMM: grid (8, 17, 8). A=ST [1024][8192].
__global__ __launch_bounds__(256) void gemm_tn_bf16_part3(
        const unsigned short* __restrict__ A,
        const unsigned short* __restrict__ B0, const unsigned short* __restrict__ B1,
        const unsigned short* __restrict__ B2,
        float* __restrict__ P0, float* __restrict__ P1, float* __restrict__ P2,
        int K) {
    __shared__ __align__(16) unsigned short As[128 * 64];
    __shared__ __align__(16) unsigned short Bs[128 * 64];
    int tid = threadIdx.x;
    int wave = tid >> 6, lane = tid & 63;
    int wm = wave >> 1, wn = wave & 1;
    int by = blockIdx.y;
    const unsigned short* B; float* P; int N, n0;
    if (by < 8)       { B = B0; P = P0; N = 1024; n0 = by * 128; }
    else if (by < 16) { B = B1; P = P1; N = 1024; n0 = (by - 8) * 128; }
    else              { B = B2; P = P2; N = 128;  n0 = 0; }
    int m0 = blockIdx.x * 128;
    int kchunk = K / gridDim.z;
    int k0 = blockIdx.z * kchunk;
    float* Pz = P + (size_t)blockIdx.z * 1024 * N;
    floatx4 acc[4][4] = {};
    int q = lane >> 4, lm = lane & 15;
    int lrow = lane >> 3, lcol = (lane & 7) * 8;
    for (int kt = 0; kt < kchunk; kt += 64) {
        int gk0 = k0 + kt;
        #pragma unroll
        for (int p = 0; p < 4; ++p) {
            int rbase = wave * 32 + p * 8;
            int row = rbase + lrow;
            int scol = lcol ^ ((row & 7) * 8);
            gl_lds16(&A[(size_t)(m0 + row) * K + gk0 + scol], &As[rbase * 64]);
            gl_lds16(&B[(size_t)(n0 + row) * K + gk0 + scol], &Bs[rbase * 64]);
        }
        __syncthreads();
        #pragma unroll
        for (int ks = 0; ks < 64; ks += 32) {
            short8 af[4], bf[4];
            int kk = ks + q * 8;
            #pragma unroll
            for (int i = 0; i < 4; ++i) {
                int ml = wm * 64 + i * 16 + lm;
                af[i] = *(const short8*)(&As[ml * 64 + (kk ^ ((ml & 7) * 8))]);
                int nl = wn * 64 + i * 16 + lm;
                bf[i] = *(const short8*)(&Bs[nl * 64 + (kk ^ ((nl & 7) * 8))]);
            }
            #pragma unroll
            for (int i = 0; i < 4; ++i)
                #pragma unroll
                for (int j = 0; j < 4; ++j)
                    acc[i][j] = __builtin_amdgcn_mfma_f32_16x16x32_bf16(af[i], bf[j], acc[i][j], 0, 0, 0);
        }
        __syncthreads();
    }
    for (int i = 0; i < 4; ++i) {
        int rowb = m0 + wm * 64 + i * 16 + q * 4;
        for (int j = 0; j < 4; ++j) {
            int col = n0 + wn * 64 + j * 16 + lm;
            #pragma unroll
            for (int r = 0; r < 4; ++r)
                Pz[(size_t)(rowb + r) * N + col] = acc[i][j][r];
        }
    }
}

// full-K store with bias+relu (s1o)
__global__ __launch_bounds__(256) void gemm_tn_bf16_store(
        const unsigned short* __restrict__ A, const unsigned short* __restrict__ B,
        float* __restrict__ C, int M, int N, int K,
        const float* __restrict__ bias, int relu) {
    __shared__ __align__(16) unsigned short As[128 * 64];
    __shared__ __align__(16) unsigned short Bs[128 * 64];
    int tid = threadIdx.x;
    int wave = tid >> 6, lane = tid & 63;
    int wm = wave >> 1, wn = wave & 1;
    int m0 = blockIdx.x * 128, n0 = blockIdx.y * 128;
    floatx4 acc[4][4] = {};
    int q = lane >> 4, lm = lane & 15;
    int lrow = lane >> 3, lcol = (lane & 7) * 8;
    for (int kt = 0; kt < K; kt += 64) {
        #pragma unroll
        for (int p = 0; p < 4; ++p) {
            int rbase = wave * 32 + p * 8;
            int row = rbase + lrow;
            int scol = lcol ^ ((row & 7) * 8);
            gl_lds16(&A[(size_t)(m0 + row) * K + kt + scol], &As[rbase * 64]);
            gl_lds16(&B[(size_t)(n0 + row) * K + kt + scol], &Bs[rbase * 64]);
        }
        __syncthreads();
        #pragma unroll
        for (int ks = 0; ks < 64; ks += 32) {
            short8 af[4], bf[4];
            int kk = ks + q * 8;
            #pragma unroll
            for (int i = 0; i < 4; ++i) {
                int ml = wm * 64 + i * 16 + lm;
                af[i] = *(const short8*)(&As[ml * 64 + (kk ^ ((ml & 7) * 8))]);
                int nl = wn * 64 + i * 16 + lm;
                bf[i] = *(const short8*)(&Bs[nl * 64 + (kk ^ ((nl & 7) * 8))]);
            }
            #pragma unroll
            for (int i = 0; i < 4; ++i)
                #pragma unroll
                for (int j = 0; j < 4; ++j)
                    acc[i][j] = __builtin_amdgcn_mfma_f32_16x16x32_bf16(af[i], bf[j], acc[i][j], 0, 0, 0);
        }
        __syncthreads();
    }
    for (int i = 0; i < 4; ++i) {
        int rowb = m0 + wm * 64 + i * 16 + q * 4;
        for (int j = 0; j < 4; ++j) {
            int col = n0 + wn * 64 + j * 16 + lm;
            float bv = bias ? bias[col] : 0.f;
            #pragma unroll
            for (int r = 0; r < 4; ++r) {
                float v = acc[i][j][r] + bv;
                if (relu) v = fmaxf(v, 0.f);
                C[(size_t)(rowb + r) * N + col] = v;
            }
        }
    }
}

// merged reduction of the 3 split-K partial sets (nsplit=8)
__global__ __launch_bounds__(256) void k_reduce3m(
        const float* __restrict__ P0, float* __restrict__ C0, unsigned short* __restrict__ Cb0, float* ss0,
        const float* __restrict__ P1, float* ss1,
        const float* __restrict__ P2, float* __restrict__ C2) {
    __shared__ float red[256];
    const float* P; float* C; unsigned short* Cb; float* ss; int n;
    if (blockIdx.y == 0)      { P = P0; C = C0;      Cb = Cb0;     ss = ss0;     n = 1024 * 1024; }
    else if (blockIdx.y == 1) { P = P1; C = nullptr; Cb = nullptr; ss = ss1;     n = 1024 * 1024; }
    else                      { P = P2; C = C2;      Cb = nullptr; ss = nullptr; n = 1024 * 128; }
    float ssv = 0.f;
    for (int i4 = (blockIdx.x * 256 + threadIdx.x) * 4; i4 < n; i4 += gridDim.x * 256 * 4) {
        float4 v = *(const float4*)(P + i4);
        #pragma unroll
        for (int s = 1; s < 8; ++s) {
            float4 w = *(const float4*)(P + (size_t)s * n + i4);
            v.x += w.x; v.y += w.y; v.z += w.z; v.w += w.w;
        }
        if (C) *(float4*)(C + i4) = v;
        if (Cb) {
            ushort4 o; o.x = f2bf(v.x); o.y = f2bf(v.y); o.z = f2bf(v.z); o.w = f2bf(v.w);
            *(ushort4*)(Cb + i4) = o;
        }
        ssv += v.x * v.x + v.y * v.y + v.z * v.z + v.w * v.w;
    }
    if (!ss) return;
    red[threadIdx.x] = ssv; __syncthreads();
    for (int s = 128; s > 0; s >>= 1) { if (threadIdx.x < s) red[threadIdx.x] += red[threadIdx.x + s]; __syncthreads(); }
    if (threadIdx.x == 0) atomicAdd(ss, red[0]);
}

// reduce nsplit partials [ns][M][N] -> C fp32 with bias (len N) + relu
__global__ __launch_bounds__(256) void k_reduce_br(const float* __restrict__ P,
        float* __restrict__ C, int n, int N, int nsplit,
        const float* __restrict__ bias, int relu) {
    for (int i4 = (blockIdx.x * 256 + threadIdx.x) * 4; i4 < n; i4 += gridDim.x * 256 * 4) {
        float4 v = *(const float4*)(P + i4);
        for (int s = 1; s < nsplit; ++s) {
            float4 w = *(const float4*)(P + (size_t)s * n + i4);
            v.x += w.x; v.y += w.y; v.z += w.z; v.w += w.w;
        }
        if (bias) {
            float4 b = *(const float4*)(bias + (i4 % N));
            v.x += b.x; v.y += b.y; v.z += b.z; v.w += b.w;
        }
        if (relu) {
            v.x = fmaxf(v.x, 0.f); v.y = fmaxf(v.y, 0.f);
            v.z = fmaxf(v.z, 0.f); v.w = fmaxf(v.w, 0.f);
        }
        *(float4*)(C + i4) = v;
    }
}

// =========================== transposes ===========================

__global__ __launch_bounds__(256) void k_transpose_f2b(
        const float* __restrict__ in, unsigned short* __restrict__ outb,
        int R, int C, const float* __restrict__ rowscale) {
    __shared__ float tile[64][65];
    int rb = blockIdx.y * 64, cb = blockIdx.x * 64;
    int t = threadIdx.x;
    int lr = t >> 4, lc4 = (t & 15) * 4;
    #pragma unroll
    for (int p = 0; p < 4; ++p) {
        int r = rb + lr + p * 16;
        float4 v = *(const float4*)(in + (size_t)r * C + cb + lc4);
        float s = rowscale ? rowscale[r] : 1.0f;
        tile[lr + p * 16][lc4 + 0] = v.x * s;
        tile[lr + p * 16][lc4 + 1] = v.y * s;
        tile[lr + p * 16][lc4 + 2] = v.z * s;
        tile[lr + p * 16][lc4 + 3] = v.w * s;
    }
    __syncthreads();
    int cc0 = t >> 5, rr = (t & 31) * 2;
    #pragma unroll
    for (int p = 0; p < 8; ++p) {
        int cc = cc0 + p * 8;
        unsigned a = f2bf(tile[rr][cc]);
        unsigned b = f2bf(tile[rr + 1][cc]);
        *(unsigned*)(outb + (size_t)(cb + cc) * R + rb + rr) = a | (b << 16);
    }
}

// dual bf16 transpose: blockIdx.z selects (in0->out0) or (in1->out1)
__global__ __launch_bounds__(256) void k_transpose_b2b2(
        const unsigned short* __restrict__ in0, unsigned short* __restrict__ out0,
        const unsigned short* __restrict__ in1, unsigned short* __restrict__ out1,
        int R, int C) {
    __shared__ __align__(16) unsigned short tile[64][72];
    const unsigned short* in = blockIdx.z ? in1 : in0;
    unsigned short* out = blockIdx.z ? out1 : out0;
    int rb = blockIdx.y * 64, cb = blockIdx.x * 64;
    int t = threadIdx.x;
    int lr = t >> 3, lc = (t & 7) * 8;
    #pragma unroll
    for (int p = 0; p < 2; ++p) {
        int r = lr + p * 32;
        *(short8*)(&tile[r][lc]) = *(const short8*)(&in[(size_t)(rb + r) * C + cb + lc]);
    }
    __syncthreads();
    int cc0 = t >> 4, rr = (t & 15) * 4;
    #pragma unroll
    for (int p = 0; p < 4; ++p) {
        int cc = cc0 + p * 16;
        unsigned long long v = (unsigned long long)tile[rr][cc]
                             | ((unsigned long long)tile[rr + 1][cc] << 16)
                             | ((unsigned long long)tile[rr + 2][cc] << 32)
                             | ((unsigned long long)tile[rr + 3][cc] << 48);
        *(unsigned long long*)(&out[(size_t)(cb + cc) * R + rb + rr]) = v;
    }
}

// an1Tb[j][i] = bf16( dinv[i]*(adj1[i][j] + (i==j)*dfix[i])*dinv[j] )
__global__ __launch_bounds__(256) void k_anorm_tb(const float* __restrict__ adjm, int n,
        const float* __restrict__ dinvv, const float* __restrict__ dfix,
        unsigned short* __restrict__ outb) {
    __shared__ float tile[64][65];
    int rb = blockIdx.y * 64, cb = blockIdx.x * 64;
    int t = threadIdx.x;
    int lr = t >> 4, lc4 = (t & 15) * 4;
    #pragma unroll
    for (int p = 0; p < 4; ++p) {
        int i = rb + lr + p * 16;
        float4 v = *(const float4*)(adjm + (size_t)i * n + cb + lc4);
        float di = dinvv[i];
        float vv[4] = {v.x, v.y, v.z, v.w};
        #pragma unroll
        for (int q = 0; q < 4; ++q) {
            int j = cb + lc4 + q;
            float val = vv[q];
            if (i == j) val += dfix[i];
            tile[lr + p * 16][lc4 + q] = di * val * dinvv[j];
        }
    }
    __syncthreads();
    int cc0 = t >> 5, rr = (t & 31) * 2;
    #pragma unroll
    for (int p = 0; p < 8; ++p) {
        int cc = cc0 + p * 8;
        unsigned a = f2bf(tile[rr][cc]);
        unsigned b = f2bf(tile[rr + 1][cc]);
        *(unsigned*)(outb + (size_t)(cb + cc) * n + rb + rr) = a | (b << 16);
    }
}

// =========================== aggregation / misc ===========================

__global__ __launch_bounds__(64) void k_agg_b16(const unsigned short* __restrict__ h,
        float* __restrict__ out, unsigned short* __restrict__ outb,
        const int* __restrict__ cptr, const int* __restrict__ colr,
        const float* __restrict__ coln, const float* __restrict__ dinv,
        const float* __restrict__ bias, int relu) {
    int c = blockIdx.x, t = threadIdx.x;
    int f0 = t * 2;
    float d = dinv[c], dd = d * d;
    const unsigned short* hf = h + f0;
    unsigned u = *(const unsigned*)(hf + (size_t)c * 128);
    float a0 = dd * bf2f((unsigned short)(u & 0xffff));
    float a1 = dd * bf2f((unsigned short)(u >> 16));
    int e0 = cptr[c], e1 = cptr[c + 1];
    int e = e0;
    for (; e + 4 <= e1; e += 4) {
        int r0 = colr[e], r1 = colr[e + 1], r2 = colr[e + 2], r3 = colr[e + 3];
        float w0 = coln[e], w1 = coln[e + 1], w2 = coln[e + 2], w3 = coln[e + 3];
        unsigned v0 = *(const unsigned*)(hf + (size_t)r0 * 128);
        unsigned v1 = *(const unsigned*)(hf + (size_t)r1 * 128);
        unsigned v2 = *(const unsigned*)(hf + (size_t)r2 * 128);
        unsigned v3 = *(const unsigned*)(hf + (size_t)r3 * 128);
        a0 += w0 * bf2f((unsigned short)(v0 & 0xffff)) + w1 * bf2f((unsigned short)(v1 & 0xffff))
            + w2 * bf2f((unsigned short)(v2 & 0xffff)) + w3 * bf2f((unsigned short)(v3 & 0xffff));
        a1 += w0 * bf2f((unsigned short)(v0 >> 16)) + w1 * bf2f((unsigned short)(v1 >> 16))
            + w2 * bf2f((unsigned short)(v2 >> 16)) + w3 * bf2f((unsigned short)(v3 >> 16));
    }
    for (; e < e1; ++e) {
        float w = coln[e];
        unsigned v = *(const unsigned*)(hf + (size_t)colr[e] * 128);
        a0 += w * bf2f((unsigned short)(v & 0xffff));
        a1 += w * bf2f((unsigned short)(v >> 16));
    }
    if (bias) { a0 += bias[f0]; a1 += bias[f0 + 1]; }
    if (relu) { a0 = fmaxf(a0, 0.f); a1 = fmaxf(a1, 0.f); }
    if (out) { out[(size_t)c * 128 + f0] = a0; out[(size_t)c * 128 + f0 + 1] = a1; }
    if (outb) {
        unsigned o = (unsigned)f2bf(a0) | ((unsigned)f2bf(a1) << 16);
        *(unsigned*)(outb + (size_t)c * 128 + f0) = o;
    }
}

// F=16 agg + fused log_softmax (16-lane groups), writes prediction directly
__global__ __launch_bounds__(256) void k_agg16_ls(const float* __restrict__ h, float* __restrict__ pred,
        const int* __restrict__ cptr, const int* __restrict__ colr,
        const float* __restrict__ coln, const float* __restrict__ dinv,
        const float* __restrict__ bias) {
    int node = blockIdx.x * 16 + (threadIdx.x >> 4);
    int f = threadIdx.x & 15;
    float d = dinv[node];
    const float* hf = h + f;
    float acc = d * d * hf[(size_t)node * 16];
    int e0 = cptr[node], e1 = cptr[node + 1];
    int e = e0;
    for (; e + 4 <= e1; e += 4) {
        int r0 = colr[e], r1 = colr[e + 1], r2 = colr[e + 2], r3 = colr[e + 3];
        float w0 = coln[e], w1 = coln[e + 1], w2 = coln[e + 2], w3 = coln[e + 3];
        float v0 = hf[(size_t)r0 * 16], v1 = hf[(size_t)r1 * 16];
        float v2 = hf[(size_t)r2 * 16], v3 = hf[(size_t)r3 * 16];
        acc += w0 * v0 + w1 * v1 + w2 * v2 + w3 * v3;
    }
    for (; e < e1; ++e)
        acc += coln[e] * hf[(size_t)colr[e] * 16];
    acc += bias[f];
    acc = fmaxf(acc, 0.f);
    float m = acc;
    #pragma unroll
    for (int off = 1; off < 16; off <<= 1) m = fmaxf(m, __shfl_xor(m, off, 16));
    float ex = expf(acc - m);
    float s = ex;
    #pragma unroll
    for (int off = 1; off < 16; off <<= 1) s += __shfl_xor(s, off, 16);
    pred[(size_t)node * 16 + f] = acc - m - logf(s);
}

__global__ __launch_bounds__(256) void k_softmax1024(const float* __restrict__ x,
        unsigned short* __restrict__ Sb, const float* __restrict__ mask, float* ent_acc) {
    __shared__ float red[256];
    int r = blockIdx.x, tid = threadIdx.x;
    const float* xr = x + (size_t)r * 1024;
    float4 v = *(const float4*)(xr + tid * 4);
    float m = fmaxf(fmaxf(v.x, v.y), fmaxf(v.z, v.w));
    red[tid] = m; __syncthreads();
    for (int s = 128; s > 0; s >>= 1) { if (tid < s) red[tid] = fmaxf(red[tid], red[tid + s]); __syncthreads(); }
    m = red[0]; __syncthreads();
    float e0 = expf(v.x - m), e1 = expf(v.y - m), e2 = expf(v.z - m), e3 = expf(v.w - m);
    red[tid] = e0 + e1 + e2 + e3; __syncthreads();
    for (int s = 128; s > 0; s >>= 1) { if (tid < s) red[tid] += red[tid + s]; __syncthreads(); }
    float inv = 1.0f / red[0]; __syncthreads();
    float mk = mask ? mask[r] : 1.0f;
    float s0 = e0 * inv * mk, s1 = e1 * inv * mk, s2 = e2 * inv * mk, s3 = e3 * inv * mk;
    float ent = -(s0 * logf(s0 + 1e-15f) + s1 * logf(s1 + 1e-15f)
                + s2 * logf(s2 + 1e-15f) + s3 * logf(s3 + 1e-15f));
    ushort4 o;
    o.x = f2bf(s0); o.y = f2bf(s1); o.z = f2bf(s2); o.w = f2bf(s3);
    *(ushort4*)(Sb + (size_t)r * 1024 + tid * 4) = o;
    red[tid] = ent; __syncthreads();
    for (int s = 128; s > 0; s >>= 1) { if (tid < s) red[tid] += red[tid + s]; __syncthreads(); }
    if (tid == 0) atomicAdd(ent_acc, red[0]);
}

__global__ __launch_bounds__(256) void k_softmax_ent(const float* __restrict__ x, float* __restrict__ S,
        int W, const float* __restrict__ mask, float* ent_acc) {
    __shared__ float red[256];
    int row = blockIdx.x, tid = threadIdx.x;
    const float* xr = x + (size_t)row * W;
    float m = -3.0e38f;
    for (int q = tid; q < W; q += 256) m = fmaxf(m, xr[q]);
    red[tid] = m; __syncthreads();
    for (int s = 128; s > 0; s >>= 1) { if (tid < s) red[tid] = fmaxf(red[tid], red[tid + s]); __syncthreads(); }
    m = red[0]; __syncthreads();
    float sum = 0.f;
    for (int q = tid; q < W; q += 256) sum += expf(xr[q] - m);
    red[tid] = sum; __syncthreads();
    for (int s = 128; s > 0; s >>= 1) { if (tid < s) red[tid] += red[tid + s]; __syncthreads(); }
    float inv = 1.0f / red[0]; __syncthreads();
    float mk = mask ? mask[row] : 1.0f;
    float* Sr = S + (size_t)row * W;
    float ent = 0.f;
    for (int q = tid; q < W; q += 256) {
        float v = expf(xr[q] - m) * inv * mk;
        Sr[q] = v;
        ent -= v * logf(v + 1e-15f);
    }
    red[tid] = ent; __syncthreads();
    for (int s = 128; s > 0; s >>= 1) { if (tid < s) red[tid] += red[tid + s]; __syncthreads(); }
    if (tid == 0) atomicAdd(ent_acc, red[0]);
}

// L2-segmented SpMM, 4 waves/block = 4 rows, pass p = cols [p*256, p*256+256)
__global__ __launch_bounds__(256) void k_spmm_seg(const unsigned short* __restrict__ Sb,
        const int* __restrict__ rptr, const int* __restrict__ rowc, const float* __restrict__ roww,
        unsigned short* __restrict__ tb) {
    int wave = threadIdx.x >> 6, lane = threadIdx.x & 63;
    int r = blockIdx.x * 4 + wave;
    int j0 = blockIdx.y * 256 + lane * 4;
    const unsigned short* Sj = Sb + j0;
    float a0 = 0.f, a1 = 0.f, a2 = 0.f, a3 = 0.f;
    int e0 = rptr[r], e1 = rptr[r + 1];
    int e = e0;
    for (; e + 4 <= e1; e += 4) {
        int c0 = rowc[e], c1 = rowc[e + 1], c2 = rowc[e + 2], c3 = rowc[e + 3];
        float w0 = roww[e], w1 = roww[e + 1], w2 = roww[e + 2], w3 = roww[e + 3];
        uint2 v0 = *(const uint2*)(Sj + (size_t)c0 * 1024);
        uint2 v1 = *(const uint2*)(Sj + (size_t)c1 * 1024);
        uint2 v2 = *(const uint2*)(Sj + (size_t)c2 * 1024);
        uint2 v3 = *(const uint2*)(Sj + (size_t)c3 * 1024);
        a0 += w0 * bf2f((unsigned short)(v0.x & 0xffff)) + w1 * bf2f((unsigned short)(v1.x & 0xffff))
            + w2 * bf2f((unsigned short)(v2.x & 0xffff)) + w3 * bf2f((unsigned short)(v3.x & 0xffff));
        a1 += w0 * bf2f((unsigned short)(v0.x >> 16)) + w1 * bf2f((unsigned short)(v1.x >> 16))
            + w2 * bf2f((unsigned short)(v2.x >> 16)) + w3 * bf2f((unsigned short)(v3.x >> 16));
        a2 += w0 * bf2f((unsigned short)(v0.y & 0xffff)) + w1 * bf2f((unsigned short)(v1.y & 0xffff))
            + w2 * bf2f((unsigned short)(v2.y & 0xffff)) + w3 * bf2f((unsigned short)(v3.y & 0xffff));
        a3 += w0 * bf2f((unsigned short)(v0.y >> 16)) + w1 * bf2f((unsigned short)(v1.y >> 16))
            + w2 * bf2f((unsigned short)(v2.y >> 16)) + w3 * bf2f((unsigned short)(v3.y >> 16));
    }
    for (; e < e1; ++e) {
        int c = rowc[e]; float w = roww[e];
        uint2 v = *(const uint2*)(Sj + (size_t)c * 1024);
        a0 += w * bf2f((unsigned short)(v.x & 0xffff));
        a1 += w * bf2f((unsigned short)(v.x >> 16));
        a2 += w * bf2f((unsigned short)(v.y & 0xffff));
        a3 += w * bf2f((unsigned short)(v.y >> 16));
    }
    unsigned lo = (unsigned)f2bf(a0) | ((unsigned)f2bf(a1) << 16);
    unsigned hi = (unsigned)f2bf(a2) | ((unsigned)f2bf(a3) << 16);
    unsigned long long o = (unsigned long long)lo | ((unsigned long long)hi << 32);
    *(unsigned long long*)(tb + (size_t)r * 1024 + j0) = o;
}

// fused colsum + dfix + dinv + trace for n=1024 (16 blocks x 64 cols)
__global__ __launch_bounds__(256) void k_coldfix1024(const float* __restrict__ adjm,
        float* dinvv, float* dfix, float* cross_acc) {
    __shared__ float part[4][64];
    __shared__ float red[256];
    int jl = threadIdx.x & 63;
    int j = blockIdx.x * 64 + jl;
    int rg = threadIdx.x >> 6;
    float s = 0.f;
    for (int r = rg * 256; r < rg * 256 + 256; ++r)
        s += adjm[(size_t)r * 1024 + j];
    part[rg][jl] = s;
    __syncthreads();
    float diag = 0.f;
    if (rg == 0) {
        float tot = part[0][jl] + part[1][jl] + part[2][jl] + part[3][jl];
        diag = adjm[(size_t)j * 1024 + j];
        float fix = (diag == 0.f) ? 1.0f : 0.f;
        tot += fix;
        dfix[j] = fix;
        dinvv[j] = (tot > 0.f) ? 1.0f / sqrtf(tot) : 0.f;
    }
    red[threadIdx.x] = diag; __syncthreads();
    for (int st = 128; st > 0; st >>= 1) { if (threadIdx.x < st) red[threadIdx.x] += red[threadIdx.x + st]; __syncthreads(); }
    if (threadIdx.x == 0) atomicAdd(cross_acc, red[0]);
}

// fused colsum+dfix for n=128 + cross2 = trace(adj2)
__global__ __launch_bounds__(128) void k_coldfix128(const float* __restrict__ adjm,
        float* dinvv, float* dfix, float* cross2_out) {
    __shared__ float red[128];
    int j = threadIdx.x;
    float s = 0.f;
    for (int i = 0; i < 128; ++i) s += adjm[(size_t)i * 128 + j];
    float diag = adjm[(size_t)j * 128 + j];
    float fix = (diag == 0.f) ? 1.0f : 0.f;
    s += fix;
    dfix[j] = fix;
    dinvv[j] = (s > 0.f) ? 1.0f / sqrtf(s) : 0.f;
    red[j] = diag; __syncthreads();
    for (int st = 64; st > 0; st >>= 1) { if (j < st) red[j] += red[j + st]; __syncthreads(); }
    if (j == 0) *cross2_out = red[0];
}

__global__ void k_finalize(const float* __restrict__ sc, float* loss) {
    if (threadIdx.x == 0 && blockIdx.x == 0) {
        float e1     = sc[0] / 8192.0f;
        float cross  = sc[1];
        float g2     = sc[2];
        float sumA2  = sc[3];
        float ssadj1 = sc[4];
        float e2     = sc[5] / 1024.0f;
        float cross2 = sc[6];
        float g2b    = sc[7];
        float l1 = sqrtf(fmaxf(sumA2 - 2.0f * cross + g2, 0.f)) / 67108864.0f;
        float l2 = sqrtf(fmaxf(ssadj1 - 2.0f * cross2 + g2b, 0.f)) / 1048576.0f;
        *loss = l1 + e1 + l2 + e2;
    }
}

// =========================== launcher ===========================

extern "C" void kernel_launch(void* const* d_in, const int* in_sizes, int n_in,
                              void* d_out, int out_size, void* d_ws, size_t ws_size,
                              hipStream_t stream) {
    const int N = N_NODES, E = N_EDGES;
    const float* x0     = (const float*)d_in[0];
    const int*   eidx   = (const int*)d_in[1];
    const float* ew     = (const float*)d_in[2];
    const float* mask   = (const float*)d_in[4];
    const float* W0_in  = (const float*)d_in[5];
    const float* b0_in  = (const float*)d_in[6];
    const float* Wp1    = (const float*)d_in[7];
    const float* bp1    = (const float*)d_in[8];
    const float* W1_in  = (const float*)d_in[9];
    const float* b1_in  = (const float*)d_in[10];
    const float* Wp2    = (const float*)d_in[11];
    const float* bp2    = (const float*)d_in[12];
    const float* W2_in  = (const float*)d_in[13];
    const float* b2_in  = (const float*)d_in[14];
    const float* W1_out = (const float*)d_in[15];
    const float* b1_out = (const float*)d_in[16];
    const float* W0_out = (const float*)d_in[17];
    const float* b0_out = (const float*)d_in[18];

    float* out   = (float*)d_out;
    float* predo = out + OUT_PRED;
    float* s1o   = out + OUT_S1;
    float* losso = out + OUT_LOSS;
    float* adj1o = out + OUT_ADJ1;

    float* wsf = (float*)d_ws;
    int*   wsi = (int*)d_ws;
    float* deg   = wsf + OFF_DEG;
    int*   cntc  = wsi + OFF_CNTC;
    int*   cntr  = wsi + OFF_CNTR;
    float* scal  = wsf + OFF_SCAL;
    int*   cptr  = wsi + OFF_COLPTR;
    int*   rptr  = wsi + OFF_ROWPTR;
    int*   curc  = wsi + OFF_CURC;
    int*   curr  = wsi + OFF_CURR;
    int*   colr  = wsi + OFF_COLR;
    float* coln  = wsf + OFF_COLN;
    int*   rowc  = wsi + OFF_ROWC;
    float* roww  = wsf + OFF_ROWW;
    float* dinv  = wsf + OFF_DINV;
    float* x0_   = wsf + OFF_X0;
    unsigned short* h0b   = (unsigned short*)(wsf + OFF_H0);
    unsigned short* Sb    = (unsigned short*)(wsf + OFF_S);
    unsigned short* TT    = (unsigned short*)(wsf + OFF_TT2);
    unsigned short* AN1TB = (unsigned short*)(wsf + OFF_AN1TB);
    unsigned short* ADJ1B = (unsigned short*)(wsf + OFF_ADJ1B);
    unsigned short* HAT   = (unsigned short*)(wsf + OFF_HAT);
    unsigned short* HBT   = (unsigned short*)(wsf + OFF_HBT);
    unsigned short* HCATT = (unsigned short*)(wsf + OFF_HCATT);
    unsigned short* S2ST  = (unsigned short*)(wsf + OFF_S2ST);
    unsigned short* ST    = (unsigned short*)(wsf + OFF_ST);
    unsigned short* TBF   = (unsigned short*)(wsf + OFF_TBF);
    unsigned short* WP1T  = (unsigned short*)(wsf + OFF_WP1T);
    unsigned short* X0T   = (unsigned short*)(wsf + OFF_X0T);
    unsigned short* x0b   = (unsigned short*)(wsf + OFF_X0B);
    float* PADJ  = wsf + OFF_PADJ;
    float* PG    = wsf + OFF_PG;
    float* PP    = wsf + OFF_PP;
    float* PX1   = wsf + OFF_PX1;
    float* x1    = wsf + OFF_X1;
    float* y16   = wsf + OFF_Y16;
    float* x1_   = wsf + OFF_X1_;
    float* s2    = wsf + OFF_S2;
    float* S2s   = wsf + OFF_S2S;
    float* u     = wsf + OFF_U;
    float* x2    = wsf + OFF_X2;
    float* adj2  = wsf + OFF_ADJ2;
    float* hC    = wsf + OFF_HC;
    float* x2_   = wsf + OFF_X2_;
    float* z2    = wsf + OFF_Z2;
    float* x1o_  = wsf + OFF_X1O;
    float* p16   = wsf + OFF_P16;
    float* di1   = wsf + OFF_DI1;
    float* df1   = wsf + OFF_DF1;
    float* di2   = wsf + OFF_DI2;
    float* df2   = wsf + OFF_DF2;

    const int* row = eidx;
    const int* col = eidx + E;

    hipMemsetAsync(wsf, 0, (size_t)ZERO_FLOATS * sizeof(float), stream);

    // --- graph structure ---
    k_hist<<<E / 256, 256, 0, stream>>>(row, col, ew, E, deg, cntc, cntr, &scal[3]);
    k_scan<<<1, 1024, 0, stream>>>(cntc, cntr, cptr, rptr, curc, curr, N, E, deg, dinv);
    k_scatter<<<E / 256, 256, 0, stream>>>(row, col, ew, E, dinv, curc, curr, colr, coln, rowc, roww);

    // --- level 0 GCN ---
    gemm_ab_b16<<<dim3(2, 128), 256, 0, stream>>>(x0, W0_in, h0b, 8192, 128, 128);
    k_agg_b16<<<N, 64, 0, stream>>>(h0b, x0_, x0b, cptr, colr, coln, dinv, b0_in, 1);

    // --- s1 = relu((M^T x0_)@Wp1 + bp1) ---
    k_agg_b16<<<N, 64, 0, stream>>>(x0b, nullptr, h0b, cptr, colr, coln, dinv, nullptr, 0);
    k_transpose_f2b<<<dim3(16, 2), 256, 0, stream>>>(Wp1, WP1T, 128, 1024, nullptr);
    gemm_tn_bf16_store<<<dim3(64, 8), 256, 0, stream>>>(h0b, WP1T, s1o, 8192, 1024, 128, bp1, 1);

    // --- diff_pool level 1 ---
    k_softmax1024<<<N, 256, 0, stream>>>(s1o, Sb, mask, &scal[0]);
    k_spmm_seg<<<dim3(N / 4, 4), 256, 0, stream>>>(Sb, rptr, rowc, roww, TBF);
    k_transpose_b2b2<<<dim3(16, 128, 2), 256, 0, stream>>>(Sb, ST, TBF, TT, 8192, 1024);
    k_transpose_f2b<<<dim3(2, 128), 256, 0, stream>>>(x0_, X0T, 8192, 128, mask);

    // merged: adj1 = ST@TT^T, G = ST@ST^T, x1 = ST@X0T^T  (split-K z=8)
    gemm_tn_bf16_part3<<<dim3(8, 17, 8), 256, 0, stream>>>(ST, TT, ST, X0T, PADJ, PG, PX1, 8192);
    k_reduce3m<<<dim3(1024, 3), 256, 0, stream>>>(PADJ, adj1o, ADJ1B, &scal[4], PG, &scal[2], PX1, x1);

    // --- a_norm for adj1 (bf16 transposed only) + cross = tr(adj1) ---
    k_coldfix1024<<<16, 256, 0, stream>>>(adj1o, di1, df1, &scal[1]);
    k_anorm_tb<<<dim3(16, 16), 256, 0, stream>>>(adj1o, 1024, di1, df1, AN1TB);

    // --- level 1 dense GCNs (MFMA, K=1024, split-K z=16) ---
    gemm_ab32_bt<<<dim3(4, 32), 256, 0, stream>>>(x1, W1_in, HAT, 1024, 128, 128);
    gemm_tn_bf16_part<<<dim3(8, 1, 16), 256, 0, stream>>>(AN1TB, HAT, PP, 1024, 128, 1024);
    k_reduce_br<<<128, 256, 0, stream>>>(PP, x1_, 1024 * 128, 128, 16, b1_in, 1);
    gemm_ab32_bt<<<dim3(4, 32), 256, 0, stream>>>(x1_, Wp2, HBT, 1024, 128, 128);
    gemm_tn_bf16_part<<<dim3(8, 1, 16), 256, 0, stream>>>(AN1TB, HBT, PP, 1024, 128, 1024);
    k_reduce_br<<<128, 256, 0, stream>>>(PP, s2, 1024 * 128, 128, 16, bp2, 1);

    // --- diff_pool level 2 ---
    k_softmax_ent<<<1024, 256, 0, stream>>>(s2, S2s, 128, nullptr, &scal[5]);
    k_transpose_f2b<<<dim3(2, 16), 256, 0, stream>>>(S2s, S2ST, 1024, 128, nullptr);
    gemm_tn_bf16_part<<<dim3(8, 1, 16), 256, 0, stream>>>(ADJ1B, S2ST, PP, 1024, 128, 1024);
    k_reduce_br<<<128, 256, 0, stream>>>(PP, u, 1024 * 128, 128, 16, nullptr, 0);
    // fused: x2 = S2s^T@x1_, adj2 = S2s^T@u, g2b = ||S2s^T@S2s||^2
    k_atb32_3<<<dim3(4, 4, 3), 256, 0, stream>>>(S2s, x1_, u, S2s, x2, adj2, &scal[7], 128, 128, 1024);

    // --- a_norm for adj2 folded into GCN (+cross2 = tr(adj2)) ---
    k_coldfix128<<<1, 128, 0, stream>>>(adj2, di2, df2, &scal[6]);
    gemm_ab32<<<dim3(4, 4), 256, 0, stream>>>(x2, W2_in, hC, 128, 128, 128, nullptr, 0, 0);
    gemm_atb32n<<<dim3(4, 4), 256, 0, stream>>>(adj2, hC, x2_, 128, 128, 128, b2_in, di2, df2, di2);

    // --- unpool to level 1: HCATT = (x1_@W1o1 + s2@z2)^T bf16, x1o_ via MFMA ---
    gemm_ab32<<<dim3(4, 4), 256, 0, stream>>>(x2_, W1_out + 128 * 128, z2, 128, 128, 128, nullptr, 0, 0);
    gemm_dual_bt<<<dim3(4, 32), 256, 0, stream>>>(x1_, W1_out, s2, z2, HCATT, 1024, 128, 128);
    gemm_tn_bf16_part<<<dim3(8, 1, 16), 256, 0, stream>>>(AN1TB, HCATT, PP, 1024, 128, 1024);
    k_reduce_br<<<128, 256, 0, stream>>>(PP, x1o_, 1024 * 128, 128, 16, b1_out, 1);

    // --- unpool to level 0: p16 = x0_@W0out1 + s1o@(x1o_@W0out2) ---
    k_gemm_n16<<<64, 256, 0, stream>>>(x1o_, W0_out + 128 * 16, y16, 1024, 128, 0);
    k_gemm_n16_dual<<<512, 256, 0, stream>>>(x0_, 128, W0_out, s1o, 1024, y16, p16, 8192);
    k_agg16_ls<<<512, 256, 0, stream>>>(p16, predo, cptr, colr, coln, dinv, b0_out);

    k_finalize<<<1, 64, 0, stream>>>(scal, losso);
}

// Round 3
// 895.220 us; speedup vs baseline: 1.3066x; 1.0566x over previous
//
#include <hip/hip_runtime.h>
#include <math.h>

// ---------------------------------------------------------------------------
// DiffPool GNN (N=8192, E=262144, F=H=128, C1=1024, C2=128, NC=16).
// R12: big-GEMM restructure: tile-list grid (adj1 64 + G-upper 36 + x1 8),
//      z=4 tile-contiguous partials; G computed triangular-only (norm only);
//      reduce fuses colsum/diag/trace; K=1024 chains -> single-launch n128
//      full-K MFMA gemm with fused bias+relu (kills 4 part+reduce pairs).
// ---------------------------------------------------------------------------

#define N_NODES 8192
#define N_EDGES 262144

typedef __attribute__((ext_vector_type(8))) short short8;
typedef __attribute__((ext_vector_type(4))) float floatx4;

// ---------------- workspace layout (float-slot offsets, 16-aligned) ----------------
#define OFF_DEG     0           // 8192  (zeroed)
#define OFF_CNTC    8192        // 8192  (zeroed)
#define OFF_CNTR    16384       // 8192  (zeroed)
#define OFF_SCAL    24576       // 16 (zeroed) [0]=e1 [1]=cross(tr adj1) [2]=g2 [3]=sumA2
                                //             [4]=ss_adj1 [5]=e2 [6]=cross2(tr adj2) [7]=g2b
#define ZERO_FLOATS 24592
#define OFF_COLPTR  24592       // 8193
#define OFF_ROWPTR  32785       // 8193
#define OFF_CURC    40978       // 8192
#define OFF_CURR    49170       // 8192
#define OFF_COLR    57362       // E (int)
#define OFF_COLN    319506      // E
#define OFF_ROWC    581650      // E (int)
#define OFF_ROWW    843794      // E
#define OFF_DINV    1105938     // 8192
#define OFF_X0      1114144     // 8192*128 fp32 (x0_)
#define OFF_H0      2162720     // h0b bf16 [8192][128]
// Region A (4M slots at OFF_S: Sb -> {an1Tb, adj1b, hats...}):
#define OFF_S       3211296     // Sb bf16 [8192][1024]
#define OFF_AN1TB   OFF_S                 // bf16 [1024][1024] (after Sb dead)
#define OFF_ADJ1B   (OFF_S+524288)        // bf16 [1024][1024]
#define OFF_HAT     (OFF_S+1048576)       // bf16 [128][1024]
#define OFF_HBT     (OFF_S+1114112)       // bf16 [128][1024]
#define OFF_HCATT   (OFF_S+1179648)       // bf16 [128][1024]
#define OFF_S2ST    (OFF_S+1245184)       // bf16 [128][1024]
#define OFF_X0T     7405600     // bf16 [128][8192]
#define OFF_X0B     7929888     // bf16 [8192][128]
#define A2          8454176
#define OFF_X1      (A2+0)            // 1024*128
#define OFF_Y16     (A2+131072)       // 1024*16
#define OFF_X1_     (A2+262144)       // 1024*128
#define OFF_S2      (A2+524288)       // 1024*128
#define OFF_S2S     (A2+655360)       // 1024*128
#define OFF_U       (A2+786432)       // 1024*128
#define OFF_X2      (A2+917504)       // 128*128
#define OFF_ADJ2    (A2+933888)
#define OFF_HC      (A2+950272)
#define OFF_X2_     (A2+966656)
#define OFF_Z2      (A2+999424)       // 128*128
#define OFF_X1O     (A2+1261568)      // 1024*128
#define OFF_P16     (A2+1392640)      // 8192*16 (early: deg1[1024], diagv[1024])
#define OFF_DEG1    OFF_P16           // 1024 (zeroed via dedicated memset)
#define OFF_DIAGV   (OFF_P16+1024)    // 1024
#define OFF_DI1     (A2+1654784)      // 1024
#define OFF_DF1     (A2+1655808)
#define OFF_DI2     (A2+1656832)      // 128
#define OFF_DF2     (A2+1656960)
// Region B:
#define OFF_ST      10111264          // S_T bf16 [1024][8192]
#define OFF_TBF     14305568          // t bf16 [8192][1024]; WP1T aliases; later PT
#define OFF_WP1T    OFF_TBF
#define OFF_PT      OFF_TBF           // fp32 [4][108][128*128] = 28.3 MB (fits 8.4M slots)
#define OFF_TT2     32131360          // TT bf16 [8192][1024]
// total: 36,325,664 float-slots = 138.6 MiB

// ------------------- output layout (floats) -------------------
#define OUT_PRED 0          // 8192*16
#define OUT_S1   131072     // 8192*1024
#define OUT_LOSS 8519680    // 1
#define OUT_ADJ1 8519681    // 1024*1024

__device__ __forceinline__ unsigned short f2bf(float f) {
    union { float f; unsigned u; } v; v.f = f;
    unsigned r = (v.u + 0x7FFF + ((v.u >> 16) & 1)) >> 16;
    return (unsigned short)r;
}
__device__ __forceinline__ float bf2f(unsigned short b) {
    union { unsigned u; float f; } v; v.u = (unsigned)b << 16; return v.f;
}
// async global->LDS 16B (wave-uniform LDS base + lane*16)
__device__ __forceinline__ void gl_lds16(const unsigned short* g, unsigned short* l) {
    __builtin_amdgcn_global_load_lds(
        (const __attribute__((address_space(1))) void*)g,
        (__attribute__((address_space(3))) void*)l, 16, 0, 0);
}

// =========================== graph-structure kernels ===========================

__global__ void k_hist(const int* __restrict__ row, const int* __restrict__ col,
                       const float* __restrict__ ew, int E,
                       float* deg, int* cntc, int* cntr, float* sumA2) {
    __shared__ float red[256];
    int e = blockIdx.x * 256 + threadIdx.x;
    float w2 = 0.f;
    if (e < E) {
        int r = row[e], c = col[e];
        float w = ew[e];
        atomicAdd(&deg[c], w);
        atomicAdd(&cntc[c], 1);
        atomicAdd(&cntr[r], 1);
        w2 = w * w;
    }
    red[threadIdx.x] = w2; __syncthreads();
    for (int s = 128; s > 0; s >>= 1) { if (threadIdx.x < s) red[threadIdx.x] += red[threadIdx.x + s]; __syncthreads(); }
    if (threadIdx.x == 0) atomicAdd(sumA2, red[0]);
}

__global__ __launch_bounds__(1024) void k_scan(const int* cntc, const int* cntr,
        int* colptr, int* rowptr, int* curc, int* curr, int n, int E,
        const float* __restrict__ deg, float* __restrict__ dinv) {
    __shared__ int part[1024];
    int tid = threadIdx.x;
    const int per = 8;
    for (int pass = 0; pass < 2; ++pass) {
        const int* cnt = pass ? cntr : cntc;
        int* ptr = pass ? rowptr : colptr;
        int* cur = pass ? curr : curc;
        int st = tid * per;
        int loc[per]; int s = 0;
        for (int i = 0; i < per; ++i) { loc[i] = s; s += cnt[st + i]; }
        part[tid] = s; __syncthreads();
        for (int off = 1; off < 1024; off <<= 1) {
            int v = part[tid];
            int add = (tid >= off) ? part[tid - off] : 0;
            __syncthreads();
            part[tid] = v + add;
            __syncthreads();
        }
        int pre = (tid == 0) ? 0 : part[tid - 1];
        for (int i = 0; i < per; ++i) { int v = pre + loc[i]; ptr[st + i] = v; cur[st + i] = v; }
        if (tid == 0) ptr[n] = E;
        __syncthreads();
    }
    for (int i = tid; i < n; i += 1024) {
        float d = deg[i] + 1.0f;
        dinv[i] = (d > 0.f) ? 1.0f / sqrtf(d) : 0.f;
    }
}

__global__ void k_scatter(const int* __restrict__ row, const int* __restrict__ col,
                          const float* __restrict__ ew, int E, const float* __restrict__ dinv,
                          int* curc, int* curr, int* colr, float* coln, int* rowc, float* roww) {
    int e = blockIdx.x * 256 + threadIdx.x;
    if (e >= E) return;
    int r = row[e], c = col[e];
    float w = ew[e];
    float nrm = dinv[r] * w * dinv[c];
    int p = atomicAdd(&curc[c], 1);
    colr[p] = r; coln[p] = nrm;
    int q = atomicAdd(&curr[r], 1);
    rowc[q] = c; roww[q] = w;
}

// =========================== fp32 GEMMs ===========================

__global__ __launch_bounds__(256) void gemm_ab_b16(const float* __restrict__ A, const float* __restrict__ B,
        unsigned short* __restrict__ C, int M, int N, int K) {
    __shared__ float As[16][68];
    __shared__ float Bs[16][68];
    int tid = threadIdx.x, tx = tid & 15, ty = tid >> 4;
    int m0 = blockIdx.y * 64, n0 = blockIdx.x * 64;
    float acc[4][4] = {};
    for (int k0 = 0; k0 < K; k0 += 16) {
        for (int l = 0; l < 4; ++l) {
            int idx = tid + 256 * l;
            int mm = idx >> 4, kk = idx & 15;
            As[kk][mm] = A[(size_t)(m0 + mm) * K + k0 + kk];
            int kk2 = idx >> 6, nn = idx & 63;
            Bs[kk2][nn] = B[(size_t)(k0 + kk2) * N + n0 + nn];
        }
        __syncthreads();
        #pragma unroll
        for (int kk = 0; kk < 16; ++kk) {
            float a[4], b[4];
            #pragma unroll
            for (int i = 0; i < 4; ++i) a[i] = As[kk][ty * 4 + i];
            #pragma unroll
            for (int j = 0; j < 4; ++j) b[j] = Bs[kk][tx * 4 + j];
            #pragma unroll
            for (int i = 0; i < 4; ++i)
                #pragma unroll
                for (int j = 0; j < 4; ++j) acc[i][j] += a[i] * b[j];
        }
        __syncthreads();
    }
    for (int i = 0; i < 4; ++i)
        for (int j = 0; j < 4; ++j)
            C[(size_t)(m0 + ty * 4 + i) * N + n0 + tx * 4 + j] = f2bf(acc[i][j]);
}

// 32x32 tile, C = A@B (+bias/relu/accum), fp32 out
__global__ __launch_bounds__(256) void gemm_ab32(const float* __restrict__ A, const float* __restrict__ B,
        float* __restrict__ C, int M, int N, int K,
        const float* __restrict__ bias, int relu, int accum) {
    __shared__ float As[32][33];
    __shared__ float Bs[32][33];
    int tid = threadIdx.x, tx = tid & 15, ty = tid >> 4;
    int m0 = blockIdx.y * 32, n0 = blockIdx.x * 32;
    float acc[2][2] = {};
    for (int k0 = 0; k0 < K; k0 += 32) {
        #pragma unroll
        for (int l = 0; l < 4; ++l) {
            int idx = tid + 256 * l;
            int r = idx >> 5, c = idx & 31;
            As[r][c] = A[(size_t)(m0 + r) * K + k0 + c];
            Bs[r][c] = B[(size_t)(k0 + r) * N + n0 + c];
        }
        __syncthreads();
        #pragma unroll
        for (int kk = 0; kk < 32; ++kk) {
            float a0 = As[ty * 2][kk], a1 = As[ty * 2 + 1][kk];
            float b0 = Bs[kk][tx * 2], b1 = Bs[kk][tx * 2 + 1];
            acc[0][0] += a0 * b0; acc[0][1] += a0 * b1;
            acc[1][0] += a1 * b0; acc[1][1] += a1 * b1;
        }
        __syncthreads();
    }
    #pragma unroll
    for (int i = 0; i < 2; ++i)
        #pragma unroll
        for (int j = 0; j < 2; ++j) {
            int m = m0 + ty * 2 + i, n = n0 + tx * 2 + j;
            float v = acc[i][j];
            if (accum) v += C[(size_t)m * N + n];
            if (bias) v += bias[n];
            if (relu) v = fmaxf(v, 0.f);
            C[(size_t)m * N + n] = v;
        }
}

// 32x32 tile: CT[N][M] bf16 = (A@B)^T, single-source
__global__ __launch_bounds__(256) void gemm_ab32_bt(const float* __restrict__ A,
        const float* __restrict__ B, unsigned short* __restrict__ CT, int M, int N, int K) {
    __shared__ float As[32][33];
    __shared__ float Bs[32][33];
    int tid = threadIdx.x, tx = tid & 15, ty = tid >> 4;
    int m0 = blockIdx.y * 32, n0 = blockIdx.x * 32;
    float acc[2][2] = {};
    for (int k0 = 0; k0 < K; k0 += 32) {
        #pragma unroll
        for (int l = 0; l < 4; ++l) {
            int idx = tid + 256 * l;
            int r = idx >> 5, c = idx & 31;
            As[r][c] = A[(size_t)(m0 + r) * K + k0 + c];
            Bs[r][c] = B[(size_t)(k0 + r) * N + n0 + c];
        }
        __syncthreads();
        #pragma unroll
        for (int kk = 0; kk < 32; ++kk) {
            float a0 = As[ty * 2][kk], a1 = As[ty * 2 + 1][kk];
            float b0 = Bs[kk][tx * 2], b1 = Bs[kk][tx * 2 + 1];
            acc[0][0] += a0 * b0; acc[0][1] += a0 * b1;
            acc[1][0] += a1 * b0; acc[1][1] += a1 * b1;
        }
        __syncthreads();
    }
    #pragma unroll
    for (int i = 0; i < 2; ++i)
        #pragma unroll
        for (int j = 0; j < 2; ++j)
            As[ty * 2 + i][tx * 2 + j] = acc[i][j];
    __syncthreads();
    int nl = tid >> 3, moff = (tid & 7) * 4;
    ushort4 o;
    o.x = f2bf(As[moff + 0][nl]);
    o.y = f2bf(As[moff + 1][nl]);
    o.z = f2bf(As[moff + 2][nl]);
    o.w = f2bf(As[moff + 3][nl]);
    *(ushort4*)(CT + (size_t)(n0 + nl) * M + m0 + moff) = o;
}

// dual-source: CT[N][M] bf16 = (A0@B0 + A1@B1)^T  (both K=Kc)
__global__ __launch_bounds__(256) void gemm_dual_bt(const float* __restrict__ A0,
        const float* __restrict__ B0, const float* __restrict__ A1, const float* __restrict__ B1,
        unsigned short* __restrict__ CT, int M, int N, int Kc) {
    __shared__ float As[32][33];
    __shared__ float Bs[32][33];
    int tid = threadIdx.x, tx = tid & 15, ty = tid >> 4;
    int m0 = blockIdx.y * 32, n0 = blockIdx.x * 32;
    float acc[2][2] = {};
    for (int src = 0; src < 2; ++src) {
        const float* A = src ? A1 : A0;
        const float* B = src ? B1 : B0;
        for (int k0 = 0; k0 < Kc; k0 += 32) {
            #pragma unroll
            for (int l = 0; l < 4; ++l) {
                int idx = tid + 256 * l;
                int r = idx >> 5, c = idx & 31;
                As[r][c] = A[(size_t)(m0 + r) * Kc + k0 + c];
                Bs[r][c] = B[(size_t)(k0 + r) * N + n0 + c];
            }
            __syncthreads();
            #pragma unroll
            for (int kk = 0; kk < 32; ++kk) {
                float a0 = As[ty * 2][kk], a1 = As[ty * 2 + 1][kk];
                float b0 = Bs[kk][tx * 2], b1 = Bs[kk][tx * 2 + 1];
                acc[0][0] += a0 * b0; acc[0][1] += a0 * b1;
                acc[1][0] += a1 * b0; acc[1][1] += a1 * b1;
            }
            __syncthreads();
        }
    }
    #pragma unroll
    for (int i = 0; i < 2; ++i)
        #pragma unroll
        for (int j = 0; j < 2; ++j)
            As[ty * 2 + i][tx * 2 + j] = acc[i][j];
    __syncthreads();
    int nl = tid >> 3, moff = (tid & 7) * 4;
    ushort4 o;
    o.x = f2bf(As[moff + 0][nl]);
    o.y = f2bf(As[moff + 1][nl]);
    o.z = f2bf(As[moff + 2][nl]);
    o.w = f2bf(As[moff + 3][nl]);
    *(ushort4*)(CT + (size_t)(n0 + nl) * M + m0 + moff) = o;
}

// 32x32 tile, C = relu(mscale[m] * (sum_k kscale[k]*(A[k][m]+(k==m)*dfix[m])*B[k][n]) + bias[n])
__global__ __launch_bounds__(256) void gemm_atb32n(const float* __restrict__ A, const float* __restrict__ B,
        float* __restrict__ C, int M, int N, int K,
        const float* __restrict__ bias, const float* __restrict__ kscale,
        const float* __restrict__ dfixv, const float* __restrict__ mscale) {
    __shared__ float As[32][33];
    __shared__ float Bs[32][33];
    int tid = threadIdx.x, tx = tid & 15, ty = tid >> 4;
    int m0 = blockIdx.y * 32, n0 = blockIdx.x * 32;
    float acc[2][2] = {};
    for (int k0 = 0; k0 < K; k0 += 32) {
        #pragma unroll
        for (int l = 0; l < 4; ++l) {
            int idx = tid + 256 * l;
            int r = idx >> 5, c = idx & 31;
            int k = k0 + r, m = m0 + c;
            float v = A[(size_t)k * M + m];
            if (k == m) v += dfixv[m];
            As[c][r] = v * kscale[k];
            Bs[r][c] = B[(size_t)k * N + n0 + c];
        }
        __syncthreads();
        #pragma unroll
        for (int kk = 0; kk < 32; ++kk) {
            float a0 = As[ty * 2][kk], a1 = As[ty * 2 + 1][kk];
            float b0 = Bs[kk][tx * 2], b1 = Bs[kk][tx * 2 + 1];
            acc[0][0] += a0 * b0; acc[0][1] += a0 * b1;
            acc[1][0] += a1 * b0; acc[1][1] += a1 * b1;
        }
        __syncthreads();
    }
    #pragma unroll
    for (int i = 0; i < 2; ++i)
        #pragma unroll
        for (int j = 0; j < 2; ++j) {
            int m = m0 + ty * 2 + i, n = n0 + tx * 2 + j;
            float v = acc[i][j] * mscale[m] + bias[n];
            C[(size_t)m * N + n] = fmaxf(v, 0.f);
        }
}

// fused 3x (A^T@B) sharing A=S2s: op0 C0=A^T@B0, op1 C1=A^T@B1, op2 sumsq(A^T@B2)
__global__ __launch_bounds__(256) void k_atb32_3(const float* __restrict__ A,
        const float* __restrict__ B0, const float* __restrict__ B1, const float* __restrict__ B2,
        float* __restrict__ C0, float* __restrict__ C1, float* ss_acc,
        int M, int N, int K) {
    __shared__ float As[32][33];
    __shared__ float Bs[32][33];
    __shared__ float red[256];
    int op = blockIdx.z;
    const float* B = (op == 0) ? B0 : (op == 1) ? B1 : B2;
    int tid = threadIdx.x, tx = tid & 15, ty = tid >> 4;
    int m0 = blockIdx.y * 32, n0 = blockIdx.x * 32;
    float acc[2][2] = {};
    for (int k0 = 0; k0 < K; k0 += 32) {
        #pragma unroll
        for (int l = 0; l < 4; ++l) {
            int idx = tid + 256 * l;
            int r = idx >> 5, c = idx & 31;
            As[c][r] = A[(size_t)(k0 + r) * M + m0 + c];
            Bs[r][c] = B[(size_t)(k0 + r) * N + n0 + c];
        }
        __syncthreads();
        #pragma unroll
        for (int kk = 0; kk < 32; ++kk) {
            float a0 = As[ty * 2][kk], a1 = As[ty * 2 + 1][kk];
            float b0 = Bs[kk][tx * 2], b1 = Bs[kk][tx * 2 + 1];
            acc[0][0] += a0 * b0; acc[0][1] += a0 * b1;
            acc[1][0] += a1 * b0; acc[1][1] += a1 * b1;
        }
        __syncthreads();
    }
    if (op == 2) {
        float ss = acc[0][0] * acc[0][0] + acc[0][1] * acc[0][1]
                 + acc[1][0] * acc[1][0] + acc[1][1] * acc[1][1];
        red[tid] = ss; __syncthreads();
        for (int s = 128; s > 0; s >>= 1) { if (tid < s) red[tid] += red[tid + s]; __syncthreads(); }
        if (tid == 0) atomicAdd(ss_acc, red[0]);
        return;
    }
    float* C = (op == 0) ? C0 : C1;
    #pragma unroll
    for (int i = 0; i < 2; ++i)
        #pragma unroll
        for (int j = 0; j < 2; ++j)
            C[(size_t)(m0 + ty * 2 + i) * N + n0 + tx * 2 + j] = acc[i][j];
}

// C[M][16] (+)= A[M][K] @ B[K][16]
__global__ __launch_bounds__(256) void k_gemm_n16(const float* __restrict__ A, const float* __restrict__ B,
        float* __restrict__ C, int M, int K, int accum) {
    __shared__ float As[16][64];
    __shared__ float Bs[64][16];
    int tid = threadIdx.x;
    int r = tid >> 4, c = tid & 15;
    int m0 = blockIdx.x * 16;
    float acc = 0.f;
    for (int k0 = 0; k0 < K; k0 += 64) {
        #pragma unroll
        for (int l = 0; l < 4; ++l) {
            int idx = tid + 256 * l;
            int rr = idx >> 6, cc = idx & 63;
            As[rr][cc] = A[(size_t)(m0 + rr) * K + k0 + cc];
            int kk = idx >> 4, c2 = idx & 15;
            Bs[kk][c2] = B[(size_t)(k0 + kk) * 16 + c2];
        }
        __syncthreads();
        #pragma unroll 16
        for (int kk = 0; kk < 64; ++kk) acc += As[r][kk] * Bs[kk][c];
        __syncthreads();
    }
    float* p = &C[(size_t)(m0 + r) * 16 + c];
    if (accum) acc += *p;
    *p = acc;
}

// C[M][16] = A0[M][K0]@B0 + A1[M][K1]@B1
__global__ __launch_bounds__(256) void k_gemm_n16_dual(
        const float* __restrict__ A0, int K0, const float* __restrict__ B0,
        const float* __restrict__ A1, int K1, const float* __restrict__ B1,
        float* __restrict__ C, int M) {
    __shared__ float As[16][64];
    __shared__ float Bs[64][16];
    int tid = threadIdx.x;
    int r = tid >> 4, c = tid & 15;
    int m0 = blockIdx.x * 16;
    float acc = 0.f;
    for (int src = 0; src < 2; ++src) {
        const float* A = src ? A1 : A0;
        const float* B = src ? B1 : B0;
        int K = src ? K1 : K0;
        for (int k0 = 0; k0 < K; k0 += 64) {
            #pragma unroll
            for (int l = 0; l < 4; ++l) {
                int idx = tid + 256 * l;
                int rr = idx >> 6, cc = idx & 63;
                As[rr][cc] = A[(size_t)(m0 + rr) * K + k0 + cc];
                int kk = idx >> 4, c2 = idx & 15;
                Bs[kk][c2] = B[(size_t)(k0 + kk) * 16 + c2];
            }
            __syncthreads();
            #pragma unroll 16
            for (int kk = 0; kk < 64; ++kk) acc += As[r][kk] * Bs[kk][c];
            __syncthreads();
        }
    }
    C[(size_t)(m0 + r) * 16 + c] = acc;
}

// =========================== bf16 MFMA GEMMs ===========================
// staging: global_load_lds 16B, linear LDS dest, source col pre-swizzled
// (XOR involution: phys (row,c) holds logical (row, c ^ ((row&7)*8)))

// merged K=8192 split-K GEMM over a flattened tile list:
//   tile 0..63  : adj1 (m=t>>3, n=t&7), B=TT
//   tile 64..99 : G upper-tri pair (ti<=tj), B=ST (norm-only output)
//   tile 100..107: x1 (m=t-100), B=X0T (128 rows)
// grid (108, NZ=4); partials P[z][tile][128*128] tile-contiguous.
__global__ __launch_bounds__(256) void gemm_tn_bf16_tiles(
        const unsigned short* __restrict__ ST_,
        const unsigned short* __restrict__ TT_,
        const unsigned short* __restrict__ X0T_,
        float* __restrict__ P, int K) {
    __shared__ __align__(16) unsigned short As[128 * 64];
    __shared__ __align__(16) unsigned short Bs[128 * 64];
    int tid = threadIdx.x;
    int wave = tid >> 6, lane = tid & 63;
    int wm = wave >> 1, wn = wave & 1;
    int tile = blockIdx.x;
    int m, n; const unsigned short* B;
    if (tile < 64)       { m = tile >> 3; n = tile & 7; B = TT_; }
    else if (tile < 100) { int p = tile - 64; int ti = 0;
                           while (p >= 8 - ti) { p -= 8 - ti; ++ti; }
                           m = ti; n = ti + p; B = ST_; }
    else                 { m = tile - 100; n = 0; B = X0T_; }
    int m0 = m * 128, n0 = n * 128;
    int kchunk = K / gridDim.y;
    int k0 = blockIdx.y * kchunk;
    float* Pz = P + ((size_t)blockIdx.y * 108 + tile) * 16384;
    floatx4 acc[4][4] = {};
    int q = lane >> 4, lm = lane & 15;
    int lrow = lane >> 3, lcol = (lane & 7) * 8;
    for (int kt = 0; kt < kchunk; kt += 64) {
        int gk0 = k0 + kt;
        #pragma unroll
        for (int p = 0; p < 4; ++p) {
            int rbase = wave * 32 + p * 8;
            int row = rbase + lrow;
            int scol = lcol ^ ((row & 7) * 8);
            gl_lds16(&ST_[(size_t)(m0 + row) * K + gk0 + scol], &As[rbase * 64]);
            gl_lds16(&B[(size_t)(n0 + row) * K + gk0 + scol], &Bs[rbase * 64]);
        }
        __syncthreads();
        #pragma unroll
        for (int ks = 0; ks < 64; ks += 32) {
            short8 af[4], bf[4];
            int kk = ks + q * 8;
            #pragma unroll
            for (int i = 0; i < 4; ++i) {
                int ml = wm * 64 + i * 16 + lm;
                af[i] = *(const short8*)(&As[ml * 64 + (kk ^ ((ml & 7) * 8))]);
                int nl = wn * 64 + i * 16 + lm;
                bf[i] = *(const short8*)(&Bs[nl * 64 + (kk ^ ((nl & 7) * 8))]);
            }
            #pragma unroll
            for (int i = 0; i < 4; ++i)
                #pragma unroll
                for (int j = 0; j < 4; ++j)
                    acc[i][j] = __builtin_amdgcn_mfma_f32_16x16x32_bf16(af[i], bf[j], acc[i][j], 0, 0, 0);
        }
        __syncthreads();
    }
    for (int i = 0; i < 4; ++i) {
        int lr = wm * 64 + i * 16 + q * 4;
        for (int j = 0; j < 4; ++j) {
            int lc = wn * 64 + j * 16 + lm;
            #pragma unroll
            for (int r = 0; r < 4; ++r)
                Pz[(size_t)(lr + r) * 128 + lc] = acc[i][j][r];
        }
    }
}

// reduce the tile partials: adj1 -> adj1o + adj1b + ss + colsum + diag/trace;
// G -> weighted ss only; x1 -> write. grid (2, 108): half-tiles of 64 rows.
__global__ __launch_bounds__(256) void k_reduce_tiles(
        const float* __restrict__ P,
        float* __restrict__ adj1o, unsigned short* __restrict__ adj1b,
        float* __restrict__ x1, float* __restrict__ deg1, float* __restrict__ diagv,
        float* __restrict__ scal) {
    __shared__ float colsum[128];
    __shared__ float red[256];
    int tile = blockIdx.y, half = blockIdx.x, tid = threadIdx.x;
    if (tid < 128) colsum[tid] = 0.f;
    __syncthreads();
    int m, n, kind;
    if (tile < 64)       { kind = 0; m = tile >> 3; n = tile & 7; }
    else if (tile < 100) { kind = 1; int p = tile - 64; int ti = 0;
                           while (p >= 8 - ti) { p -= 8 - ti; ++ti; }
                           m = ti; n = ti + p; }
    else                 { kind = 2; m = tile - 100; n = 0; }
    const float* Pt = P + (size_t)tile * 16384 + half * 8192;
    const size_t zstr = (size_t)108 * 16384;
    float ss = 0.f, tr = 0.f;
    float cs0 = 0.f, cs1 = 0.f, cs2 = 0.f, cs3 = 0.f;
    int cc = (tid * 4) & 127;
    bool diagTile = (kind == 0) && (m == n);
    float wgt = (kind == 1 && m != n) ? 2.f : 1.f;
    for (int it = 0; it < 8; ++it) {
        int i4 = tid * 4 + it * 1024;
        float4 v = *(const float4*)(Pt + i4);
        #pragma unroll
        for (int z = 1; z < 4; ++z) {
            float4 w4 = *(const float4*)(Pt + zstr * z + i4);
            v.x += w4.x; v.y += w4.y; v.z += w4.z; v.w += w4.w;
        }
        int rr = i4 >> 7;
        if (kind == 0) {
            size_t gaddr = (size_t)(m * 128 + half * 64 + rr) * 1024 + n * 128 + cc;
            *(float4*)(adj1o + gaddr) = v;
            ushort4 o; o.x = f2bf(v.x); o.y = f2bf(v.y); o.z = f2bf(v.z); o.w = f2bf(v.w);
            *(ushort4*)(adj1b + gaddr) = o;
            cs0 += v.x; cs1 += v.y; cs2 += v.z; cs3 += v.w;
            ss += v.x * v.x + v.y * v.y + v.z * v.z + v.w * v.w;
            if (diagTile) {
                int dloc = half * 64 + rr;
                int dj = dloc - cc;
                if (dj >= 0 && dj < 4) {
                    float dv = (dj == 0) ? v.x : (dj == 1) ? v.y : (dj == 2) ? v.z : v.w;
                    diagv[m * 128 + dloc] = dv;
                    tr += dv;
                }
            }
        } else if (kind == 1) {
            ss += wgt * (v.x * v.x + v.y * v.y + v.z * v.z + v.w * v.w);
        } else {
            *(float4*)(x1 + (size_t)(m * 128 + half * 64) * 128 + i4) = v;
        }
    }
    if (kind == 2) return;
    if (kind == 0) {
        atomicAdd(&colsum[cc + 0], cs0);
        atomicAdd(&colsum[cc + 1], cs1);
        atomicAdd(&colsum[cc + 2], cs2);
        atomicAdd(&colsum[cc + 3], cs3);
    }
    __syncthreads();
    if (kind == 0 && tid < 128)
        atomicAdd(&deg1[n * 128 + tid], colsum[tid]);
    red[tid] = ss; __syncthreads();
    for (int s = 128; s > 0; s >>= 1) { if (tid < s) red[tid] += red[tid + s]; __syncthreads(); }
    if (tid == 0) atomicAdd((kind == 0) ? &scal[4] : &scal[2], red[0]);
    if (diagTile) {
        __syncthreads();
        red[tid] = tr; __syncthreads();
        for (int s = 128; s > 0; s >>= 1) { if (tid < s) red[tid] += red[tid + s]; __syncthreads(); }
        if (tid == 0) atomicAdd(&scal[1], red[0]);
    }
}

// dinv/dfix for adj1 from fused colsum+diag
__global__ __launch_bounds__(1024) void k_dinv1024(const float* __restrict__ deg1,
        const float* __restrict__ diagv, float* __restrict__ di, float* __restrict__ df) {
    int j = threadIdx.x;
    float s = deg1[j];
    float fix = (diagv[j] == 0.f) ? 1.0f : 0.f;
    s += fix;
    df[j] = fix;
    di[j] = (s > 0.f) ? 1.0f / sqrtf(s) : 0.f;
}

// full-K single-launch: C[M][128] = relu(bias + sum_k A[m][k]*B[n][k]), bf16 in
// tile 64(M) x 64(N), grid (M/64, 2), 4 waves each 16 rows x 64 cols
__global__ __launch_bounds__(256) void gemm_tn_bf16_n128(
        const unsigned short* __restrict__ A, const unsigned short* __restrict__ B,
        float* __restrict__ C, int K,
        const float* __restrict__ bias, int relu) {
    __shared__ __align__(16) unsigned short As[64 * 64];
    __shared__ __align__(16) unsigned short Bs[64 * 64];
    int tid = threadIdx.x, wave = tid >> 6, lane = tid & 63;
    int m0 = blockIdx.x * 64, n0 = blockIdx.y * 64;
    floatx4 acc[4] = {};
    int q = lane >> 4, lm = lane & 15;
    int lrow = lane >> 3, lcol = (lane & 7) * 8;
    for (int kt = 0; kt < K; kt += 64) {
        #pragma unroll
        for (int p = 0; p < 2; ++p) {
            int rbase = wave * 16 + p * 8;
            int row = rbase + lrow;
            int scol = lcol ^ ((row & 7) * 8);
            gl_lds16(&A[(size_t)(m0 + row) * K + kt + scol], &As[rbase * 64]);
            gl_lds16(&B[(size_t)(n0 + row) * K + kt + scol], &Bs[rbase * 64]);
        }
        __syncthreads();
        #pragma unroll
        for (int ks = 0; ks < 64; ks += 32) {
            int kk = ks + q * 8;
            int ml = wave * 16 + lm;
            short8 af = *(const short8*)(&As[ml * 64 + (kk ^ ((ml & 7) * 8))]);
            #pragma unroll
            for (int j = 0; j < 4; ++j) {
                int nl = j * 16 + lm;
                short8 bf = *(const short8*)(&Bs[nl * 64 + (kk ^ ((nl & 7) * 8))]);
                acc[j] = __builtin_amdgcn_mfma_f32_16x16x32_bf16(af, bf, acc[j], 0, 0, 0);
            }
        }
        __syncthreads();
    }
    #pragma unroll
    for (int j = 0; j < 4; ++j) {
        int col = n0 + j * 16 + lm;
        float bv = bias ? bias[col] : 0.f;
        int rowb = m0 + wave * 16 + q * 4;
        #pragma unroll
        for (int r = 0; r < 4; ++r) {
            float v = acc[j][r] + bv;
            if (relu) v = fmaxf(v, 0.f);
            C[(size_t)(rowb + r) * 128 + col] = v;
        }
    }
}

// full-K store with bias+relu (s1o)
__global__ __launch_bounds__(256) void gemm_tn_bf16_store(
        const unsigned short* __restrict__ A, const unsigned short* __restrict__ B,
        float* __restrict__ C, int M, int N, int K,
        const float* __restrict__ bias, int relu) {
    __shared__ __align__(16) unsigned short As[128 * 64];
    __shared__ __align__(16) unsigned short Bs[128 * 64];
    int tid = threadIdx.x;
    int wave = tid >> 6, lane = tid & 63;
    int wm = wave >> 1, wn = wave & 1;
    int m0 = blockIdx.x * 128, n0 = blockIdx.y * 128;
    floatx4 acc[4][4] = {};
    int q = lane >> 4, lm = lane & 15;
    int lrow = lane >> 3, lcol = (lane & 7) * 8;
    for (int kt = 0; kt < K; kt += 64) {
        #pragma unroll
        for (int p = 0; p < 4; ++p) {
            int rbase = wave * 32 + p * 8;
            int row = rbase + lrow;
            int scol = lcol ^ ((row & 7) * 8);
            gl_lds16(&A[(size_t)(m0 + row) * K + kt + scol], &As[rbase * 64]);
            gl_lds16(&B[(size_t)(n0 + row) * K + kt + scol], &Bs[rbase * 64]);
        }
        __syncthreads();
        #pragma unroll
        for (int ks = 0; ks < 64; ks += 32) {
            short8 af[4], bf[4];
            int kk = ks + q * 8;
            #pragma unroll
            for (int i = 0; i < 4; ++i) {
                int ml = wm * 64 + i * 16 + lm;
                af[i] = *(const short8*)(&As[ml * 64 + (kk ^ ((ml & 7) * 8))]);
                int nl = wn * 64 + i * 16 + lm;
                bf[i] = *(const short8*)(&Bs[nl * 64 + (kk ^ ((nl & 7) * 8))]);
            }
            #pragma unroll
            for (int i = 0; i < 4; ++i)
                #pragma unroll
                for (int j = 0; j < 4; ++j)
                    acc[i][j] = __builtin_amdgcn_mfma_f32_16x16x32_bf16(af[i], bf[j], acc[i][j], 0, 0, 0);
        }
        __syncthreads();
    }
    for (int i = 0; i < 4; ++i) {
        int rowb = m0 + wm * 64 + i * 16 + q * 4;
        for (int j = 0; j < 4; ++j) {
            int col = n0 + wn * 64 + j * 16 + lm;
            float bv = bias ? bias[col] : 0.f;
            #pragma unroll
            for (int r = 0; r < 4; ++r) {
                float v = acc[i][j][r] + bv;
                if (relu) v = fmaxf(v, 0.f);
                C[(size_t)(rowb + r) * N + col] = v;
            }
        }
    }
}

// =========================== transposes ===========================

__global__ __launch_bounds__(256) void k_transpose_f2b(
        const float* __restrict__ in, unsigned short* __restrict__ outb,
        int R, int C, const float* __restrict__ rowscale) {
    __shared__ float tile[64][65];
    int rb = blockIdx.y * 64, cb = blockIdx.x * 64;
    int t = threadIdx.x;
    int lr = t >> 4, lc4 = (t & 15) * 4;
    #pragma unroll
    for (int p = 0; p < 4; ++p) {
        int r = rb + lr + p * 16;
        float4 v = *(const float4*)(in + (size_t)r * C + cb + lc4);
        float s = rowscale ? rowscale[r] : 1.0f;
        tile[lr + p * 16][lc4 + 0] = v.x * s;
        tile[lr + p * 16][lc4 + 1] = v.y * s;
        tile[lr + p * 16][lc4 + 2] = v.z * s;
        tile[lr + p * 16][lc4 + 3] = v.w * s;
    }
    __syncthreads();
    int cc0 = t >> 5, rr = (t & 31) * 2;
    #pragma unroll
    for (int p = 0; p < 8; ++p) {
        int cc = cc0 + p * 8;
        unsigned a = f2bf(tile[rr][cc]);
        unsigned b = f2bf(tile[rr + 1][cc]);
        *(unsigned*)(outb + (size_t)(cb + cc) * R + rb + rr) = a | (b << 16);
    }
}

// dual bf16 transpose: blockIdx.z selects (in0->out0) or (in1->out1)
__global__ __launch_bounds__(256) void k_transpose_b2b2(
        const unsigned short* __restrict__ in0, unsigned short* __restrict__ out0,
        const unsigned short* __restrict__ in1, unsigned short* __restrict__ out1,
        int R, int C) {
    __shared__ __align__(16) unsigned short tile[64][72];
    const unsigned short* in = blockIdx.z ? in1 : in0;
    unsigned short* out = blockIdx.z ? out1 : out0;
    int rb = blockIdx.y * 64, cb = blockIdx.x * 64;
    int t = threadIdx.x;
    int lr = t >> 3, lc = (t & 7) * 8;
    #pragma unroll
    for (int p = 0; p < 2; ++p) {
        int r = lr + p * 32;
        *(short8*)(&tile[r][lc]) = *(const short8*)(&in[(size_t)(rb + r) * C + cb + lc]);
    }
    __syncthreads();
    int cc0 = t >> 4, rr = (t & 15) * 4;
    #pragma unroll
    for (int p = 0; p < 4; ++p) {
        int cc = cc0 + p * 16;
        unsigned long long v = (unsigned long long)tile[rr][cc]
                             | ((unsigned long long)tile[rr + 1][cc] << 16)
                             | ((unsigned long long)tile[rr + 2][cc] << 32)
                             | ((unsigned long long)tile[rr + 3][cc] << 48);
        *(unsigned long long*)(&out[(size_t)(cb + cc) * R + rb + rr]) = v;
    }
}

// an1Tb[j][i] = bf16( dinv[i]*(adj1[i][j] + (i==j)*dfix[i])*dinv[j] )
__global__ __launch_bounds__(256) void k_anorm_tb(const float* __restrict__ adjm, int n,
        const float* __restrict__ dinvv, const float* __restrict__ dfix,
        unsigned short* __restrict__ outb) {
    __shared__ float tile[64][65];
    int rb = blockIdx.y * 64, cb = blockIdx.x * 64;
    int t = threadIdx.x;
    int lr = t >> 4, lc4 = (t & 15) * 4;
    #pragma unroll
    for (int p = 0; p < 4; ++p) {
        int i = rb + lr + p * 16;
        float4 v = *(const float4*)(adjm + (size_t)i * n + cb + lc4);
        float di = dinvv[i];
        float vv[4] = {v.x, v.y, v.z, v.w};
        #pragma unroll
        for (int q = 0; q < 4; ++q) {
            int j = cb + lc4 + q;
            float val = vv[q];
            if (i == j) val += dfix[i];
            tile[lr + p * 16][lc4 + q] = di * val * dinvv[j];
        }
    }
    __syncthreads();
    int cc0 = t >> 5, rr = (t & 31) * 2;
    #pragma unroll
    for (int p = 0; p < 8; ++p) {
        int cc = cc0 + p * 8;
        unsigned a = f2bf(tile[rr][cc]);
        unsigned b = f2bf(tile[rr + 1][cc]);
        *(unsigned*)(outb + (size_t)(cb + cc) * n + rb + rr) = a | (b << 16);
    }
}

// =========================== aggregation / misc ===========================

__global__ __launch_bounds__(64) void k_agg_b16(const unsigned short* __restrict__ h,
        float* __restrict__ out, unsigned short* __restrict__ outb,
        const int* __restrict__ cptr, const int* __restrict__ colr,
        const float* __restrict__ coln, const float* __restrict__ dinv,
        const float* __restrict__ bias, int relu) {
    int c = blockIdx.x, t = threadIdx.x;
    int f0 = t * 2;
    float d = dinv[c], dd = d * d;
    const unsigned short* hf = h + f0;
    unsigned u = *(const unsigned*)(hf + (size_t)c * 128);
    float a0 = dd * bf2f((unsigned short)(u & 0xffff));
    float a1 = dd * bf2f((unsigned short)(u >> 16));
    int e0 = cptr[c], e1 = cptr[c + 1];
    int e = e0;
    for (; e + 4 <= e1; e += 4) {
        int r0 = colr[e], r1 = colr[e + 1], r2 = colr[e + 2], r3 = colr[e + 3];
        float w0 = coln[e], w1 = coln[e + 1], w2 = coln[e + 2], w3 = coln[e + 3];
        unsigned v0 = *(const unsigned*)(hf + (size_t)r0 * 128);
        unsigned v1 = *(const unsigned*)(hf + (size_t)r1 * 128);
        unsigned v2 = *(const unsigned*)(hf + (size_t)r2 * 128);
        unsigned v3 = *(const unsigned*)(hf + (size_t)r3 * 128);
        a0 += w0 * bf2f((unsigned short)(v0 & 0xffff)) + w1 * bf2f((unsigned short)(v1 & 0xffff))
            + w2 * bf2f((unsigned short)(v2 & 0xffff)) + w3 * bf2f((unsigned short)(v3 & 0xffff));
        a1 += w0 * bf2f((unsigned short)(v0 >> 16)) + w1 * bf2f((unsigned short)(v1 >> 16))
            + w2 * bf2f((unsigned short)(v2 >> 16)) + w3 * bf2f((unsigned short)(v3 >> 16));
    }
    for (; e < e1; ++e) {
        float w = coln[e];
        unsigned v = *(const unsigned*)(hf + (size_t)colr[e] * 128);
        a0 += w * bf2f((unsigned short)(v & 0xffff));
        a1 += w * bf2f((unsigned short)(v >> 16));
    }
    if (bias) { a0 += bias[f0]; a1 += bias[f0 + 1]; }
    if (relu) { a0 = fmaxf(a0, 0.f); a1 = fmaxf(a1, 0.f); }
    if (out) { out[(size_t)c * 128 + f0] = a0; out[(size_t)c * 128 + f0 + 1] = a1; }
    if (outb) {
        unsigned o = (unsigned)f2bf(a0) | ((unsigned)f2bf(a1) << 16);
        *(unsigned*)(outb + (size_t)c * 128 + f0) = o;
    }
}

// F=16 agg + fused log_softmax (16-lane groups), writes prediction directly
__global__ __launch_bounds__(256) void k_agg16_ls(const float* __restrict__ h, float* __restrict__ pred,
        const int* __restrict__ cptr, const int* __restrict__ colr,
        const float* __restrict__ coln, const float* __restrict__ dinv,
        const float* __restrict__ bias) {
    int node = blockIdx.x * 16 + (threadIdx.x >> 4);
    int f = threadIdx.x & 15;
    float d = dinv[node];
    const float* hf = h + f;
    float acc = d * d * hf[(size_t)node * 16];
    int e0 = cptr[node], e1 = cptr[node + 1];
    int e = e0;
    for (; e + 4 <= e1; e += 4) {
        int r0 = colr[e], r1 = colr[e + 1], r2 = colr[e + 2], r3 = colr[e + 3];
        float w0 = coln[e], w1 = coln[e + 1], w2 = coln[e + 2], w3 = coln[e + 3];
        float v0 = hf[(size_t)r0 * 16], v1 = hf[(size_t)r1 * 16];
        float v2 = hf[(size_t)r2 * 16], v3 = hf[(size_t)r3 * 16];
        acc += w0 * v0 + w1 * v1 + w2 * v2 + w3 * v3;
    }
    for (; e < e1; ++e)
        acc += coln[e] * hf[(size_t)colr[e] * 16];
    acc += bias[f];
    acc = fmaxf(acc, 0.f);
    float m = acc;
    #pragma unroll
    for (int off = 1; off < 16; off <<= 1) m = fmaxf(m, __shfl_xor(m, off, 16));
    float ex = expf(acc - m);
    float s = ex;
    #pragma unroll
    for (int off = 1; off < 16; off <<= 1) s += __shfl_xor(s, off, 16);
    pred[(size_t)node * 16 + f] = acc - m - logf(s);
}

__global__ __launch_bounds__(256) void k_softmax1024(const float* __restrict__ x,
        unsigned short* __restrict__ Sb, const float* __restrict__ mask, float* ent_acc) {
    __shared__ float red[256];
    int r = blockIdx.x, tid = threadIdx.x;
    const float* xr = x + (size_t)r * 1024;
    float4 v = *(const float4*)(xr + tid * 4);
    float m = fmaxf(fmaxf(v.x, v.y), fmaxf(v.z, v.w));
    red[tid] = m; __syncthreads();
    for (int s = 128; s > 0; s >>= 1) { if (tid < s) red[tid] = fmaxf(red[tid], red[tid + s]); __syncthreads(); }
    m = red[0]; __syncthreads();
    float e0 = expf(v.x - m), e1 = expf(v.y - m), e2 = expf(v.z - m), e3 = expf(v.w - m);
    red[tid] = e0 + e1 + e2 + e3; __syncthreads();
    for (int s = 128; s > 0; s >>= 1) { if (tid < s) red[tid] += red[tid + s]; __syncthreads(); }
    float inv = 1.0f / red[0]; __syncthreads();
    float mk = mask ? mask[r] : 1.0f;
    float s0 = e0 * inv * mk, s1 = e1 * inv * mk, s2 = e2 * inv * mk, s3 = e3 * inv * mk;
    float ent = -(s0 * logf(s0 + 1e-15f) + s1 * logf(s1 + 1e-15f)
                + s2 * logf(s2 + 1e-15f) + s3 * logf(s3 + 1e-15f));
    ushort4 o;
    o.x = f2bf(s0); o.y = f2bf(s1); o.z = f2bf(s2); o.w = f2bf(s3);
    *(ushort4*)(Sb + (size_t)r * 1024 + tid * 4) = o;
    red[tid] = ent; __syncthreads();
    for (int s = 128; s > 0; s >>= 1) { if (tid < s) red[tid] += red[tid + s]; __syncthreads(); }
    if (tid == 0) atomicAdd(ent_acc, red[0]);
}

__global__ __launch_bounds__(256) void k_softmax_ent(const float* __restrict__ x, float* __restrict__ S,
        int W, const float* __restrict__ mask, float* ent_acc) {
    __shared__ float red[256];
    int row = blockIdx.x, tid = threadIdx.x;
    const float* xr = x + (size_t)row * W;
    float m = -3.0e38f;
    for (int q = tid; q < W; q += 256) m = fmaxf(m, xr[q]);
    red[tid] = m; __syncthreads();
    for (int s = 128; s > 0; s >>= 1) { if (tid < s) red[tid] = fmaxf(red[tid], red[tid + s]); __syncthreads(); }
    m = red[0]; __syncthreads();
    float sum = 0.f;
    for (int q = tid; q < W; q += 256) sum += expf(xr[q] - m);
    red[tid] = sum; __syncthreads();
    for (int s = 128; s > 0; s >>= 1) { if (tid < s) red[tid] += red[tid + s]; __syncthreads(); }
    float inv = 1.0f / red[0]; __syncthreads();
    float mk = mask ? mask[row] : 1.0f;
    float* Sr = S + (size_t)row * W;
    float ent = 0.f;
    for (int q = tid; q < W; q += 256) {
        float v = expf(xr[q] - m) * inv * mk;
        Sr[q] = v;
        ent -= v * logf(v + 1e-15f);
    }
    red[tid] = ent; __syncthreads();
    for (int s = 128; s > 0; s >>= 1) { if (tid < s) red[tid] += red[tid + s]; __syncthreads(); }
    if (tid == 0) atomicAdd(ent_acc, red[0]);
}

// L2-segmented SpMM, 4 waves/block = 4 rows, pass p = cols [p*256, p*256+256)
__global__ __launch_bounds__(256) void k_spmm_seg(const unsigned short* __restrict__ Sb,
        const int* __restrict__ rptr, const int* __restrict__ rowc, const float* __restrict__ roww,
        unsigned short* __restrict__ tb) {
    int wave = threadIdx.x >> 6, lane = threadIdx.x & 63;
    int r = blockIdx.x * 4 + wave;
    int j0 = blockIdx.y * 256 + lane * 4;
    const unsigned short* Sj = Sb + j0;
    float a0 = 0.f, a1 = 0.f, a2 = 0.f, a3 = 0.f;
    int e0 = rptr[r], e1 = rptr[r + 1];
    int e = e0;
    for (; e + 4 <= e1; e += 4) {
        int c0 = rowc[e], c1 = rowc[e + 1], c2 = rowc[e + 2], c3 = rowc[e + 3];
        float w0 = roww[e], w1 = roww[e + 1], w2 = roww[e + 2], w3 = roww[e + 3];
        uint2 v0 = *(const uint2*)(Sj + (size_t)c0 * 1024);
        uint2 v1 = *(const uint2*)(Sj + (size_t)c1 * 1024);
        uint2 v2 = *(const uint2*)(Sj + (size_t)c2 * 1024);
        uint2 v3 = *(const uint2*)(Sj + (size_t)c3 * 1024);
        a0 += w0 * bf2f((unsigned short)(v0.x & 0xffff)) + w1 * bf2f((unsigned short)(v1.x & 0xffff))
            + w2 * bf2f((unsigned short)(v2.x & 0xffff)) + w3 * bf2f((unsigned short)(v3.x & 0xffff));
        a1 += w0 * bf2f((unsigned short)(v0.x >> 16)) + w1 * bf2f((unsigned short)(v1.x >> 16))
            + w2 * bf2f((unsigned short)(v2.x >> 16)) + w3 * bf2f((unsigned short)(v3.x >> 16));
        a2 += w0 * bf2f((unsigned short)(v0.y & 0xffff)) + w1 * bf2f((unsigned short)(v1.y & 0xffff))
            + w2 * bf2f((unsigned short)(v2.y & 0xffff)) + w3 * bf2f((unsigned short)(v3.y & 0xffff));
        a3 += w0 * bf2f((unsigned short)(v0.y >> 16)) + w1 * bf2f((unsigned short)(v1.y >> 16))
            + w2 * bf2f((unsigned short)(v2.y >> 16)) + w3 * bf2f((unsigned short)(v3.y >> 16));
    }
    for (; e < e1; ++e) {
        int c = rowc[e]; float w = roww[e];
        uint2 v = *(const uint2*)(Sj + (size_t)c * 1024);
        a0 += w * bf2f((unsigned short)(v.x & 0xffff));
        a1 += w * bf2f((unsigned short)(v.x >> 16));
        a2 += w * bf2f((unsigned short)(v.y & 0xffff));
        a3 += w * bf2f((unsigned short)(v.y >> 16));
    }
    unsigned lo = (unsigned)f2bf(a0) | ((unsigned)f2bf(a1) << 16);
    unsigned hi = (unsigned)f2bf(a2) | ((unsigned)f2bf(a3) << 16);
    unsigned long long o = (unsigned long long)lo | ((unsigned long long)hi << 32);
    *(unsigned long long*)(tb + (size_t)r * 1024 + j0) = o;
}

// fused colsum+dfix for n=128 + cross2 = trace(adj2)
__global__ __launch_bounds__(128) void k_coldfix128(const float* __restrict__ adjm,
        float* dinvv, float* dfix, float* cross2_out) {
    __shared__ float red[128];
    int j = threadIdx.x;
    float s = 0.f;
    for (int i = 0; i < 128; ++i) s += adjm[(size_t)i * 128 + j];
    float diag = adjm[(size_t)j * 128 + j];
    float fix = (diag == 0.f) ? 1.0f : 0.f;
    s += fix;
    dfix[j] = fix;
    dinvv[j] = (s > 0.f) ? 1.0f / sqrtf(s) : 0.f;
    red[j] = diag; __syncthreads();
    for (int st = 64; st > 0; st >>= 1) { if (j < st) red[j] += red[j + st]; __syncthreads(); }
    if (j == 0) *cross2_out = red[0];
}

__global__ void k_finalize(const float* __restrict__ sc, float* loss) {
    if (threadIdx.x == 0 && blockIdx.x == 0) {
        float e1     = sc[0] / 8192.0f;
        float cross  = sc[1];
        float g2     = sc[2];
        float sumA2  = sc[3];
        float ssadj1 = sc[4];
        float e2     = sc[5] / 1024.0f;
        float cross2 = sc[6];
        float g2b    = sc[7];
        float l1 = sqrtf(fmaxf(sumA2 - 2.0f * cross + g2, 0.f)) / 67108864.0f;
        float l2 = sqrtf(fmaxf(ssadj1 - 2.0f * cross2 + g2b, 0.f)) / 1048576.0f;
        *loss = l1 + e1 + l2 + e2;
    }
}

// =========================== launcher ===========================

extern "C" void kernel_launch(void* const* d_in, const int* in_sizes, int n_in,
                              void* d_out, int out_size, void* d_ws, size_t ws_size,
                              hipStream_t stream) {
    const int N = N_NODES, E = N_EDGES;
    const float* x0     = (const float*)d_in[0];
    const int*   eidx   = (const int*)d_in[1];
    const float* ew     = (const float*)d_in[2];
    const float* mask   = (const float*)d_in[4];
    const float* W0_in  = (const float*)d_in[5];
    const float* b0_in  = (const float*)d_in[6];
    const float* Wp1    = (const float*)d_in[7];
    const float* bp1    = (const float*)d_in[8];
    const float* W1_in  = (const float*)d_in[9];
    const float* b1_in  = (const float*)d_in[10];
    const float* Wp2    = (const float*)d_in[11];
    const float* bp2    = (const float*)d_in[12];
    const float* W2_in  = (const float*)d_in[13];
    const float* b2_in  = (const float*)d_in[14];
    const float* W1_out = (const float*)d_in[15];
    const float* b1_out = (const float*)d_in[16];
    const float* W0_out = (const float*)d_in[17];
    const float* b0_out = (const float*)d_in[18];

    float* out   = (float*)d_out;
    float* predo = out + OUT_PRED;
    float* s1o   = out + OUT_S1;
    float* losso = out + OUT_LOSS;
    float* adj1o = out + OUT_ADJ1;

    float* wsf = (float*)d_ws;
    int*   wsi = (int*)d_ws;
    float* deg   = wsf + OFF_DEG;
    int*   cntc  = wsi + OFF_CNTC;
    int*   cntr  = wsi + OFF_CNTR;
    float* scal  = wsf + OFF_SCAL;
    int*   cptr  = wsi + OFF_COLPTR;
    int*   rptr  = wsi + OFF_ROWPTR;
    int*   curc  = wsi + OFF_CURC;
    int*   curr  = wsi + OFF_CURR;
    int*   colr  = wsi + OFF_COLR;
    float* coln  = wsf + OFF_COLN;
    int*   rowc  = wsi + OFF_ROWC;
    float* roww  = wsf + OFF_ROWW;
    float* dinv  = wsf + OFF_DINV;
    float* x0_   = wsf + OFF_X0;
    unsigned short* h0b   = (unsigned short*)(wsf + OFF_H0);
    unsigned short* Sb    = (unsigned short*)(wsf + OFF_S);
    unsigned short* TT    = (unsigned short*)(wsf + OFF_TT2);
    unsigned short* AN1TB = (unsigned short*)(wsf + OFF_AN1TB);
    unsigned short* ADJ1B = (unsigned short*)(wsf + OFF_ADJ1B);
    unsigned short* HAT   = (unsigned short*)(wsf + OFF_HAT);
    unsigned short* HBT   = (unsigned short*)(wsf + OFF_HBT);
    unsigned short* HCATT = (unsigned short*)(wsf + OFF_HCATT);
    unsigned short* S2ST  = (unsigned short*)(wsf + OFF_S2ST);
    unsigned short* ST    = (unsigned short*)(wsf + OFF_ST);
    unsigned short* TBF   = (unsigned short*)(wsf + OFF_TBF);
    unsigned short* WP1T  = (unsigned short*)(wsf + OFF_WP1T);
    unsigned short* X0T   = (unsigned short*)(wsf + OFF_X0T);
    unsigned short* x0b   = (unsigned short*)(wsf + OFF_X0B);
    float* PT    = wsf + OFF_PT;
    float* x1    = wsf + OFF_X1;
    float* y16   = wsf + OFF_Y16;
    float* x1_   = wsf + OFF_X1_;
    float* s2    = wsf + OFF_S2;
    float* S2s   = wsf + OFF_S2S;
    float* u     = wsf + OFF_U;
    float* x2    = wsf + OFF_X2;
    float* adj2  = wsf + OFF_ADJ2;
    float* hC    = wsf + OFF_HC;
    float* x2_   = wsf + OFF_X2_;
    float* z2    = wsf + OFF_Z2;
    float* x1o_  = wsf + OFF_X1O;
    float* p16   = wsf + OFF_P16;
    float* deg1  = wsf + OFF_DEG1;
    float* diagv = wsf + OFF_DIAGV;
    float* di1   = wsf + OFF_DI1;
    float* df1   = wsf + OFF_DF1;
    float* di2   = wsf + OFF_DI2;
    float* df2   = wsf + OFF_DF2;

    const int* row = eidx;
    const int* col = eidx + E;

    hipMemsetAsync(wsf, 0, (size_t)ZERO_FLOATS * sizeof(float), stream);
    hipMemsetAsync(deg1, 0, 1024 * sizeof(float), stream);

    // --- graph structure ---
    k_hist<<<E / 256, 256, 0, stream>>>(row, col, ew, E, deg, cntc, cntr, &scal[3]);
    k_scan<<<1, 1024, 0, stream>>>(cntc, cntr, cptr, rptr, curc, curr, N, E, deg, dinv);
    k_scatter<<<E / 256, 256, 0, stream>>>(row, col, ew, E, dinv, curc, curr, colr, coln, rowc, roww);

    // --- level 0 GCN ---
    gemm_ab_b16<<<dim3(2, 128), 256, 0, stream>>>(x0, W0_in, h0b, 8192, 128, 128);
    k_agg_b16<<<N, 64, 0, stream>>>(h0b, x0_, x0b, cptr, colr, coln, dinv, b0_in, 1);

    // --- s1 = relu((M^T x0_)@Wp1 + bp1) ---
    k_agg_b16<<<N, 64, 0, stream>>>(x0b, nullptr, h0b, cptr, colr, coln, dinv, nullptr, 0);
    k_transpose_f2b<<<dim3(16, 2), 256, 0, stream>>>(Wp1, WP1T, 128, 1024, nullptr);
    gemm_tn_bf16_store<<<dim3(64, 8), 256, 0, stream>>>(h0b, WP1T, s1o, 8192, 1024, 128, bp1, 1);

    // --- diff_pool level 1 ---
    k_softmax1024<<<N, 256, 0, stream>>>(s1o, Sb, mask, &scal[0]);
    k_spmm_seg<<<dim3(N / 4, 4), 256, 0, stream>>>(Sb, rptr, rowc, roww, TBF);
    k_transpose_b2b2<<<dim3(16, 128, 2), 256, 0, stream>>>(Sb, ST, TBF, TT, 8192, 1024);
    k_transpose_f2b<<<dim3(2, 128), 256, 0, stream>>>(x0_, X0T, 8192, 128, mask);

    // merged big GEMM: adj1 (64 tiles) + G upper-tri (36, norm-only) + x1 (8), z=4
    gemm_tn_bf16_tiles<<<dim3(108, 4), 256, 0, stream>>>(ST, TT, X0T, PT, 8192);
    k_reduce_tiles<<<dim3(2, 108), 256, 0, stream>>>(PT, adj1o, ADJ1B, x1, deg1, diagv, scal);
    k_dinv1024<<<1, 1024, 0, stream>>>(deg1, diagv, di1, df1);
    k_anorm_tb<<<dim3(16, 16), 256, 0, stream>>>(adj1o, 1024, di1, df1, AN1TB);

    // --- level 1 dense GCNs (MFMA, full-K single launch) ---
    gemm_ab32_bt<<<dim3(4, 32), 256, 0, stream>>>(x1, W1_in, HAT, 1024, 128, 128);
    gemm_tn_bf16_n128<<<dim3(16, 2), 256, 0, stream>>>(AN1TB, HAT, x1_, 1024, b1_in, 1);
    gemm_ab32_bt<<<dim3(4, 32), 256, 0, stream>>>(x1_, Wp2, HBT, 1024, 128, 128);
    gemm_tn_bf16_n128<<<dim3(16, 2), 256, 0, stream>>>(AN1TB, HBT, s2, 1024, bp2, 1);

    // --- diff_pool level 2 ---
    k_softmax_ent<<<1024, 256, 0, stream>>>(s2, S2s, 128, nullptr, &scal[5]);
    k_transpose_f2b<<<dim3(2, 16), 256, 0, stream>>>(S2s, S2ST, 1024, 128, nullptr);
    gemm_tn_bf16_n128<<<dim3(16, 2), 256, 0, stream>>>(ADJ1B, S2ST, u, 1024, nullptr, 0);
    // fused: x2 = S2s^T@x1_, adj2 = S2s^T@u, g2b = ||S2s^T@S2s||^2
    k_atb32_3<<<dim3(4, 4, 3), 256, 0, stream>>>(S2s, x1_, u, S2s, x2, adj2, &scal[7], 128, 128, 1024);

    // --- a_norm for adj2 folded into GCN (+cross2 = tr(adj2)) ---
    k_coldfix128<<<1, 128, 0, stream>>>(adj2, di2, df2, &scal[6]);
    gemm_ab32<<<dim3(4, 4), 256, 0, stream>>>(x2, W2_in, hC, 128, 128, 128, nullptr, 0, 0);
    gemm_atb32n<<<dim3(4, 4), 256, 0, stream>>>(adj2, hC, x2_, 128, 128, 128, b2_in, di2, df2, di2);

    // --- unpool to level 1: HCATT = (x1_@W1o1 + s2@z2)^T bf16, x1o_ via MFMA ---
    gemm_ab32<<<dim3(4, 4), 256, 0, stream>>>(x2_, W1_out + 128 * 128, z2, 128, 128, 128, nullptr, 0, 0);
    gemm_dual_bt<<<dim3(4, 32), 256, 0, stream>>>(x1_, W1_out, s2, z2, HCATT, 1024, 128, 128);
    gemm_tn_bf16_n128<<<dim3(16, 2), 256, 0, stream>>>(AN1TB, HCATT, x1o_, 1024, b1_out, 1);

    // --- unpool to level 0: p16 = x0_@W0out1 + s1o@(x1o_@W0out2) ---
    k_gemm_n16<<<64, 256, 0, stream>>>(x1o_, W0_out + 128 * 16, y16, 1024, 128, 0);
    k_gemm_n16_dual<<<512, 256, 0, stream>>>(x0_, 128, W0_out, s1o, 1024, y16, p16, 8192);
    k_agg16_ls<<<512, 256, 0, stream>>>(p16, predo, cptr, colr, coln, dinv, b0_out);

    k_finalize<<<1, 64, 0, stream>>>(scal, losso);
}

// Round 4
// 883.905 us; speedup vs baseline: 1.3233x; 1.0128x over previous
//
#include <hip/hip_runtime.h>
#include <math.h>

// ---------------------------------------------------------------------------
// DiffPool GNN (N=8192, E=262144, F=H=128, C1=1024, C2=128, NC=16).
// R13: XCD-swizzled tiles-GEMM (A-panel groups per XCD); p16 chain via MFMA
//      (s1b bf16 dual-store, in-kernel B conversion); logf-free entropies;
//      fusions: softmax128 emits S2ST, dinv->anorm_tb, hC+coldfix, finalize
//      ->agg16_ls.
// ---------------------------------------------------------------------------

#define N_NODES 8192
#define N_EDGES 262144

typedef __attribute__((ext_vector_type(8))) short short8;
typedef __attribute__((ext_vector_type(4))) float floatx4;

// ---------------- workspace layout (float-slot offsets, 16-aligned) ----------------
#define OFF_DEG     0           // 8192  (zeroed)
#define OFF_CNTC    8192        // 8192  (zeroed)
#define OFF_CNTR    16384       // 8192  (zeroed)
#define OFF_SCAL    24576       // 16 (zeroed) [0]=e1 [1]=cross(tr adj1) [2]=g2 [3]=sumA2
                                //             [4]=ss_adj1 [5]=e2 [6]=cross2(tr adj2) [7]=g2b
#define ZERO_FLOATS 24592
#define OFF_COLPTR  24592       // 8193
#define OFF_ROWPTR  32785       // 8193
#define OFF_CURC    40978       // 8192
#define OFF_CURR    49170       // 8192
#define OFF_COLR    57362       // E (int)
#define OFF_COLN    319506      // E
#define OFF_ROWC    581650      // E (int)
#define OFF_ROWW    843794      // E
#define OFF_DINV    1105938     // 8192
#define OFF_X0      1114144     // 8192*128 fp32 (x0_)
#define OFF_H0      2162720     // h0b bf16 [8192][128]
// Region A (4M slots at OFF_S: Sb -> {an1Tb, adj1b, hats...}):
#define OFF_S       3211296     // Sb bf16 [8192][1024]
#define OFF_AN1TB   OFF_S                 // bf16 [1024][1024] (after Sb dead)
#define OFF_ADJ1B   (OFF_S+524288)        // bf16 [1024][1024]
#define OFF_HAT     (OFF_S+1048576)       // bf16 [128][1024]
#define OFF_HBT     (OFF_S+1114112)       // bf16 [128][1024]
#define OFF_HCATT   (OFF_S+1179648)       // bf16 [128][1024]
#define OFF_S2ST    (OFF_S+1245184)       // bf16 [128][1024]
#define OFF_X0T     7405600     // bf16 [128][8192]
#define OFF_X0B     7929888     // bf16 [8192][128]
#define A2          8454176
#define OFF_X1      (A2+0)            // 1024*128
#define OFF_Y16     (A2+131072)       // 1024*16
#define OFF_X1_     (A2+262144)       // 1024*128
#define OFF_S2      (A2+524288)       // 1024*128
#define OFF_S2S     (A2+655360)       // 1024*128
#define OFF_U       (A2+786432)       // 1024*128
#define OFF_X2      (A2+917504)       // 128*128
#define OFF_ADJ2    (A2+933888)
#define OFF_HC      (A2+950272)
#define OFF_X2_     (A2+966656)
#define OFF_Z2      (A2+999424)       // 128*128
#define OFF_X1O     (A2+1261568)      // 1024*128
#define OFF_P16     (A2+1392640)      // 8192*16 (early: deg1[1024], diagv[1024])
#define OFF_DEG1    OFF_P16           // 1024 (zeroed via dedicated memset)
#define OFF_DIAGV   (OFF_P16+1024)    // 1024
#define OFF_DI2     (A2+1656832)      // 128
#define OFF_DF2     (A2+1656960)
// Region B:
#define OFF_ST      10111264          // S_T bf16 [1024][8192]
#define OFF_TBF     14305568          // t bf16 [8192][1024]; WP1T aliases; later PT
#define OFF_WP1T    OFF_TBF
#define OFF_PT      OFF_TBF           // fp32 [4][108][128*128] -> ends 21,383,456
#define OFF_S1B     22694176          // s1b bf16 [8192][1024] (disjoint from PT)
#define OFF_TT2     32131360          // TT bf16 [8192][1024]
// total: 36,325,664 float-slots = 138.6 MiB

// ------------------- output layout (floats) -------------------
#define OUT_PRED 0          // 8192*16
#define OUT_S1   131072     // 8192*1024
#define OUT_LOSS 8519680    // 1
#define OUT_ADJ1 8519681    // 1024*1024

__device__ __forceinline__ unsigned short f2bf(float f) {
    union { float f; unsigned u; } v; v.f = f;
    unsigned r = (v.u + 0x7FFF + ((v.u >> 16) & 1)) >> 16;
    return (unsigned short)r;
}
__device__ __forceinline__ float bf2f(unsigned short b) {
    union { unsigned u; float f; } v; v.u = (unsigned)b << 16; return v.f;
}
// async global->LDS 16B (wave-uniform LDS base + lane*16)
__device__ __forceinline__ void gl_lds16(const unsigned short* g, unsigned short* l) {
    __builtin_amdgcn_global_load_lds(
        (const __attribute__((address_space(1))) void*)g,
        (__attribute__((address_space(3))) void*)l, 16, 0, 0);
}

// =========================== graph-structure kernels ===========================

__global__ void k_hist(const int* __restrict__ row, const int* __restrict__ col,
                       const float* __restrict__ ew, int E,
                       float* deg, int* cntc, int* cntr, float* sumA2) {
    __shared__ float red[256];
    int e = blockIdx.x * 256 + threadIdx.x;
    float w2 = 0.f;
    if (e < E) {
        int r = row[e], c = col[e];
        float w = ew[e];
        atomicAdd(&deg[c], w);
        atomicAdd(&cntc[c], 1);
        atomicAdd(&cntr[r], 1);
        w2 = w * w;
    }
    red[threadIdx.x] = w2; __syncthreads();
    for (int s = 128; s > 0; s >>= 1) { if (threadIdx.x < s) red[threadIdx.x] += red[threadIdx.x + s]; __syncthreads(); }
    if (threadIdx.x == 0) atomicAdd(sumA2, red[0]);
}

__global__ __launch_bounds__(1024) void k_scan(const int* cntc, const int* cntr,
        int* colptr, int* rowptr, int* curc, int* curr, int n, int E,
        const float* __restrict__ deg, float* __restrict__ dinv) {
    __shared__ int part[1024];
    int tid = threadIdx.x;
    const int per = 8;
    for (int pass = 0; pass < 2; ++pass) {
        const int* cnt = pass ? cntr : cntc;
        int* ptr = pass ? rowptr : colptr;
        int* cur = pass ? curr : curc;
        int st = tid * per;
        int loc[per]; int s = 0;
        for (int i = 0; i < per; ++i) { loc[i] = s; s += cnt[st + i]; }
        part[tid] = s; __syncthreads();
        for (int off = 1; off < 1024; off <<= 1) {
            int v = part[tid];
            int add = (tid >= off) ? part[tid - off] : 0;
            __syncthreads();
            part[tid] = v + add;
            __syncthreads();
        }
        int pre = (tid == 0) ? 0 : part[tid - 1];
        for (int i = 0; i < per; ++i) { int v = pre + loc[i]; ptr[st + i] = v; cur[st + i] = v; }
        if (tid == 0) ptr[n] = E;
        __syncthreads();
    }
    for (int i = tid; i < n; i += 1024) {
        float d = deg[i] + 1.0f;
        dinv[i] = (d > 0.f) ? 1.0f / sqrtf(d) : 0.f;
    }
}

__global__ void k_scatter(const int* __restrict__ row, const int* __restrict__ col,
                          const float* __restrict__ ew, int E, const float* __restrict__ dinv,
                          int* curc, int* curr, int* colr, float* coln, int* rowc, float* roww) {
    int e = blockIdx.x * 256 + threadIdx.x;
    if (e >= E) return;
    int r = row[e], c = col[e];
    float w = ew[e];
    float nrm = dinv[r] * w * dinv[c];
    int p = atomicAdd(&curc[c], 1);
    colr[p] = r; coln[p] = nrm;
    int q = atomicAdd(&curr[r], 1);
    rowc[q] = c; roww[q] = w;
}

// =========================== fp32 GEMMs ===========================

__global__ __launch_bounds__(256) void gemm_ab_b16(const float* __restrict__ A, const float* __restrict__ B,
        unsigned short* __restrict__ C, int M, int N, int K) {
    __shared__ float As[16][68];
    __shared__ float Bs[16][68];
    int tid = threadIdx.x, tx = tid & 15, ty = tid >> 4;
    int m0 = blockIdx.y * 64, n0 = blockIdx.x * 64;
    float acc[4][4] = {};
    for (int k0 = 0; k0 < K; k0 += 16) {
        for (int l = 0; l < 4; ++l) {
            int idx = tid + 256 * l;
            int mm = idx >> 4, kk = idx & 15;
            As[kk][mm] = A[(size_t)(m0 + mm) * K + k0 + kk];
            int kk2 = idx >> 6, nn = idx & 63;
            Bs[kk2][nn] = B[(size_t)(k0 + kk2) * N + n0 + nn];
        }
        __syncthreads();
        #pragma unroll
        for (int kk = 0; kk < 16; ++kk) {
            float a[4], b[4];
            #pragma unroll
            for (int i = 0; i < 4; ++i) a[i] = As[kk][ty * 4 + i];
            #pragma unroll
            for (int j = 0; j < 4; ++j) b[j] = Bs[kk][tx * 4 + j];
            #pragma unroll
            for (int i = 0; i < 4; ++i)
                #pragma unroll
                for (int j = 0; j < 4; ++j) acc[i][j] += a[i] * b[j];
        }
        __syncthreads();
    }
    for (int i = 0; i < 4; ++i)
        for (int j = 0; j < 4; ++j)
            C[(size_t)(m0 + ty * 4 + i) * N + n0 + tx * 4 + j] = f2bf(acc[i][j]);
}

// 32x32 tile, C = A@B (+bias/relu/accum), fp32 out
__global__ __launch_bounds__(256) void gemm_ab32(const float* __restrict__ A, const float* __restrict__ B,
        float* __restrict__ C, int M, int N, int K,
        const float* __restrict__ bias, int relu, int accum) {
    __shared__ float As[32][33];
    __shared__ float Bs[32][33];
    int tid = threadIdx.x, tx = tid & 15, ty = tid >> 4;
    int m0 = blockIdx.y * 32, n0 = blockIdx.x * 32;
    float acc[2][2] = {};
    for (int k0 = 0; k0 < K; k0 += 32) {
        #pragma unroll
        for (int l = 0; l < 4; ++l) {
            int idx = tid + 256 * l;
            int r = idx >> 5, c = idx & 31;
            As[r][c] = A[(size_t)(m0 + r) * K + k0 + c];
            Bs[r][c] = B[(size_t)(k0 + r) * N + n0 + c];
        }
        __syncthreads();
        #pragma unroll
        for (int kk = 0; kk < 32; ++kk) {
            float a0 = As[ty * 2][kk], a1 = As[ty * 2 + 1][kk];
            float b0 = Bs[kk][tx * 2], b1 = Bs[kk][tx * 2 + 1];
            acc[0][0] += a0 * b0; acc[0][1] += a0 * b1;
            acc[1][0] += a1 * b0; acc[1][1] += a1 * b1;
        }
        __syncthreads();
    }
    #pragma unroll
    for (int i = 0; i < 2; ++i)
        #pragma unroll
        for (int j = 0; j < 2; ++j) {
            int m = m0 + ty * 2 + i, n = n0 + tx * 2 + j;
            float v = acc[i][j];
            if (accum) v += C[(size_t)m * N + n];
            if (bias) v += bias[n];
            if (relu) v = fmaxf(v, 0.f);
            C[(size_t)m * N + n] = v;
        }
}

// 32x32 tile: CT[N][M] bf16 = (A@B)^T, single-source
__global__ __launch_bounds__(256) void gemm_ab32_bt(const float* __restrict__ A,
        const float* __restrict__ B, unsigned short* __restrict__ CT, int M, int N, int K) {
    __shared__ float As[32][33];
    __shared__ float Bs[32][33];
    int tid = threadIdx.x, tx = tid & 15, ty = tid >> 4;
    int m0 = blockIdx.y * 32, n0 = blockIdx.x * 32;
    float acc[2][2] = {};
    for (int k0 = 0; k0 < K; k0 += 32) {
        #pragma unroll
        for (int l = 0; l < 4; ++l) {
            int idx = tid + 256 * l;
            int r = idx >> 5, c = idx & 31;
            As[r][c] = A[(size_t)(m0 + r) * K + k0 + c];
            Bs[r][c] = B[(size_t)(k0 + r) * N + n0 + c];
        }
        __syncthreads();
        #pragma unroll
        for (int kk = 0; kk < 32; ++kk) {
            float a0 = As[ty * 2][kk], a1 = As[ty * 2 + 1][kk];
            float b0 = Bs[kk][tx * 2], b1 = Bs[kk][tx * 2 + 1];
            acc[0][0] += a0 * b0; acc[0][1] += a0 * b1;
            acc[1][0] += a1 * b0; acc[1][1] += a1 * b1;
        }
        __syncthreads();
    }
    #pragma unroll
    for (int i = 0; i < 2; ++i)
        #pragma unroll
        for (int j = 0; j < 2; ++j)
            As[ty * 2 + i][tx * 2 + j] = acc[i][j];
    __syncthreads();
    int nl = tid >> 3, moff = (tid & 7) * 4;
    ushort4 o;
    o.x = f2bf(As[moff + 0][nl]);
    o.y = f2bf(As[moff + 1][nl]);
    o.z = f2bf(As[moff + 2][nl]);
    o.w = f2bf(As[moff + 3][nl]);
    *(ushort4*)(CT + (size_t)(n0 + nl) * M + m0 + moff) = o;
}

// dual-source: CT[N][M] bf16 = (A0@B0 + A1@B1)^T  (both K=Kc)
__global__ __launch_bounds__(256) void gemm_dual_bt(const float* __restrict__ A0,
        const float* __restrict__ B0, const float* __restrict__ A1, const float* __restrict__ B1,
        unsigned short* __restrict__ CT, int M, int N, int Kc) {
    __shared__ float As[32][33];
    __shared__ float Bs[32][33];
    int tid = threadIdx.x, tx = tid & 15, ty = tid >> 4;
    int m0 = blockIdx.y * 32, n0 = blockIdx.x * 32;
    float acc[2][2] = {};
    for (int src = 0; src < 2; ++src) {
        const float* A = src ? A1 : A0;
        const float* B = src ? B1 : B0;
        for (int k0 = 0; k0 < Kc; k0 += 32) {
            #pragma unroll
            for (int l = 0; l < 4; ++l) {
                int idx = tid + 256 * l;
                int r = idx >> 5, c = idx & 31;
                As[r][c] = A[(size_t)(m0 + r) * Kc + k0 + c];
                Bs[r][c] = B[(size_t)(k0 + r) * N + n0 + c];
            }
            __syncthreads();
            #pragma unroll
            for (int kk = 0; kk < 32; ++kk) {
                float a0 = As[ty * 2][kk], a1 = As[ty * 2 + 1][kk];
                float b0 = Bs[kk][tx * 2], b1 = Bs[kk][tx * 2 + 1];
                acc[0][0] += a0 * b0; acc[0][1] += a0 * b1;
                acc[1][0] += a1 * b0; acc[1][1] += a1 * b1;
            }
            __syncthreads();
        }
    }
    #pragma unroll
    for (int i = 0; i < 2; ++i)
        #pragma unroll
        for (int j = 0; j < 2; ++j)
            As[ty * 2 + i][tx * 2 + j] = acc[i][j];
    __syncthreads();
    int nl = tid >> 3, moff = (tid & 7) * 4;
    ushort4 o;
    o.x = f2bf(As[moff + 0][nl]);
    o.y = f2bf(As[moff + 1][nl]);
    o.z = f2bf(As[moff + 2][nl]);
    o.w = f2bf(As[moff + 3][nl]);
    *(ushort4*)(CT + (size_t)(n0 + nl) * M + m0 + moff) = o;
}

// 32x32 tile, C = relu(mscale[m] * (sum_k kscale[k]*(A[k][m]+(k==m)*dfix[m])*B[k][n]) + bias[n])
__global__ __launch_bounds__(256) void gemm_atb32n(const float* __restrict__ A, const float* __restrict__ B,
        float* __restrict__ C, int M, int N, int K,
        const float* __restrict__ bias, const float* __restrict__ kscale,
        const float* __restrict__ dfixv, const float* __restrict__ mscale) {
    __shared__ float As[32][33];
    __shared__ float Bs[32][33];
    int tid = threadIdx.x, tx = tid & 15, ty = tid >> 4;
    int m0 = blockIdx.y * 32, n0 = blockIdx.x * 32;
    float acc[2][2] = {};
    for (int k0 = 0; k0 < K; k0 += 32) {
        #pragma unroll
        for (int l = 0; l < 4; ++l) {
            int idx = tid + 256 * l;
            int r = idx >> 5, c = idx & 31;
            int k = k0 + r, m = m0 + c;
            float v = A[(size_t)k * M + m];
            if (k == m) v += dfixv[m];
            As[c][r] = v * kscale[k];
            Bs[r][c] = B[(size_t)k * N + n0 + c];
        }
        __syncthreads();
        #pragma unroll
        for (int kk = 0; kk < 32; ++kk) {
            float a0 = As[ty * 2][kk], a1 = As[ty * 2 + 1][kk];
            float b0 = Bs[kk][tx * 2], b1 = Bs[kk][tx * 2 + 1];
            acc[0][0] += a0 * b0; acc[0][1] += a0 * b1;
            acc[1][0] += a1 * b0; acc[1][1] += a1 * b1;
        }
        __syncthreads();
    }
    #pragma unroll
    for (int i = 0; i < 2; ++i)
        #pragma unroll
        for (int j = 0; j < 2; ++j) {
            int m = m0 + ty * 2 + i, n = n0 + tx * 2 + j;
            float v = acc[i][j] * mscale[m] + bias[n];
            C[(size_t)m * N + n] = fmaxf(v, 0.f);
        }
}

// fused 3x (A^T@B) sharing A=S2s: op0 C0=A^T@B0, op1 C1=A^T@B1, op2 sumsq(A^T@B2)
__global__ __launch_bounds__(256) void k_atb32_3(const float* __restrict__ A,
        const float* __restrict__ B0, const float* __restrict__ B1, const float* __restrict__ B2,
        float* __restrict__ C0, float* __restrict__ C1, float* ss_acc,
        int M, int N, int K) {
    __shared__ float As[32][33];
    __shared__ float Bs[32][33];
    __shared__ float red[256];
    int op = blockIdx.z;
    const float* B = (op == 0) ? B0 : (op == 1) ? B1 : B2;
    int tid = threadIdx.x, tx = tid & 15, ty = tid >> 4;
    int m0 = blockIdx.y * 32, n0 = blockIdx.x * 32;
    float acc[2][2] = {};
    for (int k0 = 0; k0 < K; k0 += 32) {
        #pragma unroll
        for (int l = 0; l < 4; ++l) {
            int idx = tid + 256 * l;
            int r = idx >> 5, c = idx & 31;
            As[c][r] = A[(size_t)(k0 + r) * M + m0 + c];
            Bs[r][c] = B[(size_t)(k0 + r) * N + n0 + c];
        }
        __syncthreads();
        #pragma unroll
        for (int kk = 0; kk < 32; ++kk) {
            float a0 = As[ty * 2][kk], a1 = As[ty * 2 + 1][kk];
            float b0 = Bs[kk][tx * 2], b1 = Bs[kk][tx * 2 + 1];
            acc[0][0] += a0 * b0; acc[0][1] += a0 * b1;
            acc[1][0] += a1 * b0; acc[1][1] += a1 * b1;
        }
        __syncthreads();
    }
    if (op == 2) {
        float ss = acc[0][0] * acc[0][0] + acc[0][1] * acc[0][1]
                 + acc[1][0] * acc[1][0] + acc[1][1] * acc[1][1];
        red[tid] = ss; __syncthreads();
        for (int s = 128; s > 0; s >>= 1) { if (tid < s) red[tid] += red[tid + s]; __syncthreads(); }
        if (tid == 0) atomicAdd(ss_acc, red[0]);
        return;
    }
    float* C = (op == 0) ? C0 : C1;
    #pragma unroll
    for (int i = 0; i < 2; ++i)
        #pragma unroll
        for (int j = 0; j < 2; ++j)
            C[(size_t)(m0 + ty * 2 + i) * N + n0 + tx * 2 + j] = acc[i][j];
}

// hC = x2@W2 (z=0, grid 4x4) fused with coldfix128 on adj2 (z=1, block (0,0))
__global__ __launch_bounds__(256) void k_hC_coldfix(
        const float* __restrict__ x2, const float* __restrict__ W2,
        float* __restrict__ hC, const float* __restrict__ adj2,
        float* di2, float* df2, float* cross2_out) {
    if (blockIdx.z == 0) {
        __shared__ float As[32][33];
        __shared__ float Bs[32][33];
        int tid = threadIdx.x, tx = tid & 15, ty = tid >> 4;
        int m0 = blockIdx.y * 32, n0 = blockIdx.x * 32;
        float acc[2][2] = {};
        for (int k0 = 0; k0 < 128; k0 += 32) {
            #pragma unroll
            for (int l = 0; l < 4; ++l) {
                int idx = tid + 256 * l;
                int r = idx >> 5, c = idx & 31;
                As[r][c] = x2[(size_t)(m0 + r) * 128 + k0 + c];
                Bs[r][c] = W2[(size_t)(k0 + r) * 128 + n0 + c];
            }
            __syncthreads();
            #pragma unroll
            for (int kk = 0; kk < 32; ++kk) {
                float a0 = As[ty * 2][kk], a1 = As[ty * 2 + 1][kk];
                float b0 = Bs[kk][tx * 2], b1 = Bs[kk][tx * 2 + 1];
                acc[0][0] += a0 * b0; acc[0][1] += a0 * b1;
                acc[1][0] += a1 * b0; acc[1][1] += a1 * b1;
            }
            __syncthreads();
        }
        #pragma unroll
        for (int i = 0; i < 2; ++i)
            #pragma unroll
            for (int j = 0; j < 2; ++j)
                hC[(size_t)(m0 + ty * 2 + i) * 128 + n0 + tx * 2 + j] = acc[i][j];
    } else {
        if (blockIdx.x | blockIdx.y) return;
        __shared__ float red[256];
        int tid = threadIdx.x;
        float diag = 0.f;
        if (tid < 128) {
            float s = 0.f;
            for (int i = 0; i < 128; ++i) s += adj2[(size_t)i * 128 + tid];
            diag = adj2[(size_t)tid * 128 + tid];
            float fix = (diag == 0.f) ? 1.0f : 0.f;
            s += fix;
            df2[tid] = fix;
            di2[tid] = (s > 0.f) ? 1.0f / sqrtf(s) : 0.f;
        }
        red[tid] = diag; __syncthreads();
        for (int st = 128; st > 0; st >>= 1) { if (tid < st) red[tid] += red[tid + st]; __syncthreads(); }
        if (tid == 0) *cross2_out = red[0];
    }
}

// C[M][16] (+)= A[M][K] @ B[K][16]
__global__ __launch_bounds__(256) void k_gemm_n16(const float* __restrict__ A, const float* __restrict__ B,
        float* __restrict__ C, int M, int K, int accum) {
    __shared__ float As[16][64];
    __shared__ float Bs[64][16];
    int tid = threadIdx.x;
    int r = tid >> 4, c = tid & 15;
    int m0 = blockIdx.x * 16;
    float acc = 0.f;
    for (int k0 = 0; k0 < K; k0 += 64) {
        #pragma unroll
        for (int l = 0; l < 4; ++l) {
            int idx = tid + 256 * l;
            int rr = idx >> 6, cc = idx & 63;
            As[rr][cc] = A[(size_t)(m0 + rr) * K + k0 + cc];
            int kk = idx >> 4, c2 = idx & 15;
            Bs[kk][c2] = B[(size_t)(k0 + kk) * 16 + c2];
        }
        __syncthreads();
        #pragma unroll 16
        for (int kk = 0; kk < 64; ++kk) acc += As[r][kk] * Bs[kk][c];
        __syncthreads();
    }
    float* p = &C[(size_t)(m0 + r) * 16 + c];
    if (accum) acc += *p;
    *p = acc;
}

// =========================== bf16 MFMA GEMMs ===========================
// staging: global_load_lds 16B, linear LDS dest, source col pre-swizzled
// (XOR involution: phys (row,c) holds logical (row, c ^ ((row&7)*8)))

// merged K=8192 split-K GEMM over a flattened tile list, XCD-swizzled so all
// tiles sharing an ST A-panel (group m: 8 adj1 + (8-m) G + 1 x1, x4 z = 54*8
// blocks total) colocate per XCD.
//   canonical tiles: 0..63 adj1 (m=t>>3,n=t&7,B=TT); 64..99 G upper (B=ST);
//   100..107 x1 (B=X0T). grid (108,4); P[z][tile][128*128].
__global__ __launch_bounds__(256) void gemm_tn_bf16_tiles(
        const unsigned short* __restrict__ ST_,
        const unsigned short* __restrict__ TT_,
        const unsigned short* __restrict__ X0T_,
        float* __restrict__ P, int K) {
    __shared__ __align__(16) unsigned short As[128 * 64];
    __shared__ __align__(16) unsigned short Bs[128 * 64];
    int tid = threadIdx.x;
    int wave = tid >> 6, lane = tid & 63;
    int wm = wave >> 1, wn = wave & 1;
    // --- XCD swizzle: linear id -> m-grouped order ---
    int lin = blockIdx.x + gridDim.x * blockIdx.y;   // 0..431
    int p432 = (lin & 7) * 54 + (lin >> 3);          // bijective (8*54=432)
    int f = p432 >> 2, z = p432 & 3;                 // f: 0..107 in m-sorted order
    int m = 0, Pfx = 0;
    while (f >= Pfx + 17 - m) { Pfx += 17 - m; ++m; }
    int r = f - Pfx;
    int t, n0; const unsigned short* B;
    if (r < 8)           { t = m * 8 + r;                              n0 = r * 128;            B = TT_; }
    else if (r < 16 - m) { int tj = m + (r - 8);
                           t = 64 + (8 * m - m * (m - 1) / 2) + (r - 8); n0 = tj * 128;         B = ST_; }
    else                 { t = 100 + m;                                n0 = 0;                  B = X0T_; }
    int m0 = m * 128;
    int kchunk = K >> 2;
    int k0 = z * kchunk;
    float* Pz = P + ((size_t)z * 108 + t) * 16384;
    floatx4 acc[4][4] = {};
    int q = lane >> 4, lm = lane & 15;
    int lrow = lane >> 3, lcol = (lane & 7) * 8;
    for (int kt = 0; kt < kchunk; kt += 64) {
        int gk0 = k0 + kt;
        #pragma unroll
        for (int p = 0; p < 4; ++p) {
            int rbase = wave * 32 + p * 8;
            int row = rbase + lrow;
            int scol = lcol ^ ((row & 7) * 8);
            gl_lds16(&ST_[(size_t)(m0 + row) * K + gk0 + scol], &As[rbase * 64]);
            gl_lds16(&B[(size_t)(n0 + row) * K + gk0 + scol], &Bs[rbase * 64]);
        }
        __syncthreads();
        #pragma unroll
        for (int ks = 0; ks < 64; ks += 32) {
            short8 af[4], bf[4];
            int kk = ks + q * 8;
            #pragma unroll
            for (int i = 0; i < 4; ++i) {
                int ml = wm * 64 + i * 16 + lm;
                af[i] = *(const short8*)(&As[ml * 64 + (kk ^ ((ml & 7) * 8))]);
                int nl = wn * 64 + i * 16 + lm;
                bf[i] = *(const short8*)(&Bs[nl * 64 + (kk ^ ((nl & 7) * 8))]);
            }
            #pragma unroll
            for (int i = 0; i < 4; ++i)
                #pragma unroll
                for (int j = 0; j < 4; ++j)
                    acc[i][j] = __builtin_amdgcn_mfma_f32_16x16x32_bf16(af[i], bf[j], acc[i][j], 0, 0, 0);
        }
        __syncthreads();
    }
    for (int i = 0; i < 4; ++i) {
        int lr = wm * 64 + i * 16 + q * 4;
        for (int j = 0; j < 4; ++j) {
            int lc = wn * 64 + j * 16 + lm;
            #pragma unroll
            for (int rr = 0; rr < 4; ++rr)
                Pz[(size_t)(lr + rr) * 128 + lc] = acc[i][j][rr];
        }
    }
}

// reduce the tile partials: adj1 -> adj1o + adj1b + ss + colsum + diag/trace;
// G -> weighted ss only; x1 -> write. grid (2, 108): half-tiles of 64 rows.
__global__ __launch_bounds__(256) void k_reduce_tiles(
        const float* __restrict__ P,
        float* __restrict__ adj1o, unsigned short* __restrict__ adj1b,
        float* __restrict__ x1, float* __restrict__ deg1, float* __restrict__ diagv,
        float* __restrict__ scal) {
    __shared__ float colsum[128];
    __shared__ float red[256];
    int tile = blockIdx.y, half = blockIdx.x, tid = threadIdx.x;
    if (tid < 128) colsum[tid] = 0.f;
    __syncthreads();
    int m, n, kind;
    if (tile < 64)       { kind = 0; m = tile >> 3; n = tile & 7; }
    else if (tile < 100) { kind = 1; int p = tile - 64; int ti = 0;
                           while (p >= 8 - ti) { p -= 8 - ti; ++ti; }
                           m = ti; n = ti + p; }
    else                 { kind = 2; m = tile - 100; n = 0; }
    const float* Pt = P + (size_t)tile * 16384 + half * 8192;
    const size_t zstr = (size_t)108 * 16384;
    float ss = 0.f, tr = 0.f;
    float cs0 = 0.f, cs1 = 0.f, cs2 = 0.f, cs3 = 0.f;
    int cc = (tid * 4) & 127;
    bool diagTile = (kind == 0) && (m == n);
    float wgt = (kind == 1 && m != n) ? 2.f : 1.f;
    for (int it = 0; it < 8; ++it) {
        int i4 = tid * 4 + it * 1024;
        float4 v = *(const float4*)(Pt + i4);
        #pragma unroll
        for (int z = 1; z < 4; ++z) {
            float4 w4 = *(const float4*)(Pt + zstr * z + i4);
            v.x += w4.x; v.y += w4.y; v.z += w4.z; v.w += w4.w;
        }
        int rr = i4 >> 7;
        if (kind == 0) {
            size_t gaddr = (size_t)(m * 128 + half * 64 + rr) * 1024 + n * 128 + cc;
            *(float4*)(adj1o + gaddr) = v;
            ushort4 o; o.x = f2bf(v.x); o.y = f2bf(v.y); o.z = f2bf(v.z); o.w = f2bf(v.w);
            *(ushort4*)(adj1b + gaddr) = o;
            cs0 += v.x; cs1 += v.y; cs2 += v.z; cs3 += v.w;
            ss += v.x * v.x + v.y * v.y + v.z * v.z + v.w * v.w;
            if (diagTile) {
                int dloc = half * 64 + rr;
                int dj = dloc - cc;
                if (dj >= 0 && dj < 4) {
                    float dv = (dj == 0) ? v.x : (dj == 1) ? v.y : (dj == 2) ? v.z : v.w;
                    diagv[m * 128 + dloc] = dv;
                    tr += dv;
                }
            }
        } else if (kind == 1) {
            ss += wgt * (v.x * v.x + v.y * v.y + v.z * v.z + v.w * v.w);
        } else {
            *(float4*)(x1 + (size_t)(m * 128 + half * 64) * 128 + i4) = v;
        }
    }
    if (kind == 2) return;
    if (kind == 0) {
        atomicAdd(&colsum[cc + 0], cs0);
        atomicAdd(&colsum[cc + 1], cs1);
        atomicAdd(&colsum[cc + 2], cs2);
        atomicAdd(&colsum[cc + 3], cs3);
    }
    __syncthreads();
    if (kind == 0 && tid < 128)
        atomicAdd(&deg1[n * 128 + tid], colsum[tid]);
    red[tid] = ss; __syncthreads();
    for (int s = 128; s > 0; s >>= 1) { if (tid < s) red[tid] += red[tid + s]; __syncthreads(); }
    if (tid == 0) atomicAdd((kind == 0) ? &scal[4] : &scal[2], red[0]);
    if (diagTile) {
        __syncthreads();
        red[tid] = tr; __syncthreads();
        for (int s = 128; s > 0; s >>= 1) { if (tid < s) red[tid] += red[tid + s]; __syncthreads(); }
        if (tid == 0) atomicAdd(&scal[1], red[0]);
    }
}

// full-K single-launch: C[M][128] = relu(bias + sum_k A[m][k]*B[n][k]), bf16 in
// tile 64(M) x 64(N), grid (M/64, 2), 4 waves each 16 rows x 64 cols
__global__ __launch_bounds__(256) void gemm_tn_bf16_n128(
        const unsigned short* __restrict__ A, const unsigned short* __restrict__ B,
        float* __restrict__ C, int K,
        const float* __restrict__ bias, int relu) {
    __shared__ __align__(16) unsigned short As[64 * 64];
    __shared__ __align__(16) unsigned short Bs[64 * 64];
    int tid = threadIdx.x, wave = tid >> 6, lane = tid & 63;
    int m0 = blockIdx.x * 64, n0 = blockIdx.y * 64;
    floatx4 acc[4] = {};
    int q = lane >> 4, lm = lane & 15;
    int lrow = lane >> 3, lcol = (lane & 7) * 8;
    for (int kt = 0; kt < K; kt += 64) {
        #pragma unroll
        for (int p = 0; p < 2; ++p) {
            int rbase = wave * 16 + p * 8;
            int row = rbase + lrow;
            int scol = lcol ^ ((row & 7) * 8);
            gl_lds16(&A[(size_t)(m0 + row) * K + kt + scol], &As[rbase * 64]);
            gl_lds16(&B[(size_t)(n0 + row) * K + kt + scol], &Bs[rbase * 64]);
        }
        __syncthreads();
        #pragma unroll
        for (int ks = 0; ks < 64; ks += 32) {
            int kk = ks + q * 8;
            int ml = wave * 16 + lm;
            short8 af = *(const short8*)(&As[ml * 64 + (kk ^ ((ml & 7) * 8))]);
            #pragma unroll
            for (int j = 0; j < 4; ++j) {
                int nl = j * 16 + lm;
                short8 bf = *(const short8*)(&Bs[nl * 64 + (kk ^ ((nl & 7) * 8))]);
                acc[j] = __builtin_amdgcn_mfma_f32_16x16x32_bf16(af, bf, acc[j], 0, 0, 0);
            }
        }
        __syncthreads();
    }
    #pragma unroll
    for (int j = 0; j < 4; ++j) {
        int col = n0 + j * 16 + lm;
        float bv = bias ? bias[col] : 0.f;
        int rowb = m0 + wave * 16 + q * 4;
        #pragma unroll
        for (int r = 0; r < 4; ++r) {
            float v = acc[j][r] + bv;
            if (relu) v = fmaxf(v, 0.f);
            C[(size_t)(rowb + r) * 128 + col] = v;
        }
    }
}

// full-K store with bias+relu; optional dual bf16 output Cb (s1o + s1b)
__global__ __launch_bounds__(256) void gemm_tn_bf16_store(
        const unsigned short* __restrict__ A, const unsigned short* __restrict__ B,
        float* __restrict__ C, unsigned short* __restrict__ Cb, int M, int N, int K,
        const float* __restrict__ bias, int relu) {
    __shared__ __align__(16) unsigned short As[128 * 64];
    __shared__ __align__(16) unsigned short Bs[128 * 64];
    int tid = threadIdx.x;
    int wave = tid >> 6, lane = tid & 63;
    int wm = wave >> 1, wn = wave & 1;
    int m0 = blockIdx.x * 128, n0 = blockIdx.y * 128;
    floatx4 acc[4][4] = {};
    int q = lane >> 4, lm = lane & 15;
    int lrow = lane >> 3, lcol = (lane & 7) * 8;
    for (int kt = 0; kt < K; kt += 64) {
        #pragma unroll
        for (int p = 0; p < 4; ++p) {
            int rbase = wave * 32 + p * 8;
            int row = rbase + lrow;
            int scol = lcol ^ ((row & 7) * 8);
            gl_lds16(&A[(size_t)(m0 + row) * K + kt + scol], &As[rbase * 64]);
            gl_lds16(&B[(size_t)(n0 + row) * K + kt + scol], &Bs[rbase * 64]);
        }
        __syncthreads();
        #pragma unroll
        for (int ks = 0; ks < 64; ks += 32) {
            short8 af[4], bf[4];
            int kk = ks + q * 8;
            #pragma unroll
            for (int i = 0; i < 4; ++i) {
                int ml = wm * 64 + i * 16 + lm;
                af[i] = *(const short8*)(&As[ml * 64 + (kk ^ ((ml & 7) * 8))]);
                int nl = wn * 64 + i * 16 + lm;
                bf[i] = *(const short8*)(&Bs[nl * 64 + (kk ^ ((nl & 7) * 8))]);
            }
            #pragma unroll
            for (int i = 0; i < 4; ++i)
                #pragma unroll
                for (int j = 0; j < 4; ++j)
                    acc[i][j] = __builtin_amdgcn_mfma_f32_16x16x32_bf16(af[i], bf[j], acc[i][j], 0, 0, 0);
        }
        __syncthreads();
    }
    for (int i = 0; i < 4; ++i) {
        int rowb = m0 + wm * 64 + i * 16 + q * 4;
        for (int j = 0; j < 4; ++j) {
            int col = n0 + wn * 64 + j * 16 + lm;
            float bv = bias ? bias[col] : 0.f;
            #pragma unroll
            for (int r = 0; r < 4; ++r) {
                float v = acc[i][j][r] + bv;
                if (relu) v = fmaxf(v, 0.f);
                C[(size_t)(rowb + r) * N + col] = v;
                if (Cb) Cb[(size_t)(rowb + r) * N + col] = f2bf(v);
            }
        }
    }
}

// p16[M][16] = x0b@W0out1 + s1b@y16 via MFMA; B tiles converted fp32->bf16 in-kernel
__global__ __launch_bounds__(256) void k_gemm16_mfma(
        const unsigned short* __restrict__ A0,   // x0b [M][128] bf16
        const unsigned short* __restrict__ A1,   // s1b [M][1024] bf16
        const float* __restrict__ B0,            // W0_out [128][16] fp32
        const float* __restrict__ B1,            // y16 [1024][16] fp32
        float* __restrict__ C) {                 // p16 [M][16] fp32
    __shared__ __align__(16) unsigned short As[128 * 64];
    __shared__ __align__(16) unsigned short Bs[16 * 64];
    int tid = threadIdx.x, wave = tid >> 6, lane = tid & 63;
    int m0 = blockIdx.x * 128;
    int q = lane >> 4, lm = lane & 15;
    int lrow = lane >> 3, lcol = (lane & 7) * 8;
    floatx4 acc[2] = {};
    for (int seg = 0; seg < 2; ++seg) {
        const unsigned short* A = seg ? A1 : A0;
        const float* Bsrc = seg ? B1 : B0;
        int Ks = seg ? 1024 : 128;
        for (int kt = 0; kt < Ks; kt += 64) {
            #pragma unroll
            for (int p = 0; p < 4; ++p) {
                int rbase = wave * 32 + p * 8;
                int row = rbase + lrow;
                int scol = lcol ^ ((row & 7) * 8);
                gl_lds16(&A[(size_t)(m0 + row) * Ks + kt + scol], &As[rbase * 64]);
            }
            for (int e = tid; e < 1024; e += 256) {
                int n = e >> 6, kk = e & 63;
                Bs[n * 64 + (kk ^ ((n & 7) * 8))] = f2bf(Bsrc[(size_t)(kt + kk) * 16 + n]);
            }
            __syncthreads();
            #pragma unroll
            for (int ks = 0; ks < 64; ks += 32) {
                int kk = ks + q * 8;
                short8 bf = *(const short8*)(&Bs[lm * 64 + (kk ^ ((lm & 7) * 8))]);
                #pragma unroll
                for (int i = 0; i < 2; ++i) {
                    int ml = wave * 32 + i * 16 + lm;
                    short8 af = *(const short8*)(&As[ml * 64 + (kk ^ ((ml & 7) * 8))]);
                    acc[i] = __builtin_amdgcn_mfma_f32_16x16x32_bf16(af, bf, acc[i], 0, 0, 0);
                }
            }
            __syncthreads();
        }
    }
    #pragma unroll
    for (int i = 0; i < 2; ++i) {
        int rowb = m0 + wave * 32 + i * 16 + q * 4;
        #pragma unroll
        for (int r = 0; r < 4; ++r)
            C[(size_t)(rowb + r) * 16 + lm] = acc[i][r];
    }
}

// =========================== transposes ===========================

__global__ __launch_bounds__(256) void k_transpose_f2b(
        const float* __restrict__ in, unsigned short* __restrict__ outb,
        int R, int C, const float* __restrict__ rowscale) {
    __shared__ float tile[64][65];
    int rb = blockIdx.y * 64, cb = blockIdx.x * 64;
    int t = threadIdx.x;
    int lr = t >> 4, lc4 = (t & 15) * 4;
    #pragma unroll
    for (int p = 0; p < 4; ++p) {
        int r = rb + lr + p * 16;
        float4 v = *(const float4*)(in + (size_t)r * C + cb + lc4);
        float s = rowscale ? rowscale[r] : 1.0f;
        tile[lr + p * 16][lc4 + 0] = v.x * s;
        tile[lr + p * 16][lc4 + 1] = v.y * s;
        tile[lr + p * 16][lc4 + 2] = v.z * s;
        tile[lr + p * 16][lc4 + 3] = v.w * s;
    }
    __syncthreads();
    int cc0 = t >> 5, rr = (t & 31) * 2;
    #pragma unroll
    for (int p = 0; p < 8; ++p) {
        int cc = cc0 + p * 8;
        unsigned a = f2bf(tile[rr][cc]);
        unsigned b = f2bf(tile[rr + 1][cc]);
        *(unsigned*)(outb + (size_t)(cb + cc) * R + rb + rr) = a | (b << 16);
    }
}

// dual bf16 transpose: blockIdx.z selects (in0->out0) or (in1->out1)
__global__ __launch_bounds__(256) void k_transpose_b2b2(
        const unsigned short* __restrict__ in0, unsigned short* __restrict__ out0,
        const unsigned short* __restrict__ in1, unsigned short* __restrict__ out1,
        int R, int C) {
    __shared__ __align__(16) unsigned short tile[64][72];
    const unsigned short* in = blockIdx.z ? in1 : in0;
    unsigned short* out = blockIdx.z ? out1 : out0;
    int rb = blockIdx.y * 64, cb = blockIdx.x * 64;
    int t = threadIdx.x;
    int lr = t >> 3, lc = (t & 7) * 8;
    #pragma unroll
    for (int p = 0; p < 2; ++p) {
        int r = lr + p * 32;
        *(short8*)(&tile[r][lc]) = *(const short8*)(&in[(size_t)(rb + r) * C + cb + lc]);
    }
    __syncthreads();
    int cc0 = t >> 4, rr = (t & 15) * 4;
    #pragma unroll
    for (int p = 0; p < 4; ++p) {
        int cc = cc0 + p * 16;
        unsigned long long v = (unsigned long long)tile[rr][cc]
                             | ((unsigned long long)tile[rr + 1][cc] << 16)
                             | ((unsigned long long)tile[rr + 2][cc] << 32)
                             | ((unsigned long long)tile[rr + 3][cc] << 48);
        *(unsigned long long*)(&out[(size_t)(cb + cc) * R + rb + rr]) = v;
    }
}

// an1Tb[j][i] = bf16( dinv[i]*(adj1[i][j] + (i==j)*dfix[i])*dinv[j] ),
// dinv/dfix computed inline from deg1/diagv
__global__ __launch_bounds__(256) void k_anorm_tb(const float* __restrict__ adjm, int n,
        const float* __restrict__ deg1, const float* __restrict__ diagv,
        unsigned short* __restrict__ outb) {
    __shared__ float tile[64][65];
    __shared__ float drow[64], frow[64], dcol[64];
    int rb = blockIdx.y * 64, cb = blockIdx.x * 64;
    int t = threadIdx.x;
    if (t < 64) {
        int i = rb + t;
        float fi = (diagv[i] == 0.f) ? 1.0f : 0.f;
        float s = deg1[i] + fi;
        frow[t] = fi;
        drow[t] = (s > 0.f) ? 1.0f / sqrtf(s) : 0.f;
    } else if (t < 128) {
        int j = cb + (t - 64);
        float fj = (diagv[j] == 0.f) ? 1.0f : 0.f;
        float s = deg1[j] + fj;
        dcol[t - 64] = (s > 0.f) ? 1.0f / sqrtf(s) : 0.f;
    }
    __syncthreads();
    int lr = t >> 4, lc4 = (t & 15) * 4;
    #pragma unroll
    for (int p = 0; p < 4; ++p) {
        int rl = lr + p * 16;
        int i = rb + rl;
        float4 v = *(const float4*)(adjm + (size_t)i * n + cb + lc4);
        float di = drow[rl];
        float vv[4] = {v.x, v.y, v.z, v.w};
        #pragma unroll
        for (int qq = 0; qq < 4; ++qq) {
            int j = cb + lc4 + qq;
            float val = vv[qq];
            if (i == j) val += frow[rl];
            tile[rl][lc4 + qq] = di * val * dcol[lc4 + qq];
        }
    }
    __syncthreads();
    int cc0 = t >> 5, rr = (t & 31) * 2;
    #pragma unroll
    for (int p = 0; p < 8; ++p) {
        int cc = cc0 + p * 8;
        unsigned a = f2bf(tile[rr][cc]);
        unsigned b = f2bf(tile[rr + 1][cc]);
        *(unsigned*)(outb + (size_t)(cb + cc) * n + rb + rr) = a | (b << 16);
    }
}

// =========================== aggregation / misc ===========================

__global__ __launch_bounds__(64) void k_agg_b16(const unsigned short* __restrict__ h,
        float* __restrict__ out, unsigned short* __restrict__ outb,
        const int* __restrict__ cptr, const int* __restrict__ colr,
        const float* __restrict__ coln, const float* __restrict__ dinv,
        const float* __restrict__ bias, int relu) {
    int c = blockIdx.x, t = threadIdx.x;
    int f0 = t * 2;
    float d = dinv[c], dd = d * d;
    const unsigned short* hf = h + f0;
    unsigned u = *(const unsigned*)(hf + (size_t)c * 128);
    float a0 = dd * bf2f((unsigned short)(u & 0xffff));
    float a1 = dd * bf2f((unsigned short)(u >> 16));
    int e0 = cptr[c], e1 = cptr[c + 1];
    int e = e0;
    for (; e + 4 <= e1; e += 4) {
        int r0 = colr[e], r1 = colr[e + 1], r2 = colr[e + 2], r3 = colr[e + 3];
        float w0 = coln[e], w1 = coln[e + 1], w2 = coln[e + 2], w3 = coln[e + 3];
        unsigned v0 = *(const unsigned*)(hf + (size_t)r0 * 128);
        unsigned v1 = *(const unsigned*)(hf + (size_t)r1 * 128);
        unsigned v2 = *(const unsigned*)(hf + (size_t)r2 * 128);
        unsigned v3 = *(const unsigned*)(hf + (size_t)r3 * 128);
        a0 += w0 * bf2f((unsigned short)(v0 & 0xffff)) + w1 * bf2f((unsigned short)(v1 & 0xffff))
            + w2 * bf2f((unsigned short)(v2 & 0xffff)) + w3 * bf2f((unsigned short)(v3 & 0xffff));
        a1 += w0 * bf2f((unsigned short)(v0 >> 16)) + w1 * bf2f((unsigned short)(v1 >> 16))
            + w2 * bf2f((unsigned short)(v2 >> 16)) + w3 * bf2f((unsigned short)(v3 >> 16));
    }
    for (; e < e1; ++e) {
        float w = coln[e];
        unsigned v = *(const unsigned*)(hf + (size_t)colr[e] * 128);
        a0 += w * bf2f((unsigned short)(v & 0xffff));
        a1 += w * bf2f((unsigned short)(v >> 16));
    }
    if (bias) { a0 += bias[f0]; a1 += bias[f0 + 1]; }
    if (relu) { a0 = fmaxf(a0, 0.f); a1 = fmaxf(a1, 0.f); }
    if (out) { out[(size_t)c * 128 + f0] = a0; out[(size_t)c * 128 + f0 + 1] = a1; }
    if (outb) {
        unsigned o = (unsigned)f2bf(a0) | ((unsigned)f2bf(a1) << 16);
        *(unsigned*)(outb + (size_t)c * 128 + f0) = o;
    }
}

// F=16 agg + fused log_softmax (16-lane groups) + fused loss finalize (block 0)
__global__ __launch_bounds__(256) void k_agg16_ls(const float* __restrict__ h, float* __restrict__ pred,
        const int* __restrict__ cptr, const int* __restrict__ colr,
        const float* __restrict__ coln, const float* __restrict__ dinv,
        const float* __restrict__ bias, const float* __restrict__ sc, float* loss) {
    if (blockIdx.x == 0 && threadIdx.x == 0) {
        float e1     = sc[0] / 8192.0f;
        float cross  = sc[1];
        float g2     = sc[2];
        float sumA2  = sc[3];
        float ssadj1 = sc[4];
        float e2     = sc[5] / 1024.0f;
        float cross2 = sc[6];
        float g2b    = sc[7];
        float l1 = sqrtf(fmaxf(sumA2 - 2.0f * cross + g2, 0.f)) / 67108864.0f;
        float l2 = sqrtf(fmaxf(ssadj1 - 2.0f * cross2 + g2b, 0.f)) / 1048576.0f;
        *loss = l1 + e1 + l2 + e2;
    }
    int node = blockIdx.x * 16 + (threadIdx.x >> 4);
    int f = threadIdx.x & 15;
    float d = dinv[node];
    const float* hf = h + f;
    float acc = d * d * hf[(size_t)node * 16];
    int e0 = cptr[node], e1v = cptr[node + 1];
    int e = e0;
    for (; e + 4 <= e1v; e += 4) {
        int r0 = colr[e], r1 = colr[e + 1], r2 = colr[e + 2], r3 = colr[e + 3];
        float w0 = coln[e], w1 = coln[e + 1], w2 = coln[e + 2], w3 = coln[e + 3];
        float v0 = hf[(size_t)r0 * 16], v1 = hf[(size_t)r1 * 16];
        float v2 = hf[(size_t)r2 * 16], v3 = hf[(size_t)r3 * 16];
        acc += w0 * v0 + w1 * v1 + w2 * v2 + w3 * v3;
    }
    for (; e < e1v; ++e)
        acc += coln[e] * hf[(size_t)colr[e] * 16];
    acc += bias[f];
    acc = fmaxf(acc, 0.f);
    float m = acc;
    #pragma unroll
    for (int off = 1; off < 16; off <<= 1) m = fmaxf(m, __shfl_xor(m, off, 16));
    float ex = expf(acc - m);
    float s = ex;
    #pragma unroll
    for (int off = 1; off < 16; off <<= 1) s += __shfl_xor(s, off, 16);
    pred[(size_t)node * 16 + f] = acc - m - logf(s);
}

// softmax over 1024 cols + bf16 store + logf-free entropy
__global__ __launch_bounds__(256) void k_softmax1024(const float* __restrict__ x,
        unsigned short* __restrict__ Sb, const float* __restrict__ mask, float* ent_acc) {
    __shared__ float red[256];
    int r = blockIdx.x, tid = threadIdx.x;
    const float* xr = x + (size_t)r * 1024;
    float4 v = *(const float4*)(xr + tid * 4);
    float m = fmaxf(fmaxf(v.x, v.y), fmaxf(v.z, v.w));
    red[tid] = m; __syncthreads();
    for (int s = 128; s > 0; s >>= 1) { if (tid < s) red[tid] = fmaxf(red[tid], red[tid + s]); __syncthreads(); }
    m = red[0]; __syncthreads();
    float e0 = expf(v.x - m), e1 = expf(v.y - m), e2 = expf(v.z - m), e3 = expf(v.w - m);
    red[tid] = e0 + e1 + e2 + e3; __syncthreads();
    for (int s = 128; s > 0; s >>= 1) { if (tid < s) red[tid] += red[tid + s]; __syncthreads(); }
    float Z = red[0];
    float inv = 1.0f / Z, lz = logf(Z);
    __syncthreads();
    float mk = mask ? mask[r] : 1.0f;
    float s0 = e0 * inv * mk, s1 = e1 * inv * mk, s2 = e2 * inv * mk, s3 = e3 * inv * mk;
    // -s'*log s' summed == sum s'*(m+lz-x) - mk*log(mk)
    float ent = s0 * (m + lz - v.x) + s1 * (m + lz - v.y)
              + s2 * (m + lz - v.z) + s3 * (m + lz - v.w);
    ushort4 o;
    o.x = f2bf(s0); o.y = f2bf(s1); o.z = f2bf(s2); o.w = f2bf(s3);
    *(ushort4*)(Sb + (size_t)r * 1024 + tid * 4) = o;
    red[tid] = ent; __syncthreads();
    for (int s = 128; s > 0; s >>= 1) { if (tid < s) red[tid] += red[tid + s]; __syncthreads(); }
    if (tid == 0) {
        float row_ent = red[0] - ((mk > 0.f) ? mk * logf(mk) : 0.f);
        atomicAdd(ent_acc, row_ent);
    }
}

// softmax over 128 cols (s2): writes S fp32, S^T bf16, logf-free entropy
__global__ __launch_bounds__(128) void k_softmax128_t(const float* __restrict__ x,
        float* __restrict__ S, unsigned short* __restrict__ STb, float* ent_acc) {
    __shared__ float red[128];
    int row = blockIdx.x, tid = threadIdx.x;
    const float* xr = x + (size_t)row * 128;
    float v = xr[tid];
    red[tid] = v; __syncthreads();
    for (int s = 64; s > 0; s >>= 1) { if (tid < s) red[tid] = fmaxf(red[tid], red[tid + s]); __syncthreads(); }
    float m = red[0]; __syncthreads();
    float e = expf(v - m);
    red[tid] = e; __syncthreads();
    for (int s = 64; s > 0; s >>= 1) { if (tid < s) red[tid] += red[tid + s]; __syncthreads(); }
    float Z = red[0];
    float inv = 1.0f / Z, lz = logf(Z);
    __syncthreads();
    float sv = e * inv;
    S[(size_t)row * 128 + tid] = sv;
    STb[(size_t)tid * 1024 + row] = f2bf(sv);
    red[tid] = sv * (m + lz - v); __syncthreads();
    for (int s = 64; s > 0; s >>= 1) { if (tid < s) red[tid] += red[tid + s]; __syncthreads(); }
    if (tid == 0) atomicAdd(ent_acc, red[0]);
}

// L2-segmented SpMM, 4 waves/block = 4 rows, pass p = cols [p*256, p*256+256)
__global__ __launch_bounds__(256) void k_spmm_seg(const unsigned short* __restrict__ Sb,
        const int* __restrict__ rptr, const int* __restrict__ rowc, const float* __restrict__ roww,
        unsigned short* __restrict__ tb) {
    int wave = threadIdx.x >> 6, lane = threadIdx.x & 63;
    int r = blockIdx.x * 4 + wave;
    int j0 = blockIdx.y * 256 + lane * 4;
    const unsigned short* Sj = Sb + j0;
    float a0 = 0.f, a1 = 0.f, a2 = 0.f, a3 = 0.f;
    int e0 = rptr[r], e1 = rptr[r + 1];
    int e = e0;
    for (; e + 4 <= e1; e += 4) {
        int c0 = rowc[e], c1 = rowc[e + 1], c2 = rowc[e + 2], c3 = rowc[e + 3];
        float w0 = roww[e], w1 = roww[e + 1], w2 = roww[e + 2], w3 = roww[e + 3];
        uint2 v0 = *(const uint2*)(Sj + (size_t)c0 * 1024);
        uint2 v1 = *(const uint2*)(Sj + (size_t)c1 * 1024);
        uint2 v2 = *(const uint2*)(Sj + (size_t)c2 * 1024);
        uint2 v3 = *(const uint2*)(Sj + (size_t)c3 * 1024);
        a0 += w0 * bf2f((unsigned short)(v0.x & 0xffff)) + w1 * bf2f((unsigned short)(v1.x & 0xffff))
            + w2 * bf2f((unsigned short)(v2.x & 0xffff)) + w3 * bf2f((unsigned short)(v3.x & 0xffff));
        a1 += w0 * bf2f((unsigned short)(v0.x >> 16)) + w1 * bf2f((unsigned short)(v1.x >> 16))
            + w2 * bf2f((unsigned short)(v2.x >> 16)) + w3 * bf2f((unsigned short)(v3.x >> 16));
        a2 += w0 * bf2f((unsigned short)(v0.y & 0xffff)) + w1 * bf2f((unsigned short)(v1.y & 0xffff))
            + w2 * bf2f((unsigned short)(v2.y & 0xffff)) + w3 * bf2f((unsigned short)(v3.y & 0xffff));
        a3 += w0 * bf2f((unsigned short)(v0.y >> 16)) + w1 * bf2f((unsigned short)(v1.y >> 16))
            + w2 * bf2f((unsigned short)(v2.y >> 16)) + w3 * bf2f((unsigned short)(v3.y >> 16));
    }
    for (; e < e1; ++e) {
        int c = rowc[e]; float w = roww[e];
        uint2 v = *(const uint2*)(Sj + (size_t)c * 1024);
        a0 += w * bf2f((unsigned short)(v.x & 0xffff));
        a1 += w * bf2f((unsigned short)(v.x >> 16));
        a2 += w * bf2f((unsigned short)(v.y & 0xffff));
        a3 += w * bf2f((unsigned short)(v.y >> 16));
    }
    unsigned lo = (unsigned)f2bf(a0) | ((unsigned)f2bf(a1) << 16);
    unsigned hi = (unsigned)f2bf(a2) | ((unsigned)f2bf(a3) << 16);
    unsigned long long o = (unsigned long long)lo | ((unsigned long long)hi << 32);
    *(unsigned long long*)(tb + (size_t)r * 1024 + j0) = o;
}

// =========================== launcher ===========================

extern "C" void kernel_launch(void* const* d_in, const int* in_sizes, int n_in,
                              void* d_out, int out_size, void* d_ws, size_t ws_size,
                              hipStream_t stream) {
    const int N = N_NODES, E = N_EDGES;
    const float* x0     = (const float*)d_in[0];
    const int*   eidx   = (const int*)d_in[1];
    const float* ew     = (const float*)d_in[2];
    const float* mask   = (const float*)d_in[4];
    const float* W0_in  = (const float*)d_in[5];
    const float* b0_in  = (const float*)d_in[6];
    const float* Wp1    = (const float*)d_in[7];
    const float* bp1    = (const float*)d_in[8];
    const float* W1_in  = (const float*)d_in[9];
    const float* b1_in  = (const float*)d_in[10];
    const float* Wp2    = (const float*)d_in[11];
    const float* bp2    = (const float*)d_in[12];
    const float* W2_in  = (const float*)d_in[13];
    const float* b2_in  = (const float*)d_in[14];
    const float* W1_out = (const float*)d_in[15];
    const float* b1_out = (const float*)d_in[16];
    const float* W0_out = (const float*)d_in[17];
    const float* b0_out = (const float*)d_in[18];

    float* out   = (float*)d_out;
    float* predo = out + OUT_PRED;
    float* s1o   = out + OUT_S1;
    float* losso = out + OUT_LOSS;
    float* adj1o = out + OUT_ADJ1;

    float* wsf = (float*)d_ws;
    int*   wsi = (int*)d_ws;
    float* deg   = wsf + OFF_DEG;
    int*   cntc  = wsi + OFF_CNTC;
    int*   cntr  = wsi + OFF_CNTR;
    float* scal  = wsf + OFF_SCAL;
    int*   cptr  = wsi + OFF_COLPTR;
    int*   rptr  = wsi + OFF_ROWPTR;
    int*   curc  = wsi + OFF_CURC;
    int*   curr  = wsi + OFF_CURR;
    int*   colr  = wsi + OFF_COLR;
    float* coln  = wsf + OFF_COLN;
    int*   rowc  = wsi + OFF_ROWC;
    float* roww  = wsf + OFF_ROWW;
    float* dinv  = wsf + OFF_DINV;
    float* x0_   = wsf + OFF_X0;
    unsigned short* h0b   = (unsigned short*)(wsf + OFF_H0);
    unsigned short* Sb    = (unsigned short*)(wsf + OFF_S);
    unsigned short* TT    = (unsigned short*)(wsf + OFF_TT2);
    unsigned short* AN1TB = (unsigned short*)(wsf + OFF_AN1TB);
    unsigned short* ADJ1B = (unsigned short*)(wsf + OFF_ADJ1B);
    unsigned short* HAT   = (unsigned short*)(wsf + OFF_HAT);
    unsigned short* HBT   = (unsigned short*)(wsf + OFF_HBT);
    unsigned short* HCATT = (unsigned short*)(wsf + OFF_HCATT);
    unsigned short* S2ST  = (unsigned short*)(wsf + OFF_S2ST);
    unsigned short* ST    = (unsigned short*)(wsf + OFF_ST);
    unsigned short* TBF   = (unsigned short*)(wsf + OFF_TBF);
    unsigned short* WP1T  = (unsigned short*)(wsf + OFF_WP1T);
    unsigned short* X0T   = (unsigned short*)(wsf + OFF_X0T);
    unsigned short* x0b   = (unsigned short*)(wsf + OFF_X0B);
    unsigned short* s1b   = (unsigned short*)(wsf + OFF_S1B);
    float* PT    = wsf + OFF_PT;
    float* x1    = wsf + OFF_X1;
    float* y16   = wsf + OFF_Y16;
    float* x1_   = wsf + OFF_X1_;
    float* s2    = wsf + OFF_S2;
    float* S2s   = wsf + OFF_S2S;
    float* u     = wsf + OFF_U;
    float* x2    = wsf + OFF_X2;
    float* adj2  = wsf + OFF_ADJ2;
    float* hC    = wsf + OFF_HC;
    float* x2_   = wsf + OFF_X2_;
    float* z2    = wsf + OFF_Z2;
    float* x1o_  = wsf + OFF_X1O;
    float* p16   = wsf + OFF_P16;
    float* deg1  = wsf + OFF_DEG1;
    float* diagv = wsf + OFF_DIAGV;
    float* di2   = wsf + OFF_DI2;
    float* df2   = wsf + OFF_DF2;

    const int* row = eidx;
    const int* col = eidx + E;

    hipMemsetAsync(wsf, 0, (size_t)ZERO_FLOATS * sizeof(float), stream);
    hipMemsetAsync(deg1, 0, 1024 * sizeof(float), stream);

    // --- graph structure ---
    k_hist<<<E / 256, 256, 0, stream>>>(row, col, ew, E, deg, cntc, cntr, &scal[3]);
    k_scan<<<1, 1024, 0, stream>>>(cntc, cntr, cptr, rptr, curc, curr, N, E, deg, dinv);
    k_scatter<<<E / 256, 256, 0, stream>>>(row, col, ew, E, dinv, curc, curr, colr, coln, rowc, roww);

    // --- level 0 GCN ---
    gemm_ab_b16<<<dim3(2, 128), 256, 0, stream>>>(x0, W0_in, h0b, 8192, 128, 128);
    k_agg_b16<<<N, 64, 0, stream>>>(h0b, x0_, x0b, cptr, colr, coln, dinv, b0_in, 1);

    // --- s1 = relu((M^T x0_)@Wp1 + bp1) (+ bf16 copy s1b) ---
    k_agg_b16<<<N, 64, 0, stream>>>(x0b, nullptr, h0b, cptr, colr, coln, dinv, nullptr, 0);
    k_transpose_f2b<<<dim3(16, 2), 256, 0, stream>>>(Wp1, WP1T, 128, 1024, nullptr);
    gemm_tn_bf16_store<<<dim3(64, 8), 256, 0, stream>>>(h0b, WP1T, s1o, s1b, 8192, 1024, 128, bp1, 1);

    // --- diff_pool level 1 ---
    k_softmax1024<<<N, 256, 0, stream>>>(s1o, Sb, mask, &scal[0]);
    k_spmm_seg<<<dim3(N / 4, 4), 256, 0, stream>>>(Sb, rptr, rowc, roww, TBF);
    k_transpose_b2b2<<<dim3(16, 128, 2), 256, 0, stream>>>(Sb, ST, TBF, TT, 8192, 1024);
    k_transpose_f2b<<<dim3(2, 128), 256, 0, stream>>>(x0_, X0T, 8192, 128, mask);

    // merged big GEMM (XCD-swizzled): adj1 64 + G-upper 36 + x1 8, z=4
    gemm_tn_bf16_tiles<<<dim3(108, 4), 256, 0, stream>>>(ST, TT, X0T, PT, 8192);
    k_reduce_tiles<<<dim3(2, 108), 256, 0, stream>>>(PT, adj1o, ADJ1B, x1, deg1, diagv, scal);
    k_anorm_tb<<<dim3(16, 16), 256, 0, stream>>>(adj1o, 1024, deg1, diagv, AN1TB);

    // --- level 1 dense GCNs (MFMA, full-K single launch) ---
    gemm_ab32_bt<<<dim3(4, 32), 256, 0, stream>>>(x1, W1_in, HAT, 1024, 128, 128);
    gemm_tn_bf16_n128<<<dim3(16, 2), 256, 0, stream>>>(AN1TB, HAT, x1_, 1024, b1_in, 1);
    gemm_ab32_bt<<<dim3(4, 32), 256, 0, stream>>>(x1_, Wp2, HBT, 1024, 128, 128);
    gemm_tn_bf16_n128<<<dim3(16, 2), 256, 0, stream>>>(AN1TB, HBT, s2, 1024, bp2, 1);

    // --- diff_pool level 2 ---
    k_softmax128_t<<<1024, 128, 0, stream>>>(s2, S2s, S2ST, &scal[5]);
    gemm_tn_bf16_n128<<<dim3(16, 2), 256, 0, stream>>>(ADJ1B, S2ST, u, 1024, nullptr, 0);
    // fused: x2 = S2s^T@x1_, adj2 = S2s^T@u, g2b = ||S2s^T@S2s||^2
    k_atb32_3<<<dim3(4, 4, 3), 256, 0, stream>>>(S2s, x1_, u, S2s, x2, adj2, &scal[7], 128, 128, 1024);

    // --- hC = x2@W2_in fused with coldfix(adj2) -> di2/df2/cross2 ---
    k_hC_coldfix<<<dim3(4, 4, 2), 256, 0, stream>>>(x2, W2_in, hC, adj2, di2, df2, &scal[6]);
    gemm_atb32n<<<dim3(4, 4), 256, 0, stream>>>(adj2, hC, x2_, 128, 128, 128, b2_in, di2, df2, di2);

    // --- unpool to level 1: HCATT = (x1_@W1o1 + s2@z2)^T bf16, x1o_ via MFMA ---
    gemm_ab32<<<dim3(4, 4), 256, 0, stream>>>(x2_, W1_out + 128 * 128, z2, 128, 128, 128, nullptr, 0, 0);
    gemm_dual_bt<<<dim3(4, 32), 256, 0, stream>>>(x1_, W1_out, s2, z2, HCATT, 1024, 128, 128);
    gemm_tn_bf16_n128<<<dim3(16, 2), 256, 0, stream>>>(AN1TB, HCATT, x1o_, 1024, b1_out, 1);

    // --- unpool to level 0: p16 = x0b@W0out1 + s1b@y16 (MFMA) ---
    k_gemm_n16<<<64, 256, 0, stream>>>(x1o_, W0_out + 128 * 16, y16, 1024, 128, 0);
    k_gemm16_mfma<<<64, 256, 0, stream>>>(x0b, s1b, W0_out, y16, p16);
    k_agg16_ls<<<512, 256, 0, stream>>>(p16, predo, cptr, colr, coln, dinv, b0_out, scal, losso);
}